// Round 1
// baseline (379.019 us; speedup 1.0000x reference)
//
#include <hip/hip_runtime.h>

typedef unsigned short u16;
typedef unsigned int   u32;
typedef __attribute__((ext_vector_type(4))) float fx4;
typedef __attribute__((ext_vector_type(8))) __bf16 bf16x8;
typedef __attribute__((ext_vector_type(8))) unsigned short us8;
typedef __attribute__((ext_vector_type(2))) unsigned int u32x2;

__device__ __forceinline__ u16 f2bf(float x){
  u32 u = __builtin_bit_cast(u32, x);
  u += 0x7fffu + ((u >> 16) & 1u);
  return (u16)(u >> 16);
}
__device__ __forceinline__ float b2f(u16 h){
  u32 u = ((u32)h) << 16;
  return __builtin_bit_cast(float, u);
}
__device__ __forceinline__ void gld16(const void* g, void* l){
  __builtin_amdgcn_global_load_lds(
      (const __attribute__((address_space(1))) u32*)g,
      (__attribute__((address_space(3))) u32*)l, 16, 0, 0);
}

// ---------------- fp32 -> bf16 convert (vectorized, grid-stride) ----------------
__global__ __launch_bounds__(256) void k_f2bf(const float* __restrict__ in,
                                              u16* __restrict__ out, int n8){
  int i = blockIdx.x * 256 + threadIdx.x;
  const int stride = gridDim.x * 256;
  for (; i < n8; i += stride){
    const float4* p = (const float4*)in + (long)i * 2;
    float4 a = p[0], b = p[1];
    us8 o = { f2bf(a.x), f2bf(a.y), f2bf(a.z), f2bf(a.w),
              f2bf(b.x), f2bf(b.y), f2bf(b.z), f2bf(b.w) };
    *((us8*)out + i) = o;
  }
}

__global__ void k_zero(float* p, int n){
  int i = blockIdx.x * 256 + threadIdx.x;
  if (i < n) p[i] = 0.f;
}

// ---------------- transpose + convert: in [R,C] f32 -> out [C,R] bf16 ----------------
// optional per-column sum (fp32, atomicAdd) for the bias fold
__global__ __launch_bounds__(256) void k_tconv(const float* __restrict__ in,
                                               u16* __restrict__ out,
                                               int R, int C, long sIn, long sOut,
                                               float* __restrict__ colsum){
  in  += (long)blockIdx.z * sIn;
  out += (long)blockIdx.z * sOut;
  const int c0 = blockIdx.x * 64, r0 = blockIdx.y * 64;
  __shared__ u16 tile[64][72];
  __shared__ float red[256];
  const int t = threadIdx.x;
  const int cc = t & 63, wq = t >> 6;
  float part = 0.f;
  #pragma unroll
  for (int i = 0; i < 16; ++i){
    int rr = i * 4 + wq;
    float v = in[(long)(r0 + rr) * C + c0 + cc];
    tile[rr][cc] = f2bf(v);
    part += v;
  }
  if (colsum){
    red[t] = part;
    __syncthreads();
    if (t < 64){
      float s = red[t] + red[t + 64] + red[t + 128] + red[t + 192];
      atomicAdd(&colsum[c0 + t], s);
    }
  }
  __syncthreads();
  #pragma unroll
  for (int i = 0; i < 16; ++i){
    int oc = i * 4 + wq;
    out[(long)(c0 + oc) * R + r0 + cc] = tile[cc][oc];
  }
}

// ---------------- BT-layout MFMA GEMM: C[M,N] = A[M,K] * B[N,K]^T ----------------
// MODE 0: z-batch via strides.  MODE 1: scores (pk slice x qp view).
// MODE 2: attnT x pvT -> outh.  MODE 3: ck/cv combined (proj x kT/vT).
// EPI 0: none. 1: +bias[col]. 2: (v + srow[row]*bias[col])*scale.
// EPI 3: v + srow[row]*bias[col], write transposed (pvT[col][row]).
template<int BM, int BN, int MODE, int EPI, typename OutT>
__global__ __launch_bounds__(256) void k_gemm(
    const u16* __restrict__ A, int lda, long sAz,
    const u16* __restrict__ B, int ldb, long sBz,
    OutT* __restrict__ C, int ldc, long sCz,
    int K, const float* __restrict__ bias, const float* __restrict__ srow, float scale)
{
  constexpr int BK = 64;
  constexpr int FM = BM / 32, FN = BN / 32;
  __shared__ u16 ldsA[BM * BK];
  __shared__ u16 ldsB[BN * BK];
  const long z = blockIdx.z;
  if constexpr (MODE == 0){ A += z * sAz; B += z * sBz; C += z * sCz; }
  if constexpr (MODE == 1){ A += (z >> 4) * 131072 + (z & 15) * 64; B += z * 131072; C += z * 262144; }
  if constexpr (MODE == 2){ A += z * 262144; B += (z >> 4) * 131072 + (z & 15) * 8192;
                            C += (z >> 4) * 2097152 + (z & 15) * 64; }
  if constexpr (MODE == 3){ long p = z >> 3, bb = z & 7;
                            A += p * 262144; B += p * 16777216 + bb * 2097152;
                            C += p * 1048576 + bb * 131072; }
  const int t = threadIdx.x;
  const int lane = t & 63;
  const int w = t >> 6, wm = w >> 1, wn = w & 1;
  const int r15 = lane & 15, g = lane >> 4;
  const int m0 = blockIdx.y * BM, n0 = blockIdx.x * BN;
  fx4 acc[FM][FN] = {};
  constexpr int CA = BM * BK / (8 * 256);
  constexpr int CB = BN * BK / (8 * 256);
  for (int kt = 0; kt < K; kt += BK){
    #pragma unroll
    for (int i = 0; i < CA; ++i){
      int ch = i * 256 + t, row = ch >> 3, cc = ch & 7;
      gld16(A + (long)(m0 + row) * lda + kt + cc * 8, (char*)ldsA + ch * 16);
    }
    #pragma unroll
    for (int i = 0; i < CB; ++i){
      int ch = i * 256 + t, row = ch >> 3, cc = ch & 7;
      gld16(B + (long)(n0 + row) * ldb + kt + cc * 8, (char*)ldsB + ch * 16);
    }
    __syncthreads();
    #pragma unroll
    for (int ks = 0; ks < 2; ++ks){
      bf16x8 af[FM], bfv[FN];
      #pragma unroll
      for (int mf = 0; mf < FM; ++mf)
        af[mf] = *(const bf16x8*)&ldsA[(wm * (BM/2) + mf * 16 + r15) * BK + ks * 32 + g * 8];
      #pragma unroll
      for (int nf = 0; nf < FN; ++nf)
        bfv[nf] = *(const bf16x8*)&ldsB[(wn * (BN/2) + nf * 16 + r15) * BK + ks * 32 + g * 8];
      #pragma unroll
      for (int mf = 0; mf < FM; ++mf)
        #pragma unroll
        for (int nf = 0; nf < FN; ++nf)
          acc[mf][nf] = __builtin_amdgcn_mfma_f32_16x16x32_bf16(af[mf], bfv[nf], acc[mf][nf], 0, 0, 0);
    }
    __syncthreads();
  }
  #pragma unroll
  for (int mf = 0; mf < FM; ++mf){
    #pragma unroll
    for (int nf = 0; nf < FN; ++nf){
      const int row0 = m0 + wm * (BM/2) + mf * 16 + g * 4;
      const int col  = n0 + wn * (BN/2) + nf * 16 + r15;
      float vv[4];
      #pragma unroll
      for (int r = 0; r < 4; ++r){
        float v = acc[mf][nf][r];
        if constexpr (EPI == 1) v += bias[col];
        if constexpr (EPI == 2) v = (v + srow[row0 + r] * bias[col]) * scale;
        if constexpr (EPI == 3) v = v + srow[row0 + r] * bias[col];
        vv[r] = v;
      }
      if constexpr (EPI == 3){
        u32 lo = (u32)f2bf(vv[0]) | ((u32)f2bf(vv[1]) << 16);
        u32 hi = (u32)f2bf(vv[2]) | ((u32)f2bf(vv[3]) << 16);
        u32x2 pk2 = { lo, hi };
        *(u32x2*)((u16*)C + (long)col * 128 + row0) = pk2;
      } else {
        #pragma unroll
        for (int r = 0; r < 4; ++r){
          if constexpr (sizeof(OutT) == 2) C[(long)(row0 + r) * ldc + col] = (OutT)f2bf(vv[r]);
          else                             C[(long)(row0 + r) * ldc + col] = (OutT)vv[r];
        }
      }
    }
  }
}

// ---------------- row softmax over n=2048, writes transposed attnT[n][k] ----------------
// grid (8 kblocks, 128 z), block 256: thread (r = t&15 -> row, s = t>>4 -> col group)
__global__ __launch_bounds__(256) void k_softmax(const u16* __restrict__ S,
                                                 u16* __restrict__ AT){
  const int z = blockIdx.y, kb = blockIdx.x;
  const int t = threadIdx.x;
  const int r = t & 15, s = t >> 4;
  const u16* row = S + (long)z * 262144 + (long)(kb * 16 + r) * 2048;
  us8 buf[16];
  float m = -1e30f;
  #pragma unroll
  for (int i = 0; i < 16; ++i){
    buf[i] = *(const us8*)(row + (i * 16 + s) * 8);
    #pragma unroll
    for (int j = 0; j < 8; ++j) m = fmaxf(m, b2f(buf[i][j]));
  }
  __shared__ float red[256];
  __shared__ float rowm[16], rowz[16];
  red[t] = m;
  __syncthreads();
  if (t < 16){
    float mm = red[t];
    #pragma unroll
    for (int j = 1; j < 16; ++j) mm = fmaxf(mm, red[t + j * 16]);
    rowm[t] = mm;
  }
  __syncthreads();
  m = rowm[r];
  float sum = 0.f;
  #pragma unroll
  for (int i = 0; i < 16; ++i)
    #pragma unroll
    for (int j = 0; j < 8; ++j) sum += __expf(b2f(buf[i][j]) - m);
  red[t] = sum;
  __syncthreads();
  if (t < 16){
    float ss = 0.f;
    #pragma unroll
    for (int j = 0; j < 16; ++j) ss += red[t + j * 16];
    rowz[t] = 1.0f / ss;
  }
  __syncthreads();
  const float inv = rowz[r];
  u16* out = AT + (long)z * 262144 + (kb * 16 + r);
  #pragma unroll
  for (int i = 0; i < 16; ++i){
    #pragma unroll
    for (int j = 0; j < 8; ++j){
      float p = __expf(b2f(buf[i][j]) - m) * inv;
      out[(long)((i * 16 + s) * 8 + j) * 128] = f2bf(p);
    }
  }
}

extern "C" void kernel_launch(void* const* d_in, const int* in_sizes, int n_in,
                              void* d_out, int out_size, void* d_ws, size_t ws_size,
                              hipStream_t stream)
{
  const float* q   = (const float*)d_in[0];
  const float* k   = (const float*)d_in[1];
  const float* v   = (const float*)d_in[2];
  const float* Wq  = (const float*)d_in[3];
  const float* bq  = (const float*)d_in[4];
  const float* Wk  = (const float*)d_in[5];
  const float* bk  = (const float*)d_in[6];
  const float* Wv  = (const float*)d_in[7];
  const float* bv  = (const float*)d_in[8];
  const float* pjk = (const float*)d_in[9];
  const float* pjv = (const float*)d_in[10];
  const float* Wo  = (const float*)d_in[11];
  const float* bo  = (const float*)d_in[12];

  if (ws_size < 152044544u) return;   // layout below needs 145 MiB

  char* ws = (char*)d_ws;
  u16*  q_bf  = (u16*)(ws + 0);            // 32MB   (reused by outh)
  u16*  kT    = (u16*)(ws + 33554432);     // 32MB   (reused by attnT)
  u16*  vT    = (u16*)(ws + 67108864);     // 32MB   (reused by attnT)
  u16*  Wq_bf = (u16*)(ws + 100663296);
  u16*  Wk_bf = (u16*)(ws + 102760448);
  u16*  Wv_bf = (u16*)(ws + 104857600);
  u16*  Wo_bf = (u16*)(ws + 106954752);
  u16*  projT = (u16*)(ws + 109051904);    // projkT [128][2048], projvT right after
  float* sk   = (float*)(ws + 110100480);  // [128] colsum(proj_k); sv right after
  float* sv   = (float*)(ws + 110100992);
  u16*  qp    = (u16*)(ws + 110101504);    // 32MB [16384,1024]
  u16*  ck    = (u16*)(ws + 143655936);    // [2][8][128][1024] (ck then cv)
  u16*  pk    = (u16*)(ws + 147850240);    // [8][128][1024], pre-scaled by 1/8
  u16*  pvT   = (u16*)(ws + 149947392);    // [8][1024][128]
  u16*  attnT = (u16*)(ws + 33554432);     // [128][2048][128] overlay kT+vT
  u16*  outh  = (u16*)(ws + 0);            // [16384,1024] overlay q_bf
  u16*  scores = (u16*)d_out;              // [128][128][2048] bf16 in d_out (rewritten later)

  k_zero<<<1, 256, 0, stream>>>(sk, 256);                 // sk+sv contiguous

  // converts / transposes
  k_f2bf<<<2048, 256, 0, stream>>>(q,  q_bf, 2097152);
  k_f2bf<<<512,  256, 0, stream>>>(Wq, Wq_bf, 131072);
  k_f2bf<<<512,  256, 0, stream>>>(Wk, Wk_bf, 131072);
  k_f2bf<<<512,  256, 0, stream>>>(Wv, Wv_bf, 131072);
  k_f2bf<<<512,  256, 0, stream>>>(Wo, Wo_bf, 131072);
  k_tconv<<<dim3(16,32,8), 256, 0, stream>>>(k, kT, 2048, 1024, 2097152, 2097152, nullptr);
  k_tconv<<<dim3(16,32,8), 256, 0, stream>>>(v, vT, 2048, 1024, 2097152, 2097152, nullptr);
  k_tconv<<<dim3(2,32,1),  256, 0, stream>>>(pjk, projT,          2048, 128, 0, 0, sk);
  k_tconv<<<dim3(2,32,1),  256, 0, stream>>>(pjv, projT + 262144, 2048, 128, 0, 0, sv);

  // qp = q @ Wq^T + bq                       [16384,1024]
  k_gemm<128,128,0,1,u16><<<dim3(8,128,1), 256, 0, stream>>>(
      q_bf,1024,0, Wq_bf,1024,0, qp,1024,0, 1024, bq, nullptr, 1.f);
  // ck = projkT @ k^T ; cv = projvT @ v^T    (z: 0..7 k-batches, 8..15 v-batches)
  k_gemm<128,128,3,0,u16><<<dim3(8,1,16), 256, 0, stream>>>(
      projT,2048,0, kT,2048,0, ck,1024,0, 2048, nullptr, nullptr, 1.f);
  // pk = (ck @ Wk^T + sk (x) bk) / 8
  k_gemm<128,128,0,2,u16><<<dim3(8,1,8), 256, 0, stream>>>(
      ck,1024,131072, Wk_bf,1024,0, pk,1024,131072, 1024, bk, sk, 0.125f);
  // pvT = (cv @ Wv^T + sv (x) bv) transposed per batch -> [1024][128]
  k_gemm<128,128,0,3,u16><<<dim3(8,1,8), 256, 0, stream>>>(
      ck + 1048576,1024,131072, Wv_bf,1024,0, pvT,0,131072, 1024, bv, sv, 1.f);
  // scores[z][kr][n] = pk_h @ qp_view^T     (z = b*16+h, K=64)
  k_gemm<128,128,1,0,u16><<<dim3(16,1,128), 256, 0, stream>>>(
      pk,1024,0, qp,64,0, scores,2048,0, 64, nullptr, nullptr, 1.f);
  // softmax over n, write attnT[z][n][kr]
  k_softmax<<<dim3(8,128), 256, 0, stream>>>(scores, attnT);
  // outh[b][n][h*64+d] = attnT @ pvT^T      (K=128)
  k_gemm<128,64,2,0,u16><<<dim3(1,16,128), 256, 0, stream>>>(
      attnT,128,0, pvT,128,0, outh,1024,0, 128, nullptr, nullptr, 1.f);
  // final = outh @ Wo^T + bo -> fp32 d_out
  k_gemm<128,128,0,1,float><<<dim3(8,128,1), 256, 0, stream>>>(
      outh,1024,0, Wo_bf,1024,0, (float*)d_out,1024,0, 1024, bo, nullptr, 1.f);
}

// Round 2
// 344.985 us; speedup vs baseline: 1.0987x; 1.0987x over previous
//
#include <hip/hip_runtime.h>

typedef unsigned short u16;
typedef unsigned int   u32;
typedef __attribute__((ext_vector_type(4))) float fx4;
typedef __attribute__((ext_vector_type(8))) __bf16 bf16x8;
typedef __attribute__((ext_vector_type(8))) unsigned short us8;
typedef __attribute__((ext_vector_type(2))) unsigned int u32x2;

__device__ __forceinline__ u16 f2bf(float x){
  u32 u = __builtin_bit_cast(u32, x);
  u += 0x7fffu + ((u >> 16) & 1u);
  return (u16)(u >> 16);
}
__device__ __forceinline__ float b2f(u16 h){
  u32 u = ((u32)h) << 16;
  return __builtin_bit_cast(float, u);
}
__device__ __forceinline__ void gld16(const void* g, void* l){
  __builtin_amdgcn_global_load_lds(
      (const __attribute__((address_space(1))) u32*)g,
      (__attribute__((address_space(3))) u32*)l, 16, 0, 0);
}

// ---------------- fp32 -> bf16 convert (vectorized, grid-stride) ----------------
__global__ __launch_bounds__(256) void k_f2bf(const float* __restrict__ in,
                                              u16* __restrict__ out, int n8){
  int i = blockIdx.x * 256 + threadIdx.x;
  const int stride = gridDim.x * 256;
  for (; i < n8; i += stride){
    const float4* p = (const float4*)in + (long)i * 2;
    float4 a = p[0], b = p[1];
    us8 o = { f2bf(a.x), f2bf(a.y), f2bf(a.z), f2bf(a.w),
              f2bf(b.x), f2bf(b.y), f2bf(b.z), f2bf(b.w) };
    *((us8*)out + i) = o;
  }
}

__global__ void k_zero(float* p, int n){
  int i = blockIdx.x * 256 + threadIdx.x;
  if (i < n) p[i] = 0.f;
}

// ---------------- transpose + convert: in [R,C] f32 -> out [C,R] bf16 ----------------
__global__ __launch_bounds__(256) void k_tconv(const float* __restrict__ in,
                                               u16* __restrict__ out,
                                               int R, int C, long sIn, long sOut,
                                               float* __restrict__ colsum){
  in  += (long)blockIdx.z * sIn;
  out += (long)blockIdx.z * sOut;
  const int c0 = blockIdx.x * 64, r0 = blockIdx.y * 64;
  __shared__ u16 tile[64][72];
  __shared__ float red[256];
  const int t = threadIdx.x;
  const int cc = t & 63, wq = t >> 6;
  float part = 0.f;
  #pragma unroll
  for (int i = 0; i < 16; ++i){
    int rr = i * 4 + wq;
    float v = in[(long)(r0 + rr) * C + c0 + cc];
    tile[rr][cc] = f2bf(v);
    part += v;
  }
  if (colsum){
    red[t] = part;
    __syncthreads();
    if (t < 64){
      float s = red[t] + red[t + 64] + red[t + 128] + red[t + 192];
      atomicAdd(&colsum[c0 + t], s);
    }
  }
  __syncthreads();
  #pragma unroll
  for (int i = 0; i < 16; ++i){
    int oc = i * 4 + wq;
    out[(long)(c0 + oc) * R + r0 + cc] = tile[cc][oc];
  }
}

// ---------------- BT-layout MFMA GEMM: C[M,N] = A[M,K] * B[N,K]^T ----------------
// MODE 0: z-batch via strides.  MODE 3: ck/cv combined (proj x kT/vT).
// EPI 0: none. 1: +bias[col]. 2: (v + srow[row]*bias[col])*scale.
// EPI 3: v + srow[row]*bias[col], write transposed (pvT[col][row]).
template<int BM, int BN, int MODE, int EPI, typename OutT>
__global__ __launch_bounds__(256) void k_gemm(
    const u16* __restrict__ A, int lda, long sAz,
    const u16* __restrict__ B, int ldb, long sBz,
    OutT* __restrict__ C, int ldc, long sCz,
    int K, const float* __restrict__ bias, const float* __restrict__ srow, float scale)
{
  constexpr int BK = 64;
  constexpr int FM = BM / 32, FN = BN / 32;
  __shared__ u16 ldsA[BM * BK];
  __shared__ u16 ldsB[BN * BK];
  const long z = blockIdx.z;
  if constexpr (MODE == 0){ A += z * sAz; B += z * sBz; C += z * sCz; }
  if constexpr (MODE == 3){ long p = z >> 3, bb = z & 7;
                            A += p * 262144; B += p * 16777216 + bb * 2097152;
                            C += p * 1048576 + bb * 131072; }
  const int t = threadIdx.x;
  const int lane = t & 63;
  const int w = t >> 6, wm = w >> 1, wn = w & 1;
  const int r15 = lane & 15, g = lane >> 4;
  const int m0 = blockIdx.y * BM, n0 = blockIdx.x * BN;
  fx4 acc[FM][FN] = {};
  constexpr int CA = BM * BK / (8 * 256);
  constexpr int CB = BN * BK / (8 * 256);
  for (int kt = 0; kt < K; kt += BK){
    #pragma unroll
    for (int i = 0; i < CA; ++i){
      int ch = i * 256 + t, row = ch >> 3, cc = ch & 7;
      gld16(A + (long)(m0 + row) * lda + kt + cc * 8, (char*)ldsA + ch * 16);
    }
    #pragma unroll
    for (int i = 0; i < CB; ++i){
      int ch = i * 256 + t, row = ch >> 3, cc = ch & 7;
      gld16(B + (long)(n0 + row) * ldb + kt + cc * 8, (char*)ldsB + ch * 16);
    }
    __syncthreads();
    #pragma unroll
    for (int ks = 0; ks < 2; ++ks){
      bf16x8 af[FM], bfv[FN];
      #pragma unroll
      for (int mf = 0; mf < FM; ++mf)
        af[mf] = *(const bf16x8*)&ldsA[(wm * (BM/2) + mf * 16 + r15) * BK + ks * 32 + g * 8];
      #pragma unroll
      for (int nf = 0; nf < FN; ++nf)
        bfv[nf] = *(const bf16x8*)&ldsB[(wn * (BN/2) + nf * 16 + r15) * BK + ks * 32 + g * 8];
      #pragma unroll
      for (int mf = 0; mf < FM; ++mf)
        #pragma unroll
        for (int nf = 0; nf < FN; ++nf)
          acc[mf][nf] = __builtin_amdgcn_mfma_f32_16x16x32_bf16(af[mf], bfv[nf], acc[mf][nf], 0, 0, 0);
    }
    __syncthreads();
  }
  #pragma unroll
  for (int mf = 0; mf < FM; ++mf){
    #pragma unroll
    for (int nf = 0; nf < FN; ++nf){
      const int row0 = m0 + wm * (BM/2) + mf * 16 + g * 4;
      const int col  = n0 + wn * (BN/2) + nf * 16 + r15;
      float vv[4];
      #pragma unroll
      for (int r = 0; r < 4; ++r){
        float v = acc[mf][nf][r];
        if constexpr (EPI == 1) v += bias[col];
        if constexpr (EPI == 2) v = (v + srow[row0 + r] * bias[col]) * scale;
        if constexpr (EPI == 3) v = v + srow[row0 + r] * bias[col];
        vv[r] = v;
      }
      if constexpr (EPI == 3){
        u32 lo = (u32)f2bf(vv[0]) | ((u32)f2bf(vv[1]) << 16);
        u32 hi = (u32)f2bf(vv[2]) | ((u32)f2bf(vv[3]) << 16);
        u32x2 pk2 = { lo, hi };
        *(u32x2*)((u16*)C + (long)col * 128 + row0) = pk2;
      } else {
        #pragma unroll
        for (int r = 0; r < 4; ++r){
          if constexpr (sizeof(OutT) == 2) C[(long)(row0 + r) * ldc + col] = (OutT)f2bf(vv[r]);
          else                             C[(long)(row0 + r) * ldc + col] = (OutT)vv[r];
        }
      }
    }
  }
}

// ---------------- fused attention, pass 1: Z[k] = sum_n exp(s[k,n]) ----------------
// s[k,n] = sum_d pk_h[k,d] * qp_h[n,d]   (pk pre-scaled by 1/8)
// one block per (b,h); 8 waves, each covers 256 n in 8 chunks of 32.
__global__ __launch_bounds__(512) void k_stats(const u16* __restrict__ pk,
                                               const u16* __restrict__ qp,
                                               float* __restrict__ invZ){
  const int z = blockIdx.x;
  const int b = z >> 4, h = z & 15;
  const u16* pkh = pk + b * 131072 + h * 64;   // [128][.], row stride 1024
  const u16* qph = qp + (long)z * 131072;      // [2048][64]
  __shared__ u16 pkL[128 * 64];
  __shared__ float zred[8][128];
  const int t = threadIdx.x, lane = t & 63, w = t >> 6;
  const int r15 = lane & 15, g = lane >> 4;
  // stage pk: linear LDS dest, pre-swizzled global source (reader XORs col16 with row&7)
  #pragma unroll
  for (int i = 0; i < 2; ++i){
    int ch = i * 512 + t, row = ch >> 3, cc = ch & 7;
    int csrc = cc ^ (row & 7);
    gld16(pkh + (long)row * 1024 + csrc * 8, (char*)pkL + ch * 16);
  }
  __syncthreads();
  float zacc[8][4] = {};
  for (int c = 0; c < 8; ++c){
    const int n0 = w * 256 + c * 32;
    fx4 acc[8][2] = {};
    #pragma unroll
    for (int ks = 0; ks < 2; ++ks){
      bf16x8 bq[2];
      #pragma unroll
      for (int nf = 0; nf < 2; ++nf)
        bq[nf] = *(const bf16x8*)(qph + (long)(n0 + nf * 16 + r15) * 64 + ks * 32 + g * 8);
      #pragma unroll
      for (int mf = 0; mf < 8; ++mf){
        int row = mf * 16 + r15;
        int x = (ks * 4 + g) ^ (row & 7);
        bf16x8 a = *(const bf16x8*)((const char*)pkL + row * 128 + x * 16);
        #pragma unroll
        for (int nf = 0; nf < 2; ++nf)
          acc[mf][nf] = __builtin_amdgcn_mfma_f32_16x16x32_bf16(a, bq[nf], acc[mf][nf], 0, 0, 0);
      }
    }
    #pragma unroll
    for (int mf = 0; mf < 8; ++mf)
      #pragma unroll
      for (int nf = 0; nf < 2; ++nf)
        #pragma unroll
        for (int r = 0; r < 4; ++r)
          zacc[mf][r] += __expf(acc[mf][nf][r]);
  }
  // reduce over the 16 r15-lanes (cols), then across waves
  #pragma unroll
  for (int mf = 0; mf < 8; ++mf)
    #pragma unroll
    for (int r = 0; r < 4; ++r){
      float v = zacc[mf][r];
      v += __shfl_xor(v, 1); v += __shfl_xor(v, 2);
      v += __shfl_xor(v, 4); v += __shfl_xor(v, 8);
      zacc[mf][r] = v;
    }
  if (r15 == 0){
    #pragma unroll
    for (int mf = 0; mf < 8; ++mf)
      #pragma unroll
      for (int r = 0; r < 4; ++r)
        zred[w][mf * 16 + g * 4 + r] = zacc[mf][r];
  }
  __syncthreads();
  if (t < 128){
    float s = 0.f;
    #pragma unroll
    for (int w2 = 0; w2 < 8; ++w2) s += zred[w2][t];
    invZ[(long)z * 128 + t] = 1.0f / s;
  }
}

// ---------------- fused attention, pass 2: out = attn^T @ pv ----------------
// per block: (b,h) x 128-n tile; wave w owns 32 n rows.
// S-MFMA (identical operands to k_stats) -> p=exp(s)*invZ[k] -> bf16 -> per-wave
// transposed LDS tile pT[32][132] -> PV-MFMA with pvT as B -> outh.
__global__ __launch_bounds__(256) void k_attn(const u16* __restrict__ pk,
                                              const u16* __restrict__ qp,
                                              const u16* __restrict__ pvT,
                                              const float* __restrict__ invZ,
                                              u16* __restrict__ outh){
  const int z = blockIdx.y, nb = blockIdx.x;
  const int b = z >> 4, h = z & 15;
  const u16* pkh = pk  + b * 131072 + h * 64;     // [128][.], stride 1024
  const u16* qph = qp  + (long)z * 131072;        // [2048][64]
  const u16* pvh = pvT + b * 131072 + h * 8192;   // [64][128]
  const float* zh = invZ + (long)z * 128;
  __shared__ u16 pkL[128 * 64];
  __shared__ u16 ptL[4][32 * 132];
  __shared__ float zL[128];
  const int t = threadIdx.x, lane = t & 63, w = t >> 6;
  const int r15 = lane & 15, g = lane >> 4;
  #pragma unroll
  for (int i = 0; i < 4; ++i){
    int ch = i * 256 + t, row = ch >> 3, cc = ch & 7;
    int csrc = cc ^ (row & 7);
    gld16(pkh + (long)row * 1024 + csrc * 8, (char*)pkL + ch * 16);
  }
  if (t < 128) zL[t] = zh[t];
  __syncthreads();
  const int n0 = nb * 128 + w * 32;
  // S = pk @ q^T : rows k = mf*16+g*4+r, cols n = n0 + nf*16 + r15
  fx4 acc[8][2] = {};
  #pragma unroll
  for (int ks = 0; ks < 2; ++ks){
    bf16x8 bq[2];
    #pragma unroll
    for (int nf = 0; nf < 2; ++nf)
      bq[nf] = *(const bf16x8*)(qph + (long)(n0 + nf * 16 + r15) * 64 + ks * 32 + g * 8);
    #pragma unroll
    for (int mf = 0; mf < 8; ++mf){
      int row = mf * 16 + r15;
      int x = (ks * 4 + g) ^ (row & 7);
      bf16x8 a = *(const bf16x8*)((const char*)pkL + row * 128 + x * 16);
      #pragma unroll
      for (int nf = 0; nf < 2; ++nf)
        acc[mf][nf] = __builtin_amdgcn_mfma_f32_16x16x32_bf16(a, bq[nf], acc[mf][nf], 0, 0, 0);
    }
  }
  // p = exp(s) * invZ[k], packed b64 transposed write into per-wave pT[n_local][k]
  u16* pt = ptL[w];
  #pragma unroll
  for (int mf = 0; mf < 8; ++mf){
    const int kb = mf * 16 + g * 4;
    const float z0 = zL[kb], z1 = zL[kb + 1], z2 = zL[kb + 2], z3 = zL[kb + 3];
    #pragma unroll
    for (int nf = 0; nf < 2; ++nf){
      const int nl = nf * 16 + r15;
      u32 lo = (u32)f2bf(__expf(acc[mf][nf][0]) * z0) |
               ((u32)f2bf(__expf(acc[mf][nf][1]) * z1) << 16);
      u32 hi = (u32)f2bf(__expf(acc[mf][nf][2]) * z2) |
               ((u32)f2bf(__expf(acc[mf][nf][3]) * z3) << 16);
      u32x2 pkd = { lo, hi };
      *(u32x2*)(pt + nl * 132 + kb) = pkd;
    }
  }
  // PV: out[n,d] = sum_k pT[n][k] * pvT[d][k]   (per-wave private pT, no barrier)
  fx4 o[2][4] = {};
  #pragma unroll
  for (int ks = 0; ks < 4; ++ks){
    bf16x8 bv[4];
    #pragma unroll
    for (int nf = 0; nf < 4; ++nf)
      bv[nf] = *(const bf16x8*)(pvh + (long)(nf * 16 + r15) * 128 + ks * 32 + g * 8);
    #pragma unroll
    for (int mf = 0; mf < 2; ++mf){
      bf16x8 pa = *(const bf16x8*)(pt + (mf * 16 + r15) * 132 + ks * 32 + g * 8);
      #pragma unroll
      for (int nf = 0; nf < 4; ++nf)
        o[mf][nf] = __builtin_amdgcn_mfma_f32_16x16x32_bf16(pa, bv[nf], o[mf][nf], 0, 0, 0);
    }
  }
  u16* og = outh + ((long)b * 2048 + n0) * 1024 + h * 64;
  #pragma unroll
  for (int mf = 0; mf < 2; ++mf)
    #pragma unroll
    for (int nf = 0; nf < 4; ++nf)
      #pragma unroll
      for (int r = 0; r < 4; ++r){
        int nl = mf * 16 + g * 4 + r;
        og[(long)nl * 1024 + nf * 16 + r15] = f2bf(o[mf][nf][r]);
      }
}

extern "C" void kernel_launch(void* const* d_in, const int* in_sizes, int n_in,
                              void* d_out, int out_size, void* d_ws, size_t ws_size,
                              hipStream_t stream)
{
  const float* q   = (const float*)d_in[0];
  const float* k   = (const float*)d_in[1];
  const float* v   = (const float*)d_in[2];
  const float* Wq  = (const float*)d_in[3];
  const float* bq  = (const float*)d_in[4];
  const float* Wk  = (const float*)d_in[5];
  const float* bk  = (const float*)d_in[6];
  const float* Wv  = (const float*)d_in[7];
  const float* bv  = (const float*)d_in[8];
  const float* pjk = (const float*)d_in[9];
  const float* pjv = (const float*)d_in[10];
  const float* Wo  = (const float*)d_in[11];
  const float* bo  = (const float*)d_in[12];

  if (ws_size < 152044544u) return;

  char* ws = (char*)d_ws;
  u16*  q_bf  = (u16*)(ws + 0);            // 32MB (reused by outh)
  u16*  kT    = (u16*)(ws + 33554432);     // 32MB (reused by invZ)
  u16*  vT    = (u16*)(ws + 67108864);     // 32MB
  u16*  Wq_bf = (u16*)(ws + 100663296);
  u16*  Wk_bf = (u16*)(ws + 102760448);
  u16*  Wv_bf = (u16*)(ws + 104857600);
  u16*  Wo_bf = (u16*)(ws + 106954752);
  u16*  projT = (u16*)(ws + 109051904);    // projkT [128][2048], projvT after
  float* sk   = (float*)(ws + 110100480);
  float* sv   = (float*)(ws + 110100992);
  u16*  qp    = (u16*)(ws + 110101504);    // 32MB [16384,1024]
  u16*  ck    = (u16*)(ws + 143655936);    // [2][8][128][1024]
  u16*  pk    = (u16*)(ws + 147850240);    // [8][128][1024], pre-scaled 1/8
  u16*  pvT   = (u16*)(ws + 149947392);    // [8][16][64][128]
  float* invZ = (float*)(ws + 33554432);   // [128][128] overlay kT (free after ck GEMM)
  u16*  outh  = (u16*)(ws + 0);            // [16384,1024] overlay q_bf

  k_zero<<<1, 256, 0, stream>>>(sk, 256);

  k_f2bf<<<2048, 256, 0, stream>>>(q,  q_bf, 2097152);
  k_f2bf<<<512,  256, 0, stream>>>(Wq, Wq_bf, 131072);
  k_f2bf<<<512,  256, 0, stream>>>(Wk, Wk_bf, 131072);
  k_f2bf<<<512,  256, 0, stream>>>(Wv, Wv_bf, 131072);
  k_f2bf<<<512,  256, 0, stream>>>(Wo, Wo_bf, 131072);
  k_tconv<<<dim3(16,32,8), 256, 0, stream>>>(k, kT, 2048, 1024, 2097152, 2097152, nullptr);
  k_tconv<<<dim3(16,32,8), 256, 0, stream>>>(v, vT, 2048, 1024, 2097152, 2097152, nullptr);
  k_tconv<<<dim3(2,32,1),  256, 0, stream>>>(pjk, projT,          2048, 128, 0, 0, sk);
  k_tconv<<<dim3(2,32,1),  256, 0, stream>>>(pjv, projT + 262144, 2048, 128, 0, 0, sv);

  // qp = q @ Wq^T + bq
  k_gemm<128,128,0,1,u16><<<dim3(8,128,1), 256, 0, stream>>>(
      q_bf,1024,0, Wq_bf,1024,0, qp,1024,0, 1024, bq, nullptr, 1.f);
  // ck = projkT @ k^T ; cv = projvT @ v^T
  k_gemm<128,128,3,0,u16><<<dim3(8,1,16), 256, 0, stream>>>(
      projT,2048,0, kT,2048,0, ck,1024,0, 2048, nullptr, nullptr, 1.f);
  // pk = (ck @ Wk^T + sk (x) bk) / 8
  k_gemm<128,128,0,2,u16><<<dim3(8,1,8), 256, 0, stream>>>(
      ck,1024,131072, Wk_bf,1024,0, pk,1024,131072, 1024, bk, sk, 0.125f);
  // pvT = (cv @ Wv^T + sv (x) bv), transposed write -> [64 d][128 kr] per (b,h)
  k_gemm<128,128,0,3,u16><<<dim3(8,1,8), 256, 0, stream>>>(
      ck + 1048576,1024,131072, Wv_bf,1024,0, pvT,0,131072, 1024, bv, sv, 1.f);
  // fused attention (never materializes scores in HBM)
  k_stats<<<128, 512, 0, stream>>>(pk, qp, invZ);
  k_attn<<<dim3(16,128), 256, 0, stream>>>(pk, qp, pvT, invZ, outh);
  // final = outh @ Wo^T + bo -> fp32 d_out
  k_gemm<128,128,0,1,float><<<dim3(8,128,1), 256, 0, stream>>>(
      outh,1024,0, Wo_bf,1024,0, (float*)d_out,1024,0, 1024, bo, nullptr, 1.f);
}

// Round 3
// 335.719 us; speedup vs baseline: 1.1290x; 1.0276x over previous
//
#include <hip/hip_runtime.h>

typedef unsigned short u16;
typedef unsigned int   u32;
typedef __attribute__((ext_vector_type(4))) float fx4;
typedef __attribute__((ext_vector_type(8))) __bf16 bf16x8;
typedef __attribute__((ext_vector_type(8))) unsigned short us8;
typedef __attribute__((ext_vector_type(2))) unsigned int u32x2;

__device__ __forceinline__ u16 f2bf(float x){
  u32 u = __builtin_bit_cast(u32, x);
  u += 0x7fffu + ((u >> 16) & 1u);
  return (u16)(u >> 16);
}
__device__ __forceinline__ float b2f(u16 h){
  u32 u = ((u32)h) << 16;
  return __builtin_bit_cast(float, u);
}
__device__ __forceinline__ void gld16(const void* g, void* l){
  __builtin_amdgcn_global_load_lds(
      (const __attribute__((address_space(1))) u32*)g,
      (__attribute__((address_space(3))) u32*)l, 16, 0, 0);
}
// XCD-chunked bijective swizzle (grid size must be %8==0): blocks that share an
// operand panel (consecutive logical ids) land on the same XCD's L2.
__device__ __forceinline__ void xcd_remap(u32& bx, u32& by, u32& bz){
  u32 nx = gridDim.x, ny = gridDim.y, nz = gridDim.z;
  u32 nwg = nx * ny * nz;
  u32 orig = (blockIdx.z * ny + blockIdx.y) * nx + blockIdx.x;
  u32 lid = (orig & 7u) * (nwg >> 3) + (orig >> 3);
  bx = lid % nx;
  u32 rem = lid / nx;
  by = rem % ny;
  bz = rem / ny;
}

// ---------------- fp32 -> bf16 convert (vectorized, grid-stride) ----------------
__global__ __launch_bounds__(256) void k_f2bf(const float* __restrict__ in,
                                              u16* __restrict__ out, int n8){
  int i = blockIdx.x * 256 + threadIdx.x;
  const int stride = gridDim.x * 256;
  for (; i < n8; i += stride){
    const float4* p = (const float4*)in + (long)i * 2;
    float4 a = p[0], b = p[1];
    us8 o = { f2bf(a.x), f2bf(a.y), f2bf(a.z), f2bf(a.w),
              f2bf(b.x), f2bf(b.y), f2bf(b.z), f2bf(b.w) };
    *((us8*)out + i) = o;
  }
}

__global__ void k_zero(float* p, int n){
  int i = blockIdx.x * 256 + threadIdx.x;
  if (i < n) p[i] = 0.f;
}

// ---------------- transpose + convert: in [R,C] f32 -> out [C,R] bf16 ----------------
// write phase packs 2 u16 per lane (4B stores, 128B contiguous per half-wave).
__global__ __launch_bounds__(256) void k_tconv(const float* __restrict__ in,
                                               u16* __restrict__ out,
                                               int R, int C, long sIn, long sOut,
                                               float* __restrict__ colsum){
  in  += (long)blockIdx.z * sIn;
  out += (long)blockIdx.z * sOut;
  const int c0 = blockIdx.x * 64, r0 = blockIdx.y * 64;
  __shared__ u16 tile[64][66];
  __shared__ float red[256];
  const int t = threadIdx.x;
  const int cc = t & 63, wq = t >> 6;
  float part = 0.f;
  #pragma unroll
  for (int i = 0; i < 16; ++i){
    int rr = i * 4 + wq;
    float v = in[(long)(r0 + rr) * C + c0 + cc];
    tile[rr][cc] = f2bf(v);
    part += v;
  }
  if (colsum){
    red[t] = part;
    __syncthreads();
    if (t < 64){
      float s = red[t] + red[t + 64] + red[t + 128] + red[t + 192];
      atomicAdd(&colsum[c0 + t], s);
    }
  }
  __syncthreads();
  const int oc0 = t >> 5, jb = (t & 31) * 2;
  #pragma unroll
  for (int i = 0; i < 8; ++i){
    int oc = oc0 + i * 8;
    u32 pk2 = (u32)tile[jb][oc] | ((u32)tile[jb + 1][oc] << 16);
    *(u32*)(out + (long)(c0 + oc) * R + r0 + jb) = pk2;
  }
}

// ---------------- BT-layout MFMA GEMM: C[M,N] = A[M,K] * B[N,K]^T ----------------
// MODE 0: z-batch via strides.  MODE 3: ck/cv combined (proj x kT/vT).
// EPI 0: none. 1: +bias[col]. 2: (v + srow[row]*bias[col])*scale.
// EPI 3: v + srow[row]*bias[col], write transposed (pvT[col][row]).
template<int BM, int BN, int MODE, int EPI, typename OutT>
__global__ __launch_bounds__(256) void k_gemm(
    const u16* __restrict__ A, int lda, long sAz,
    const u16* __restrict__ B, int ldb, long sBz,
    OutT* __restrict__ C, int ldc, long sCz,
    int K, const float* __restrict__ bias, const float* __restrict__ srow, float scale)
{
  constexpr int BK = 64;
  constexpr int FM = BM / 32, FN = BN / 32;
  __shared__ u16 ldsA[BM * BK];
  __shared__ u16 ldsB[BN * BK];
  u32 bx, by, bz;
  xcd_remap(bx, by, bz);
  const long z = bz;
  if constexpr (MODE == 0){ A += z * sAz; B += z * sBz; C += z * sCz; }
  if constexpr (MODE == 3){ long p = z >> 3, bb = z & 7;
                            A += p * 262144; B += p * 16777216 + bb * 2097152;
                            C += p * 1048576 + bb * 131072; }
  const int t = threadIdx.x;
  const int lane = t & 63;
  const int w = t >> 6, wm = w >> 1, wn = w & 1;
  const int r15 = lane & 15, g = lane >> 4;
  const int m0 = by * BM, n0 = bx * BN;
  fx4 acc[FM][FN] = {};
  constexpr int CA = BM * BK / (8 * 256);
  constexpr int CB = BN * BK / (8 * 256);
  for (int kt = 0; kt < K; kt += BK){
    #pragma unroll
    for (int i = 0; i < CA; ++i){
      int ch = i * 256 + t, row = ch >> 3, cc = ch & 7;
      gld16(A + (long)(m0 + row) * lda + kt + cc * 8, (char*)ldsA + ch * 16);
    }
    #pragma unroll
    for (int i = 0; i < CB; ++i){
      int ch = i * 256 + t, row = ch >> 3, cc = ch & 7;
      gld16(B + (long)(n0 + row) * ldb + kt + cc * 8, (char*)ldsB + ch * 16);
    }
    __syncthreads();
    #pragma unroll
    for (int ks = 0; ks < 2; ++ks){
      bf16x8 af[FM], bfv[FN];
      #pragma unroll
      for (int mf = 0; mf < FM; ++mf)
        af[mf] = *(const bf16x8*)&ldsA[(wm * (BM/2) + mf * 16 + r15) * BK + ks * 32 + g * 8];
      #pragma unroll
      for (int nf = 0; nf < FN; ++nf)
        bfv[nf] = *(const bf16x8*)&ldsB[(wn * (BN/2) + nf * 16 + r15) * BK + ks * 32 + g * 8];
      #pragma unroll
      for (int mf = 0; mf < FM; ++mf)
        #pragma unroll
        for (int nf = 0; nf < FN; ++nf)
          acc[mf][nf] = __builtin_amdgcn_mfma_f32_16x16x32_bf16(af[mf], bfv[nf], acc[mf][nf], 0, 0, 0);
    }
    __syncthreads();
  }
  #pragma unroll
  for (int mf = 0; mf < FM; ++mf){
    #pragma unroll
    for (int nf = 0; nf < FN; ++nf){
      const int row0 = m0 + wm * (BM/2) + mf * 16 + g * 4;
      const int col  = n0 + wn * (BN/2) + nf * 16 + r15;
      float vv[4];
      #pragma unroll
      for (int r = 0; r < 4; ++r){
        float v = acc[mf][nf][r];
        if constexpr (EPI == 1) v += bias[col];
        if constexpr (EPI == 2) v = (v + srow[row0 + r] * bias[col]) * scale;
        if constexpr (EPI == 3) v = v + srow[row0 + r] * bias[col];
        vv[r] = v;
      }
      if constexpr (EPI == 3){
        u32 lo = (u32)f2bf(vv[0]) | ((u32)f2bf(vv[1]) << 16);
        u32 hi = (u32)f2bf(vv[2]) | ((u32)f2bf(vv[3]) << 16);
        u32x2 pk2 = { lo, hi };
        *(u32x2*)((u16*)C + (long)col * 128 + row0) = pk2;
      } else {
        #pragma unroll
        for (int r = 0; r < 4; ++r){
          if constexpr (sizeof(OutT) == 2) C[(long)(row0 + r) * ldc + col] = (OutT)f2bf(vv[r]);
          else                             C[(long)(row0 + r) * ldc + col] = (OutT)vv[r];
        }
      }
    }
  }
}

// ---------------- fused attention, pass 1: Z[k] = sum_n exp(s[k,n]) ----------------
__global__ __launch_bounds__(512) void k_stats(const u16* __restrict__ pk,
                                               const u16* __restrict__ qp,
                                               float* __restrict__ invZ){
  const int z = blockIdx.x;
  const int b = z >> 4, h = z & 15;
  const u16* pkh = pk + b * 131072 + h * 64;   // [128][.], row stride 1024
  const u16* qph = qp + (long)z * 131072;      // [2048][64]
  __shared__ u16 pkL[128 * 64];
  __shared__ float zred[8][128];
  const int t = threadIdx.x, lane = t & 63, w = t >> 6;
  const int r15 = lane & 15, g = lane >> 4;
  #pragma unroll
  for (int i = 0; i < 2; ++i){
    int ch = i * 512 + t, row = ch >> 3, cc = ch & 7;
    int csrc = cc ^ (row & 7);
    gld16(pkh + (long)row * 1024 + csrc * 8, (char*)pkL + ch * 16);
  }
  __syncthreads();
  float zacc[8][4] = {};
  for (int c = 0; c < 8; ++c){
    const int n0 = w * 256 + c * 32;
    fx4 acc[8][2] = {};
    #pragma unroll
    for (int ks = 0; ks < 2; ++ks){
      bf16x8 bq[2];
      #pragma unroll
      for (int nf = 0; nf < 2; ++nf)
        bq[nf] = *(const bf16x8*)(qph + (long)(n0 + nf * 16 + r15) * 64 + ks * 32 + g * 8);
      #pragma unroll
      for (int mf = 0; mf < 8; ++mf){
        int row = mf * 16 + r15;
        int x = (ks * 4 + g) ^ (row & 7);
        bf16x8 a = *(const bf16x8*)((const char*)pkL + row * 128 + x * 16);
        #pragma unroll
        for (int nf = 0; nf < 2; ++nf)
          acc[mf][nf] = __builtin_amdgcn_mfma_f32_16x16x32_bf16(a, bq[nf], acc[mf][nf], 0, 0, 0);
      }
    }
    #pragma unroll
    for (int mf = 0; mf < 8; ++mf)
      #pragma unroll
      for (int nf = 0; nf < 2; ++nf)
        #pragma unroll
        for (int r = 0; r < 4; ++r)
          zacc[mf][r] += __expf(acc[mf][nf][r]);
  }
  #pragma unroll
  for (int mf = 0; mf < 8; ++mf)
    #pragma unroll
    for (int r = 0; r < 4; ++r){
      float v = zacc[mf][r];
      v += __shfl_xor(v, 1); v += __shfl_xor(v, 2);
      v += __shfl_xor(v, 4); v += __shfl_xor(v, 8);
      zacc[mf][r] = v;
    }
  if (r15 == 0){
    #pragma unroll
    for (int mf = 0; mf < 8; ++mf)
      #pragma unroll
      for (int r = 0; r < 4; ++r)
        zred[w][mf * 16 + g * 4 + r] = zacc[mf][r];
  }
  __syncthreads();
  if (t < 128){
    float s = 0.f;
    #pragma unroll
    for (int w2 = 0; w2 < 8; ++w2) s += zred[w2][t];
    invZ[(long)z * 128 + t] = 1.0f / s;
  }
}

// ---------------- fused attention, pass 2: out = attn^T @ pv ----------------
__global__ __launch_bounds__(256) void k_attn(const u16* __restrict__ pk,
                                              const u16* __restrict__ qp,
                                              const u16* __restrict__ pvT,
                                              const float* __restrict__ invZ,
                                              u16* __restrict__ outh){
  u32 bx, by, bz;
  xcd_remap(bx, by, bz);
  const int z = by, nb = bx;
  const int b = z >> 4, h = z & 15;
  const u16* pkh = pk  + b * 131072 + h * 64;     // [128][.], stride 1024
  const u16* qph = qp  + (long)z * 131072;        // [2048][64]
  const u16* pvh = pvT + b * 131072 + h * 8192;   // [64][128]
  const float* zh = invZ + (long)z * 128;
  __shared__ u16 pkL[128 * 64];
  __shared__ u16 ptL[4][32 * 132];
  __shared__ float zL[128];
  const int t = threadIdx.x, lane = t & 63, w = t >> 6;
  const int r15 = lane & 15, g = lane >> 4;
  #pragma unroll
  for (int i = 0; i < 4; ++i){
    int ch = i * 256 + t, row = ch >> 3, cc = ch & 7;
    int csrc = cc ^ (row & 7);
    gld16(pkh + (long)row * 1024 + csrc * 8, (char*)pkL + ch * 16);
  }
  if (t < 128) zL[t] = zh[t];
  __syncthreads();
  const int n0 = nb * 128 + w * 32;
  fx4 acc[8][2] = {};
  #pragma unroll
  for (int ks = 0; ks < 2; ++ks){
    bf16x8 bq[2];
    #pragma unroll
    for (int nf = 0; nf < 2; ++nf)
      bq[nf] = *(const bf16x8*)(qph + (long)(n0 + nf * 16 + r15) * 64 + ks * 32 + g * 8);
    #pragma unroll
    for (int mf = 0; mf < 8; ++mf){
      int row = mf * 16 + r15;
      int x = (ks * 4 + g) ^ (row & 7);
      bf16x8 a = *(const bf16x8*)((const char*)pkL + row * 128 + x * 16);
      #pragma unroll
      for (int nf = 0; nf < 2; ++nf)
        acc[mf][nf] = __builtin_amdgcn_mfma_f32_16x16x32_bf16(a, bq[nf], acc[mf][nf], 0, 0, 0);
    }
  }
  u16* pt = ptL[w];
  #pragma unroll
  for (int mf = 0; mf < 8; ++mf){
    const int kb = mf * 16 + g * 4;
    const float z0 = zL[kb], z1 = zL[kb + 1], z2 = zL[kb + 2], z3 = zL[kb + 3];
    #pragma unroll
    for (int nf = 0; nf < 2; ++nf){
      const int nl = nf * 16 + r15;
      u32 lo = (u32)f2bf(__expf(acc[mf][nf][0]) * z0) |
               ((u32)f2bf(__expf(acc[mf][nf][1]) * z1) << 16);
      u32 hi = (u32)f2bf(__expf(acc[mf][nf][2]) * z2) |
               ((u32)f2bf(__expf(acc[mf][nf][3]) * z3) << 16);
      u32x2 pkd = { lo, hi };
      *(u32x2*)(pt + nl * 132 + kb) = pkd;
    }
  }
  fx4 o[2][4] = {};
  #pragma unroll
  for (int ks = 0; ks < 4; ++ks){
    bf16x8 bv[4];
    #pragma unroll
    for (int nf = 0; nf < 4; ++nf)
      bv[nf] = *(const bf16x8*)(pvh + (long)(nf * 16 + r15) * 128 + ks * 32 + g * 8);
    #pragma unroll
    for (int mf = 0; mf < 2; ++mf){
      bf16x8 pa = *(const bf16x8*)(pt + (mf * 16 + r15) * 132 + ks * 32 + g * 8);
      #pragma unroll
      for (int nf = 0; nf < 4; ++nf)
        o[mf][nf] = __builtin_amdgcn_mfma_f32_16x16x32_bf16(pa, bv[nf], o[mf][nf], 0, 0, 0);
    }
  }
  u16* og = outh + ((long)b * 2048 + n0) * 1024 + h * 64;
  #pragma unroll
  for (int mf = 0; mf < 2; ++mf)
    #pragma unroll
    for (int nf = 0; nf < 4; ++nf)
      #pragma unroll
      for (int r = 0; r < 4; ++r){
        int nl = mf * 16 + g * 4 + r;
        og[(long)nl * 1024 + nf * 16 + r15] = f2bf(o[mf][nf][r]);
      }
}

extern "C" void kernel_launch(void* const* d_in, const int* in_sizes, int n_in,
                              void* d_out, int out_size, void* d_ws, size_t ws_size,
                              hipStream_t stream)
{
  const float* q   = (const float*)d_in[0];
  const float* k   = (const float*)d_in[1];
  const float* v   = (const float*)d_in[2];
  const float* Wq  = (const float*)d_in[3];
  const float* bq  = (const float*)d_in[4];
  const float* Wk  = (const float*)d_in[5];
  const float* bk  = (const float*)d_in[6];
  const float* Wv  = (const float*)d_in[7];
  const float* bv  = (const float*)d_in[8];
  const float* pjk = (const float*)d_in[9];
  const float* pjv = (const float*)d_in[10];
  const float* Wo  = (const float*)d_in[11];
  const float* bo  = (const float*)d_in[12];

  if (ws_size < 152044544u) return;

  char* ws = (char*)d_ws;
  u16*  q_bf  = (u16*)(ws + 0);            // 32MB (reused by outh)
  u16*  kT    = (u16*)(ws + 33554432);     // 32MB (reused by invZ)
  u16*  vT    = (u16*)(ws + 67108864);     // 32MB
  u16*  Wq_bf = (u16*)(ws + 100663296);
  u16*  Wk_bf = (u16*)(ws + 102760448);
  u16*  Wv_bf = (u16*)(ws + 104857600);
  u16*  Wo_bf = (u16*)(ws + 106954752);
  u16*  projT = (u16*)(ws + 109051904);    // projkT [128][2048], projvT after
  float* sk   = (float*)(ws + 110100480);
  float* sv   = (float*)(ws + 110100992);
  u16*  qp    = (u16*)(ws + 110101504);    // 32MB [16384,1024]
  u16*  ck    = (u16*)(ws + 143655936);    // [2][8][128][1024]
  u16*  pk    = (u16*)(ws + 147850240);    // [8][128][1024], pre-scaled 1/8
  u16*  pvT   = (u16*)(ws + 149947392);    // [8][16][64][128]
  float* invZ = (float*)(ws + 33554432);   // [128][128] overlay kT (free after ck GEMM)
  u16*  outh  = (u16*)(ws + 0);            // [16384,1024] overlay q_bf

  k_zero<<<1, 256, 0, stream>>>(sk, 256);

  k_f2bf<<<2048, 256, 0, stream>>>(q,  q_bf, 2097152);
  k_f2bf<<<512,  256, 0, stream>>>(Wq, Wq_bf, 131072);
  k_f2bf<<<512,  256, 0, stream>>>(Wk, Wk_bf, 131072);
  k_f2bf<<<512,  256, 0, stream>>>(Wv, Wv_bf, 131072);
  k_f2bf<<<512,  256, 0, stream>>>(Wo, Wo_bf, 131072);
  k_tconv<<<dim3(16,32,8), 256, 0, stream>>>(k, kT, 2048, 1024, 2097152, 2097152, nullptr);
  k_tconv<<<dim3(16,32,8), 256, 0, stream>>>(v, vT, 2048, 1024, 2097152, 2097152, nullptr);
  k_tconv<<<dim3(2,32,1),  256, 0, stream>>>(pjk, projT,          2048, 128, 0, 0, sk);
  k_tconv<<<dim3(2,32,1),  256, 0, stream>>>(pjv, projT + 262144, 2048, 128, 0, 0, sv);

  // qp = q @ Wq^T + bq
  k_gemm<128,128,0,1,u16><<<dim3(8,128,1), 256, 0, stream>>>(
      q_bf,1024,0, Wq_bf,1024,0, qp,1024,0, 1024, bq, nullptr, 1.f);
  // ck = projkT @ k^T ; cv = projvT @ v^T
  k_gemm<128,128,3,0,u16><<<dim3(8,1,16), 256, 0, stream>>>(
      projT,2048,0, kT,2048,0, ck,1024,0, 2048, nullptr, nullptr, 1.f);
  // pk = (ck @ Wk^T + sk (x) bk) / 8
  k_gemm<128,128,0,2,u16><<<dim3(8,1,8), 256, 0, stream>>>(
      ck,1024,131072, Wk_bf,1024,0, pk,1024,131072, 1024, bk, sk, 0.125f);
  // pvT = (cv @ Wv^T + sv (x) bv), transposed write -> [64 d][128 kr] per (b,h)
  k_gemm<128,128,0,3,u16><<<dim3(8,1,8), 256, 0, stream>>>(
      ck + 1048576,1024,131072, Wv_bf,1024,0, pvT,0,131072, 1024, bv, sv, 1.f);
  // fused attention (never materializes scores in HBM)
  k_stats<<<128, 512, 0, stream>>>(pk, qp, invZ);
  k_attn<<<dim3(16,128), 256, 0, stream>>>(pk, qp, pvT, invZ, outh);
  // final = outh @ Wo^T + bo -> fp32 d_out
  k_gemm<128,128,0,1,float><<<dim3(8,128,1), 256, 0, stream>>>(
      outh,1024,0, Wo_bf,1024,0, (float*)d_out,1024,0, 1024, bo, nullptr, 1.f);
}

// Round 4
// 314.474 us; speedup vs baseline: 1.2052x; 1.0676x over previous
//
#include <hip/hip_runtime.h>

typedef unsigned short u16;
typedef unsigned int   u32;
typedef __attribute__((ext_vector_type(4))) float fx4;
typedef __attribute__((ext_vector_type(8))) __bf16 bf16x8;
typedef __attribute__((ext_vector_type(8))) unsigned short us8;
typedef __attribute__((ext_vector_type(2))) unsigned int u32x2;

__device__ __forceinline__ u16 f2bf(float x){
  u32 u = __builtin_bit_cast(u32, x);
  u += 0x7fffu + ((u >> 16) & 1u);
  return (u16)(u >> 16);
}
__device__ __forceinline__ float b2f(u16 h){
  u32 u = ((u32)h) << 16;
  return __builtin_bit_cast(float, u);
}
__device__ __forceinline__ void gld16(const void* g, void* l){
  __builtin_amdgcn_global_load_lds(
      (const __attribute__((address_space(1))) u32*)g,
      (__attribute__((address_space(3))) u32*)l, 16, 0, 0);
}
// XCD-chunked bijective swizzle (grid size must be %8==0).
__device__ __forceinline__ void xcd_remap(u32& bx, u32& by, u32& bz){
  u32 nx = gridDim.x, ny = gridDim.y, nz = gridDim.z;
  u32 nwg = nx * ny * nz;
  u32 orig = (blockIdx.z * ny + blockIdx.y) * nx + blockIdx.x;
  u32 lid = (orig & 7u) * (nwg >> 3) + (orig >> 3);
  bx = lid % nx;
  u32 rem = lid / nx;
  by = rem % ny;
  bz = rem / ny;
}

// ---------------- fp32 -> bf16 convert (vectorized, grid-stride) ----------------
__global__ __launch_bounds__(256) void k_f2bf(const float* __restrict__ in,
                                              u16* __restrict__ out, int n8){
  int i = blockIdx.x * 256 + threadIdx.x;
  const int stride = gridDim.x * 256;
  for (; i < n8; i += stride){
    const float4* p = (const float4*)in + (long)i * 2;
    float4 a = p[0], b = p[1];
    us8 o = { f2bf(a.x), f2bf(a.y), f2bf(a.z), f2bf(a.w),
              f2bf(b.x), f2bf(b.y), f2bf(b.z), f2bf(b.w) };
    *((us8*)out + i) = o;
  }
}

__global__ void k_zero(float* p, int n){
  int i = blockIdx.x * 256 + threadIdx.x;
  if (i < n) p[i] = 0.f;
}

// ---------------- transpose + convert: in [R,C] f32 -> out [C,R] bf16 ----------------
__global__ __launch_bounds__(256) void k_tconv(const float* __restrict__ in,
                                               u16* __restrict__ out,
                                               int R, int C, long sIn, long sOut,
                                               float* __restrict__ colsum){
  in  += (long)blockIdx.z * sIn;
  out += (long)blockIdx.z * sOut;
  const int c0 = blockIdx.x * 64, r0 = blockIdx.y * 64;
  __shared__ u16 tile[64][66];
  __shared__ float red[256];
  const int t = threadIdx.x;
  const int cc = t & 63, wq = t >> 6;
  float part = 0.f;
  #pragma unroll
  for (int i = 0; i < 16; ++i){
    int rr = i * 4 + wq;
    float v = in[(long)(r0 + rr) * C + c0 + cc];
    tile[rr][cc] = f2bf(v);
    part += v;
  }
  if (colsum){
    red[t] = part;
    __syncthreads();
    if (t < 64){
      float s = red[t] + red[t + 64] + red[t + 128] + red[t + 192];
      atomicAdd(&colsum[c0 + t], s);
    }
  }
  __syncthreads();
  const int oc0 = t >> 5, jb = (t & 31) * 2;
  #pragma unroll
  for (int i = 0; i < 8; ++i){
    int oc = oc0 + i * 8;
    u32 pk2 = (u32)tile[jb][oc] | ((u32)tile[jb + 1][oc] << 16);
    *(u32*)(out + (long)(c0 + oc) * R + r0 + jb) = pk2;
  }
}

// ---------------- BT-layout MFMA GEMM (small/batched shapes) ----------------
template<int BM, int BN, int MODE, int EPI, typename OutT>
__global__ __launch_bounds__(256) void k_gemm(
    const u16* __restrict__ A, int lda, long sAz,
    const u16* __restrict__ B, int ldb, long sBz,
    OutT* __restrict__ C, int ldc, long sCz,
    int K, const float* __restrict__ bias, const float* __restrict__ srow, float scale)
{
  constexpr int BK = 64;
  constexpr int FM = BM / 32, FN = BN / 32;
  __shared__ u16 ldsA[BM * BK];
  __shared__ u16 ldsB[BN * BK];
  u32 bx, by, bz;
  xcd_remap(bx, by, bz);
  const long z = bz;
  if constexpr (MODE == 0){ A += z * sAz; B += z * sBz; C += z * sCz; }
  if constexpr (MODE == 3){ long p = z >> 3, bb = z & 7;
                            A += p * 262144; B += p * 16777216 + bb * 2097152;
                            C += p * 1048576 + bb * 131072; }
  const int t = threadIdx.x;
  const int lane = t & 63;
  const int w = t >> 6, wm = w >> 1, wn = w & 1;
  const int r15 = lane & 15, g = lane >> 4;
  const int m0 = by * BM, n0 = bx * BN;
  fx4 acc[FM][FN] = {};
  constexpr int CA = BM * BK / (8 * 256);
  constexpr int CB = BN * BK / (8 * 256);
  for (int kt = 0; kt < K; kt += BK){
    #pragma unroll
    for (int i = 0; i < CA; ++i){
      int ch = i * 256 + t, row = ch >> 3, cc = ch & 7;
      gld16(A + (long)(m0 + row) * lda + kt + cc * 8, (char*)ldsA + ch * 16);
    }
    #pragma unroll
    for (int i = 0; i < CB; ++i){
      int ch = i * 256 + t, row = ch >> 3, cc = ch & 7;
      gld16(B + (long)(n0 + row) * ldb + kt + cc * 8, (char*)ldsB + ch * 16);
    }
    __syncthreads();
    #pragma unroll
    for (int ks = 0; ks < 2; ++ks){
      bf16x8 af[FM], bfv[FN];
      #pragma unroll
      for (int mf = 0; mf < FM; ++mf)
        af[mf] = *(const bf16x8*)&ldsA[(wm * (BM/2) + mf * 16 + r15) * BK + ks * 32 + g * 8];
      #pragma unroll
      for (int nf = 0; nf < FN; ++nf)
        bfv[nf] = *(const bf16x8*)&ldsB[(wn * (BN/2) + nf * 16 + r15) * BK + ks * 32 + g * 8];
      #pragma unroll
      for (int mf = 0; mf < FM; ++mf)
        #pragma unroll
        for (int nf = 0; nf < FN; ++nf)
          acc[mf][nf] = __builtin_amdgcn_mfma_f32_16x16x32_bf16(af[mf], bfv[nf], acc[mf][nf], 0, 0, 0);
    }
    __syncthreads();
  }
  #pragma unroll
  for (int mf = 0; mf < FM; ++mf){
    #pragma unroll
    for (int nf = 0; nf < FN; ++nf){
      const int row0 = m0 + wm * (BM/2) + mf * 16 + g * 4;
      const int col  = n0 + wn * (BN/2) + nf * 16 + r15;
      float vv[4];
      #pragma unroll
      for (int r = 0; r < 4; ++r){
        float v = acc[mf][nf][r];
        if constexpr (EPI == 1) v += bias[col];
        if constexpr (EPI == 2) v = (v + srow[row0 + r] * bias[col]) * scale;
        if constexpr (EPI == 3) v = v + srow[row0 + r] * bias[col];
        vv[r] = v;
      }
      if constexpr (EPI == 3){
        u32 lo = (u32)f2bf(vv[0]) | ((u32)f2bf(vv[1]) << 16);
        u32 hi = (u32)f2bf(vv[2]) | ((u32)f2bf(vv[3]) << 16);
        u32x2 pk2 = { lo, hi };
        *(u32x2*)((u16*)C + (long)col * 128 + row0) = pk2;
      } else {
        #pragma unroll
        for (int r = 0; r < 4; ++r){
          if constexpr (sizeof(OutT) == 2) C[(long)(row0 + r) * ldc + col] = (OutT)f2bf(vv[r]);
          else                             C[(long)(row0 + r) * ldc + col] = (OutT)vv[r];
        }
      }
    }
  }
}

// ---------------- big-M GEMM: 256x128 tile, phased counted-vmcnt schedule ----------------
// C[M,N] = A[M,K] * B[N,K]^T (+bias). 512 thr = 8 waves (4M x 2N), wave tile 64x64.
// Triple-buffered LDS (stage tile t+2 while computing t; t+1 resident).
// XOR-swizzle both-sides: gld source col-chunk ^= row&7; ds_read chunk ^= row&7.
template<int EPI, typename OutT>
__global__ __launch_bounds__(512, 1) void k_gemm256(
    const u16* __restrict__ A, int lda,
    const u16* __restrict__ B, int ldb,
    OutT* __restrict__ C, int ldc,
    int K, const float* __restrict__ bias)
{
  constexpr int BM = 256, BN = 128, BK = 64;
  __shared__ u16 ldsA[3][BM * BK];
  __shared__ u16 ldsB[3][BN * BK];
  u32 bx, by, bz;
  xcd_remap(bx, by, bz);
  const int m0 = by * BM, n0 = bx * BN;
  const int t = threadIdx.x;
  const int lane = t & 63, w = t >> 6;
  const int wm = w >> 1, wn = w & 1;
  const int r15 = lane & 15, g = lane >> 4;
  const int NT = K >> 6;

  auto stageA = [&](int kt, int buf){
    #pragma unroll
    for (int j = 0; j < 4; ++j){
      int ch = j * 512 + t, row = ch >> 3, cc = ch & 7;
      gld16(A + (long)(m0 + row) * lda + kt + ((cc ^ (row & 7)) * 8),
            (char*)ldsA[buf] + ch * 16);
    }
  };
  auto stageB = [&](int kt, int buf){
    #pragma unroll
    for (int j = 0; j < 2; ++j){
      int ch = j * 512 + t, row = ch >> 3, cc = ch & 7;
      gld16(B + (long)(n0 + row) * ldb + kt + ((cc ^ (row & 7)) * 8),
            (char*)ldsB[buf] + ch * 16);
    }
  };

  stageA(0, 0); stageB(0, 0);
  if (NT > 1){
    stageA(BK, 1); stageB(BK, 1);
    asm volatile("s_waitcnt vmcnt(6)" ::: "memory");
  } else {
    asm volatile("s_waitcnt vmcnt(0)" ::: "memory");
  }
  __builtin_amdgcn_s_barrier();
  asm volatile("" ::: "memory");

  fx4 acc[4][4] = {};
  for (int tt = 0; tt < NT; ++tt){
    const u16* bA = ldsA[tt % 3];
    const u16* bB = ldsB[tt % 3];
    const int sbuf = (tt + 2) % 3;
    const bool pf = (tt + 2 < NT);
    // ---- phase 1: ds A-frags + B nf0/1; stage A(t+2); MFMA nf0/1 ----
    bf16x8 af[2][4], bf[2][2];
    #pragma unroll
    for (int ks = 0; ks < 2; ++ks)
      #pragma unroll
      for (int mf = 0; mf < 4; ++mf)
        af[ks][mf] = *(const bf16x8*)((const char*)bA +
            (wm * 64 + mf * 16 + r15) * 128 + (((ks * 4 + g) ^ (r15 & 7)) * 16));
    #pragma unroll
    for (int ks = 0; ks < 2; ++ks)
      #pragma unroll
      for (int nf = 0; nf < 2; ++nf)
        bf[ks][nf] = *(const bf16x8*)((const char*)bB +
            (wn * 64 + nf * 16 + r15) * 128 + (((ks * 4 + g) ^ (r15 & 7)) * 16));
    if (pf) stageA((tt + 2) * BK, sbuf);
    asm volatile("" ::: "memory");
    __builtin_amdgcn_s_barrier();
    asm volatile("" ::: "memory");
    __builtin_amdgcn_s_setprio(1);
    #pragma unroll
    for (int ks = 0; ks < 2; ++ks)
      #pragma unroll
      for (int mf = 0; mf < 4; ++mf)
        #pragma unroll
        for (int nf = 0; nf < 2; ++nf)
          acc[mf][nf] = __builtin_amdgcn_mfma_f32_16x16x32_bf16(af[ks][mf], bf[ks][nf], acc[mf][nf], 0, 0, 0);
    __builtin_amdgcn_s_setprio(0);
    asm volatile("" ::: "memory");
    __builtin_amdgcn_s_barrier();
    asm volatile("" ::: "memory");
    // ---- phase 2: ds B nf2/3; stage B(t+2); MFMA nf2/3; counted vm-wait ----
    bf16x8 bf2[2][2];
    #pragma unroll
    for (int ks = 0; ks < 2; ++ks)
      #pragma unroll
      for (int nf = 0; nf < 2; ++nf)
        bf2[ks][nf] = *(const bf16x8*)((const char*)bB +
            (wn * 64 + (nf + 2) * 16 + r15) * 128 + (((ks * 4 + g) ^ (r15 & 7)) * 16));
    if (pf) stageB((tt + 2) * BK, sbuf);
    __builtin_amdgcn_s_setprio(1);
    #pragma unroll
    for (int ks = 0; ks < 2; ++ks)
      #pragma unroll
      for (int mf = 0; mf < 4; ++mf)
        #pragma unroll
        for (int nf = 0; nf < 2; ++nf)
          acc[mf][nf + 2] = __builtin_amdgcn_mfma_f32_16x16x32_bf16(af[ks][mf], bf2[ks][nf], acc[mf][nf + 2], 0, 0, 0);
    __builtin_amdgcn_s_setprio(0);
    if (pf)                { asm volatile("s_waitcnt vmcnt(6)" ::: "memory"); }
    else if (tt + 1 < NT)  { asm volatile("s_waitcnt vmcnt(0)" ::: "memory"); }
    asm volatile("" ::: "memory");
    __builtin_amdgcn_s_barrier();
    asm volatile("" ::: "memory");
  }

  #pragma unroll
  for (int mf = 0; mf < 4; ++mf)
    #pragma unroll
    for (int nf = 0; nf < 4; ++nf){
      const int row0 = m0 + wm * 64 + mf * 16 + g * 4;
      const int col  = n0 + wn * 64 + nf * 16 + r15;
      float bcol = 0.f;
      if constexpr (EPI == 1) bcol = bias[col];
      #pragma unroll
      for (int r = 0; r < 4; ++r){
        float vv = acc[mf][nf][r] + bcol;
        if constexpr (sizeof(OutT) == 2) C[(long)(row0 + r) * ldc + col] = (OutT)f2bf(vv);
        else                             C[(long)(row0 + r) * ldc + col] = (OutT)vv;
      }
    }
}

// ---------------- fused attention, pass 1: Z[k] = sum_n exp(s[k,n]) ----------------
__global__ __launch_bounds__(512) void k_stats(const u16* __restrict__ pk,
                                               const u16* __restrict__ qp,
                                               float* __restrict__ invZ){
  const int z = blockIdx.x;
  const int b = z >> 4, h = z & 15;
  const u16* pkh = pk + b * 131072 + h * 64;
  const u16* qph = qp + (long)z * 131072;
  __shared__ u16 pkL[128 * 64];
  __shared__ float zred[8][128];
  const int t = threadIdx.x, lane = t & 63, w = t >> 6;
  const int r15 = lane & 15, g = lane >> 4;
  #pragma unroll
  for (int i = 0; i < 2; ++i){
    int ch = i * 512 + t, row = ch >> 3, cc = ch & 7;
    int csrc = cc ^ (row & 7);
    gld16(pkh + (long)row * 1024 + csrc * 8, (char*)pkL + ch * 16);
  }
  __syncthreads();
  float zacc[8][4] = {};
  for (int c = 0; c < 8; ++c){
    const int n0 = w * 256 + c * 32;
    fx4 acc[8][2] = {};
    #pragma unroll
    for (int ks = 0; ks < 2; ++ks){
      bf16x8 bq[2];
      #pragma unroll
      for (int nf = 0; nf < 2; ++nf)
        bq[nf] = *(const bf16x8*)(qph + (long)(n0 + nf * 16 + r15) * 64 + ks * 32 + g * 8);
      #pragma unroll
      for (int mf = 0; mf < 8; ++mf){
        int row = mf * 16 + r15;
        int x = (ks * 4 + g) ^ (row & 7);
        bf16x8 a = *(const bf16x8*)((const char*)pkL + row * 128 + x * 16);
        #pragma unroll
        for (int nf = 0; nf < 2; ++nf)
          acc[mf][nf] = __builtin_amdgcn_mfma_f32_16x16x32_bf16(a, bq[nf], acc[mf][nf], 0, 0, 0);
      }
    }
    #pragma unroll
    for (int mf = 0; mf < 8; ++mf)
      #pragma unroll
      for (int nf = 0; nf < 2; ++nf)
        #pragma unroll
        for (int r = 0; r < 4; ++r)
          zacc[mf][r] += __expf(acc[mf][nf][r]);
  }
  #pragma unroll
  for (int mf = 0; mf < 8; ++mf)
    #pragma unroll
    for (int r = 0; r < 4; ++r){
      float v = zacc[mf][r];
      v += __shfl_xor(v, 1); v += __shfl_xor(v, 2);
      v += __shfl_xor(v, 4); v += __shfl_xor(v, 8);
      zacc[mf][r] = v;
    }
  if (r15 == 0){
    #pragma unroll
    for (int mf = 0; mf < 8; ++mf)
      #pragma unroll
      for (int r = 0; r < 4; ++r)
        zred[w][mf * 16 + g * 4 + r] = zacc[mf][r];
  }
  __syncthreads();
  if (t < 128){
    float s = 0.f;
    #pragma unroll
    for (int w2 = 0; w2 < 8; ++w2) s += zred[w2][t];
    invZ[(long)z * 128 + t] = 1.0f / s;
  }
}

// ---------------- fused attention, pass 2: out = attn^T @ pv ----------------
__global__ __launch_bounds__(256) void k_attn(const u16* __restrict__ pk,
                                              const u16* __restrict__ qp,
                                              const u16* __restrict__ pvT,
                                              const float* __restrict__ invZ,
                                              u16* __restrict__ outh){
  u32 bx, by, bz;
  xcd_remap(bx, by, bz);
  const int z = by, nb = bx;
  const int b = z >> 4, h = z & 15;
  const u16* pkh = pk  + b * 131072 + h * 64;
  const u16* qph = qp  + (long)z * 131072;
  const u16* pvh = pvT + b * 131072 + h * 8192;
  const float* zh = invZ + (long)z * 128;
  __shared__ u16 pkL[128 * 64];
  __shared__ u16 ptL[4][32 * 132];
  __shared__ float zL[128];
  const int t = threadIdx.x, lane = t & 63, w = t >> 6;
  const int r15 = lane & 15, g = lane >> 4;
  #pragma unroll
  for (int i = 0; i < 4; ++i){
    int ch = i * 256 + t, row = ch >> 3, cc = ch & 7;
    int csrc = cc ^ (row & 7);
    gld16(pkh + (long)row * 1024 + csrc * 8, (char*)pkL + ch * 16);
  }
  if (t < 128) zL[t] = zh[t];
  __syncthreads();
  const int n0 = nb * 128 + w * 32;
  fx4 acc[8][2] = {};
  #pragma unroll
  for (int ks = 0; ks < 2; ++ks){
    bf16x8 bq[2];
    #pragma unroll
    for (int nf = 0; nf < 2; ++nf)
      bq[nf] = *(const bf16x8*)(qph + (long)(n0 + nf * 16 + r15) * 64 + ks * 32 + g * 8);
    #pragma unroll
    for (int mf = 0; mf < 8; ++mf){
      int row = mf * 16 + r15;
      int x = (ks * 4 + g) ^ (row & 7);
      bf16x8 a = *(const bf16x8*)((const char*)pkL + row * 128 + x * 16);
      #pragma unroll
      for (int nf = 0; nf < 2; ++nf)
        acc[mf][nf] = __builtin_amdgcn_mfma_f32_16x16x32_bf16(a, bq[nf], acc[mf][nf], 0, 0, 0);
    }
  }
  u16* pt = ptL[w];
  #pragma unroll
  for (int mf = 0; mf < 8; ++mf){
    const int kb = mf * 16 + g * 4;
    const float z0 = zL[kb], z1 = zL[kb + 1], z2 = zL[kb + 2], z3 = zL[kb + 3];
    #pragma unroll
    for (int nf = 0; nf < 2; ++nf){
      const int nl = nf * 16 + r15;
      u32 lo = (u32)f2bf(__expf(acc[mf][nf][0]) * z0) |
               ((u32)f2bf(__expf(acc[mf][nf][1]) * z1) << 16);
      u32 hi = (u32)f2bf(__expf(acc[mf][nf][2]) * z2) |
               ((u32)f2bf(__expf(acc[mf][nf][3]) * z3) << 16);
      u32x2 pkd = { lo, hi };
      *(u32x2*)(pt + nl * 132 + kb) = pkd;
    }
  }
  fx4 o[2][4] = {};
  #pragma unroll
  for (int ks = 0; ks < 4; ++ks){
    bf16x8 bv[4];
    #pragma unroll
    for (int nf = 0; nf < 4; ++nf)
      bv[nf] = *(const bf16x8*)(pvh + (long)(nf * 16 + r15) * 128 + ks * 32 + g * 8);
    #pragma unroll
    for (int mf = 0; mf < 2; ++mf){
      bf16x8 pa = *(const bf16x8*)(pt + (mf * 16 + r15) * 132 + ks * 32 + g * 8);
      #pragma unroll
      for (int nf = 0; nf < 4; ++nf)
        o[mf][nf] = __builtin_amdgcn_mfma_f32_16x16x32_bf16(pa, bv[nf], o[mf][nf], 0, 0, 0);
    }
  }
  u16* og = outh + ((long)b * 2048 + n0) * 1024 + h * 64;
  #pragma unroll
  for (int mf = 0; mf < 2; ++mf)
    #pragma unroll
    for (int nf = 0; nf < 4; ++nf)
      #pragma unroll
      for (int r = 0; r < 4; ++r){
        int nl = mf * 16 + g * 4 + r;
        og[(long)nl * 1024 + nf * 16 + r15] = f2bf(o[mf][nf][r]);
      }
}

extern "C" void kernel_launch(void* const* d_in, const int* in_sizes, int n_in,
                              void* d_out, int out_size, void* d_ws, size_t ws_size,
                              hipStream_t stream)
{
  const float* q   = (const float*)d_in[0];
  const float* k   = (const float*)d_in[1];
  const float* v   = (const float*)d_in[2];
  const float* Wq  = (const float*)d_in[3];
  const float* bq  = (const float*)d_in[4];
  const float* Wk  = (const float*)d_in[5];
  const float* bk  = (const float*)d_in[6];
  const float* Wv  = (const float*)d_in[7];
  const float* bv  = (const float*)d_in[8];
  const float* pjk = (const float*)d_in[9];
  const float* pjv = (const float*)d_in[10];
  const float* Wo  = (const float*)d_in[11];
  const float* bo  = (const float*)d_in[12];

  if (ws_size < 152044544u) return;

  char* ws = (char*)d_ws;
  u16*  q_bf  = (u16*)(ws + 0);            // 32MB (reused by outh)
  u16*  kT    = (u16*)(ws + 33554432);     // 32MB (reused by invZ)
  u16*  vT    = (u16*)(ws + 67108864);     // 32MB
  u16*  Wq_bf = (u16*)(ws + 100663296);
  u16*  Wk_bf = (u16*)(ws + 102760448);
  u16*  Wv_bf = (u16*)(ws + 104857600);
  u16*  Wo_bf = (u16*)(ws + 106954752);
  u16*  projT = (u16*)(ws + 109051904);    // projkT [128][2048], projvT after
  float* sk   = (float*)(ws + 110100480);
  float* sv   = (float*)(ws + 110100992);
  u16*  qp    = (u16*)(ws + 110101504);    // 32MB [16384,1024]
  u16*  ck    = (u16*)(ws + 143655936);    // [2][8][128][1024]
  u16*  pk    = (u16*)(ws + 147850240);    // [8][128][1024], pre-scaled 1/8
  u16*  pvT   = (u16*)(ws + 149947392);    // [8][16][64][128]
  float* invZ = (float*)(ws + 33554432);   // [128][128] overlay kT
  u16*  outh  = (u16*)(ws + 0);            // [16384,1024] overlay q_bf

  k_zero<<<1, 256, 0, stream>>>(sk, 256);

  k_f2bf<<<2048, 256, 0, stream>>>(q,  q_bf, 2097152);
  k_f2bf<<<512,  256, 0, stream>>>(Wq, Wq_bf, 131072);
  k_f2bf<<<512,  256, 0, stream>>>(Wk, Wk_bf, 131072);
  k_f2bf<<<512,  256, 0, stream>>>(Wv, Wv_bf, 131072);
  k_f2bf<<<512,  256, 0, stream>>>(Wo, Wo_bf, 131072);
  k_tconv<<<dim3(16,32,8), 256, 0, stream>>>(k, kT, 2048, 1024, 2097152, 2097152, nullptr);
  k_tconv<<<dim3(16,32,8), 256, 0, stream>>>(v, vT, 2048, 1024, 2097152, 2097152, nullptr);
  k_tconv<<<dim3(2,32,1),  256, 0, stream>>>(pjk, projT,          2048, 128, 0, 0, sk);
  k_tconv<<<dim3(2,32,1),  256, 0, stream>>>(pjv, projT + 262144, 2048, 128, 0, 0, sv);

  // qp = q @ Wq^T + bq   (phased 256x128 kernel)
  k_gemm256<1,u16><<<dim3(8,64), 512, 0, stream>>>(
      q_bf,1024, Wq_bf,1024, qp,1024, 1024, bq);
  // ck = projkT @ k^T ; cv = projvT @ v^T
  k_gemm<128,128,3,0,u16><<<dim3(8,1,16), 256, 0, stream>>>(
      projT,2048,0, kT,2048,0, ck,1024,0, 2048, nullptr, nullptr, 1.f);
  // pk = (ck @ Wk^T + sk (x) bk) / 8
  k_gemm<128,128,0,2,u16><<<dim3(8,1,8), 256, 0, stream>>>(
      ck,1024,131072, Wk_bf,1024,0, pk,1024,131072, 1024, bk, sk, 0.125f);
  // pvT = (cv @ Wv^T + sv (x) bv), transposed write
  k_gemm<128,128,0,3,u16><<<dim3(8,1,8), 256, 0, stream>>>(
      ck + 1048576,1024,131072, Wv_bf,1024,0, pvT,0,131072, 1024, bv, sv, 1.f);
  // fused attention
  k_stats<<<128, 512, 0, stream>>>(pk, qp, invZ);
  k_attn<<<dim3(16,128), 256, 0, stream>>>(pk, qp, pvT, invZ, outh);
  // final = outh @ Wo^T + bo -> fp32 d_out   (phased 256x128 kernel)
  k_gemm256<1,float><<<dim3(8,64), 512, 0, stream>>>(
      outh,1024, Wo_bf,1024, (float*)d_out,1024, 1024, bo);
}

// Round 5
// 284.237 us; speedup vs baseline: 1.3335x; 1.1064x over previous
//
#include <hip/hip_runtime.h>

typedef unsigned short u16;
typedef unsigned int   u32;
typedef __attribute__((ext_vector_type(4))) float fx4;
typedef __attribute__((ext_vector_type(8))) __bf16 bf16x8;
typedef __attribute__((ext_vector_type(8))) unsigned short us8;
typedef __attribute__((ext_vector_type(2))) unsigned int u32x2;

__device__ __forceinline__ u16 f2bf(float x){
  u32 u = __builtin_bit_cast(u32, x);
  u += 0x7fffu + ((u >> 16) & 1u);
  return (u16)(u >> 16);
}
__device__ __forceinline__ float b2f(u16 h){
  u32 u = ((u32)h) << 16;
  return __builtin_bit_cast(float, u);
}
__device__ __forceinline__ void gld16(const void* g, void* l){
  __builtin_amdgcn_global_load_lds(
      (const __attribute__((address_space(1))) u32*)g,
      (__attribute__((address_space(3))) u32*)l, 16, 0, 0);
}
// XCD-chunked bijective swizzle (grid size must be %8==0).
__device__ __forceinline__ void xcd_remap(u32& bx, u32& by, u32& bz){
  u32 nx = gridDim.x, ny = gridDim.y, nz = gridDim.z;
  u32 nwg = nx * ny * nz;
  u32 orig = (blockIdx.z * ny + blockIdx.y) * nx + blockIdx.x;
  u32 lid = (orig & 7u) * (nwg >> 3) + (orig >> 3);
  bx = lid % nx;
  u32 rem = lid / nx;
  by = rem % ny;
  bz = rem / ny;
}

// ---------------- fp32 -> bf16 convert (vectorized, grid-stride) ----------------
__global__ __launch_bounds__(256) void k_f2bf(const float* __restrict__ in,
                                              u16* __restrict__ out, int n8){
  int i = blockIdx.x * 256 + threadIdx.x;
  const int stride = gridDim.x * 256;
  for (; i < n8; i += stride){
    const float4* p = (const float4*)in + (long)i * 2;
    float4 a = p[0], b = p[1];
    us8 o = { f2bf(a.x), f2bf(a.y), f2bf(a.z), f2bf(a.w),
              f2bf(b.x), f2bf(b.y), f2bf(b.z), f2bf(b.w) };
    *((us8*)out + i) = o;
  }
}

// four 1024x1024 weights in one launch; dst slabs contiguous (1Mi elems apart)
__global__ __launch_bounds__(256) void k_f2bfW(const float* __restrict__ w0,
                                               const float* __restrict__ w1,
                                               const float* __restrict__ w2,
                                               const float* __restrict__ w3,
                                               u16* __restrict__ out){
  const float* src = blockIdx.y == 0 ? w0 : blockIdx.y == 1 ? w1 :
                     blockIdx.y == 2 ? w2 : w3;
  u16* dst = out + (long)blockIdx.y * 1048576;
  int i = blockIdx.x * 256 + threadIdx.x;
  const int stride = gridDim.x * 256;
  for (; i < 131072; i += stride){
    const float4* p = (const float4*)src + (long)i * 2;
    float4 a = p[0], b = p[1];
    us8 o = { f2bf(a.x), f2bf(a.y), f2bf(a.z), f2bf(a.w),
              f2bf(b.x), f2bf(b.y), f2bf(b.z), f2bf(b.w) };
    *((us8*)dst + i) = o;
  }
}

__global__ void k_zero(float* p, int n){
  int i = blockIdx.x * 256 + threadIdx.x;
  if (i < n) p[i] = 0.f;
}

// ---------------- transpose + convert: in [R,C] f32 -> out [C,R] bf16 ----------------
__global__ __launch_bounds__(256) void k_tconv(const float* __restrict__ in,
                                               u16* __restrict__ out,
                                               int R, int C, long sIn, long sOut,
                                               float* __restrict__ colsum){
  in  += (long)blockIdx.z * sIn;
  out += (long)blockIdx.z * sOut;
  const int c0 = blockIdx.x * 64, r0 = blockIdx.y * 64;
  __shared__ u16 tile[64][66];
  __shared__ float red[256];
  const int t = threadIdx.x;
  const int cc = t & 63, wq = t >> 6;
  float part = 0.f;
  #pragma unroll
  for (int i = 0; i < 16; ++i){
    int rr = i * 4 + wq;
    float v = in[(long)(r0 + rr) * C + c0 + cc];
    tile[rr][cc] = f2bf(v);
    part += v;
  }
  if (colsum){
    red[t] = part;
    __syncthreads();
    if (t < 64){
      float s = red[t] + red[t + 64] + red[t + 128] + red[t + 192];
      atomicAdd(&colsum[c0 + t], s);
    }
  }
  __syncthreads();
  const int oc0 = t >> 5, jb = (t & 31) * 2;
  #pragma unroll
  for (int i = 0; i < 8; ++i){
    int oc = oc0 + i * 8;
    u32 pk2 = (u32)tile[jb][oc] | ((u32)tile[jb + 1][oc] << 16);
    *(u32*)(out + (long)(c0 + oc) * R + r0 + jb) = pk2;
  }
}

// ---------------- BT-layout MFMA GEMM (small/batched shapes) ----------------
template<int BM, int BN, int MODE, int EPI, typename OutT>
__global__ __launch_bounds__(256) void k_gemm(
    const u16* __restrict__ A, int lda, long sAz,
    const u16* __restrict__ B, int ldb, long sBz,
    OutT* __restrict__ C, int ldc, long sCz,
    int K, const float* __restrict__ bias, const float* __restrict__ srow, float scale)
{
  constexpr int BK = 64;
  constexpr int FM = BM / 32, FN = BN / 32;
  __shared__ u16 ldsA[BM * BK];
  __shared__ u16 ldsB[BN * BK];
  u32 bx, by, bz;
  xcd_remap(bx, by, bz);
  const long z = bz;
  if constexpr (MODE == 0){ A += z * sAz; B += z * sBz; C += z * sCz; }
  if constexpr (MODE == 3){ long p = z >> 3, bb = z & 7;
                            A += p * 262144; B += p * 16777216 + bb * 2097152;
                            C += p * 1048576 + bb * 131072; }
  const int t = threadIdx.x;
  const int lane = t & 63;
  const int w = t >> 6, wm = w >> 1, wn = w & 1;
  const int r15 = lane & 15, g = lane >> 4;
  const int m0 = by * BM, n0 = bx * BN;
  fx4 acc[FM][FN] = {};
  constexpr int CA = BM * BK / (8 * 256);
  constexpr int CB = BN * BK / (8 * 256);
  for (int kt = 0; kt < K; kt += BK){
    #pragma unroll
    for (int i = 0; i < CA; ++i){
      int ch = i * 256 + t, row = ch >> 3, cc = ch & 7;
      gld16(A + (long)(m0 + row) * lda + kt + cc * 8, (char*)ldsA + ch * 16);
    }
    #pragma unroll
    for (int i = 0; i < CB; ++i){
      int ch = i * 256 + t, row = ch >> 3, cc = ch & 7;
      gld16(B + (long)(n0 + row) * ldb + kt + cc * 8, (char*)ldsB + ch * 16);
    }
    __syncthreads();
    #pragma unroll
    for (int ks = 0; ks < 2; ++ks){
      bf16x8 af[FM], bfv[FN];
      #pragma unroll
      for (int mf = 0; mf < FM; ++mf)
        af[mf] = *(const bf16x8*)&ldsA[(wm * (BM/2) + mf * 16 + r15) * BK + ks * 32 + g * 8];
      #pragma unroll
      for (int nf = 0; nf < FN; ++nf)
        bfv[nf] = *(const bf16x8*)&ldsB[(wn * (BN/2) + nf * 16 + r15) * BK + ks * 32 + g * 8];
      #pragma unroll
      for (int mf = 0; mf < FM; ++mf)
        #pragma unroll
        for (int nf = 0; nf < FN; ++nf)
          acc[mf][nf] = __builtin_amdgcn_mfma_f32_16x16x32_bf16(af[mf], bfv[nf], acc[mf][nf], 0, 0, 0);
    }
    __syncthreads();
  }
  #pragma unroll
  for (int mf = 0; mf < FM; ++mf){
    #pragma unroll
    for (int nf = 0; nf < FN; ++nf){
      const int row0 = m0 + wm * (BM/2) + mf * 16 + g * 4;
      const int col  = n0 + wn * (BN/2) + nf * 16 + r15;
      float vv[4];
      #pragma unroll
      for (int r = 0; r < 4; ++r){
        float v = acc[mf][nf][r];
        if constexpr (EPI == 1) v += bias[col];
        if constexpr (EPI == 2) v = (v + srow[row0 + r] * bias[col]) * scale;
        if constexpr (EPI == 3) v = v + srow[row0 + r] * bias[col];
        vv[r] = v;
      }
      if constexpr (EPI == 3){
        u32 lo = (u32)f2bf(vv[0]) | ((u32)f2bf(vv[1]) << 16);
        u32 hi = (u32)f2bf(vv[2]) | ((u32)f2bf(vv[3]) << 16);
        u32x2 pk2 = { lo, hi };
        *(u32x2*)((u16*)C + (long)col * 128 + row0) = pk2;
      } else {
        #pragma unroll
        for (int r = 0; r < 4; ++r){
          if constexpr (sizeof(OutT) == 2) C[(long)(row0 + r) * ldc + col] = (OutT)f2bf(vv[r]);
          else                             C[(long)(row0 + r) * ldc + col] = (OutT)vv[r];
        }
      }
    }
  }
}

// ---------------- big GEMM: 256x256 tile, 4-phase/K-tile counted-vmcnt schedule ----
// C[M,N] = A[M,K]*B[N,K]^T (+bias). 512 thr = 8 waves (2M x 4N), wave tile 128x64.
// LDS 128KiB double-buffered; half-tile staging into phase-proven-dead slots:
//   ph1 -> A-hi(t+1), ph3 -> B-lo(t+2), ph4 -> A-lo(t+2)+B-hi(t+2).
// One vmcnt(6) per K-tile at ph4 (exactly tile t+1's trailing 6 loads in flight).
// Phases: Q(mf0-3,nf0-1) / Q(mf0-3,nf2-3) / Q(mf4-7,nf2-3) / Q(mf4-7,nf0-1);
// B01/B23 fragments stay in registers across phases (24 ds_read/tile: 12/4/8/0).
template<int EPI, typename OutT>
__global__ __launch_bounds__(512, 1) void k_gemm256b(
    const u16* __restrict__ A, int lda,
    const u16* __restrict__ B, int ldb,
    OutT* __restrict__ C, int ldc,
    int K, const float* __restrict__ bias)
{
  constexpr int BM = 256, BN = 256, BK = 64;
  __shared__ u16 ldsA[2][BM * BK];
  __shared__ u16 ldsB[2][BN * BK];
  u32 bx, by, bz;
  xcd_remap(bx, by, bz);
  const int m0 = by * BM, n0 = bx * BN;
  const int t = threadIdx.x, lane = t & 63, w = t >> 6;
  const int wm = w >> 2, wn = w & 3;
  const int r15 = lane & 15, g = lane >> 4;
  const int NT = K >> 6;

  auto stA = [&](int buf, int half, int kt){
    #pragma unroll
    for (int j = 0; j < 2; ++j){
      int ch = j * 512 + t, row = ch >> 3, cc = ch & 7;
      gld16(A + (long)(m0 + half * 128 + row) * lda + kt + ((cc ^ (row & 7)) * 8),
            (char*)ldsA[buf] + half * 16384 + ch * 16);
    }
  };
  auto stB = [&](int buf, int half, int kt){
    #pragma unroll
    for (int j = 0; j < 2; ++j){
      int ch = j * 512 + t, row = ch >> 3, cc = ch & 7;
      gld16(B + (long)(n0 + half * 128 + row) * ldb + kt + ((cc ^ (row & 7)) * 8),
            (char*)ldsB[buf] + half * 16384 + ch * 16);
    }
  };

  // prologue: tile0 fully (8 loads), then Blo1,Bhi1,Alo1 (6 loads)
  stB(0,0,0); stB(0,1,0); stA(0,0,0); stA(0,1,0);
  if (NT > 1){ stB(1,0,BK); stB(1,1,BK); stA(1,0,BK); }
  asm volatile("s_waitcnt vmcnt(6)" ::: "memory");
  __builtin_amdgcn_s_barrier();
  asm volatile("" ::: "memory");

  fx4 acc[8][4] = {};
  for (int tt = 0; tt < NT; ++tt){
    const int buf = tt & 1;
    bf16x8 a[2][4], b01[2][2], b23[2][2];
    // ---------- phase 1: read A(mf0-3)+B01; stage A-hi(t+1); MFMA Q(0-3,0-1)
    #pragma unroll
    for (int ks = 0; ks < 2; ++ks)
      #pragma unroll
      for (int mf = 0; mf < 4; ++mf){
        int row = wm * 128 + mf * 16 + r15;
        a[ks][mf] = *(const bf16x8*)((const char*)ldsA[buf] + row * 128 + (((ks*4+g) ^ (r15 & 7)) * 16));
      }
    #pragma unroll
    for (int ks = 0; ks < 2; ++ks)
      #pragma unroll
      for (int nf = 0; nf < 2; ++nf){
        int row = wn * 64 + nf * 16 + r15;
        b01[ks][nf] = *(const bf16x8*)((const char*)ldsB[buf] + row * 128 + (((ks*4+g) ^ (r15 & 7)) * 16));
      }
    if (tt + 1 < NT) stA(buf ^ 1, 1, (tt + 1) * BK);
    __builtin_amdgcn_s_setprio(1);
    #pragma unroll
    for (int ks = 0; ks < 2; ++ks)
      #pragma unroll
      for (int mf = 0; mf < 4; ++mf)
        #pragma unroll
        for (int nf = 0; nf < 2; ++nf)
          acc[mf][nf] = __builtin_amdgcn_mfma_f32_16x16x32_bf16(a[ks][mf], b01[ks][nf], acc[mf][nf], 0, 0, 0);
    __builtin_amdgcn_s_setprio(0);
    asm volatile("" ::: "memory");
    __builtin_amdgcn_s_barrier();
    asm volatile("" ::: "memory");
    // ---------- phase 2: read B23; MFMA Q(0-3,2-3)
    #pragma unroll
    for (int ks = 0; ks < 2; ++ks)
      #pragma unroll
      for (int nf = 0; nf < 2; ++nf){
        int row = wn * 64 + (nf + 2) * 16 + r15;
        b23[ks][nf] = *(const bf16x8*)((const char*)ldsB[buf] + row * 128 + (((ks*4+g) ^ (r15 & 7)) * 16));
      }
    __builtin_amdgcn_s_setprio(1);
    #pragma unroll
    for (int ks = 0; ks < 2; ++ks)
      #pragma unroll
      for (int mf = 0; mf < 4; ++mf)
        #pragma unroll
        for (int nf = 0; nf < 2; ++nf)
          acc[mf][nf + 2] = __builtin_amdgcn_mfma_f32_16x16x32_bf16(a[ks][mf], b23[ks][nf], acc[mf][nf + 2], 0, 0, 0);
    __builtin_amdgcn_s_setprio(0);
    asm volatile("" ::: "memory");
    __builtin_amdgcn_s_barrier();
    asm volatile("" ::: "memory");
    // ---------- phase 3: read A(mf4-7); stage B-lo(t+2); MFMA Q(4-7,2-3)
    #pragma unroll
    for (int ks = 0; ks < 2; ++ks)
      #pragma unroll
      for (int mf = 0; mf < 4; ++mf){
        int row = wm * 128 + (mf + 4) * 16 + r15;
        a[ks][mf] = *(const bf16x8*)((const char*)ldsA[buf] + row * 128 + (((ks*4+g) ^ (r15 & 7)) * 16));
      }
    if (tt + 2 < NT) stB(buf, 0, (tt + 2) * BK);
    __builtin_amdgcn_s_setprio(1);
    #pragma unroll
    for (int ks = 0; ks < 2; ++ks)
      #pragma unroll
      for (int mf = 0; mf < 4; ++mf)
        #pragma unroll
        for (int nf = 0; nf < 2; ++nf)
          acc[mf + 4][nf + 2] = __builtin_amdgcn_mfma_f32_16x16x32_bf16(a[ks][mf], b23[ks][nf], acc[mf + 4][nf + 2], 0, 0, 0);
    __builtin_amdgcn_s_setprio(0);
    asm volatile("" ::: "memory");
    __builtin_amdgcn_s_barrier();
    asm volatile("" ::: "memory");
    // ---------- phase 4: stage A-lo(t+2)+B-hi(t+2); MFMA Q(4-7,0-1); counted wait
    if (tt + 2 < NT){ stA(buf, 0, (tt + 2) * BK); stB(buf, 1, (tt + 2) * BK); }
    __builtin_amdgcn_s_setprio(1);
    #pragma unroll
    for (int ks = 0; ks < 2; ++ks)
      #pragma unroll
      for (int mf = 0; mf < 4; ++mf)
        #pragma unroll
        for (int nf = 0; nf < 2; ++nf)
          acc[mf + 4][nf] = __builtin_amdgcn_mfma_f32_16x16x32_bf16(a[ks][mf], b01[ks][nf], acc[mf + 4][nf], 0, 0, 0);
    __builtin_amdgcn_s_setprio(0);
    if (tt + 2 < NT)      { asm volatile("s_waitcnt vmcnt(6)" ::: "memory"); }
    else if (tt + 1 < NT) { asm volatile("s_waitcnt vmcnt(0)" ::: "memory"); }
    asm volatile("" ::: "memory");
    __builtin_amdgcn_s_barrier();
    asm volatile("" ::: "memory");
  }

  #pragma unroll
  for (int mf = 0; mf < 8; ++mf)
    #pragma unroll
    for (int nf = 0; nf < 4; ++nf){
      const int row0 = m0 + wm * 128 + mf * 16 + g * 4;
      const int col  = n0 + wn * 64 + nf * 16 + r15;
      float bcol = 0.f;
      if constexpr (EPI == 1) bcol = bias[col];
      #pragma unroll
      for (int r = 0; r < 4; ++r){
        float vv = acc[mf][nf][r] + bcol;
        if constexpr (sizeof(OutT) == 2) C[(long)(row0 + r) * ldc + col] = (OutT)f2bf(vv);
        else                             C[(long)(row0 + r) * ldc + col] = (OutT)vv;
      }
    }
}

// ---------------- fused attention, pass 1: Z[k] = sum_n exp(s[k,n]) ----------------
__global__ __launch_bounds__(512) void k_stats(const u16* __restrict__ pk,
                                               const u16* __restrict__ qp,
                                               float* __restrict__ invZ){
  const int z = blockIdx.x;
  const int b = z >> 4, h = z & 15;
  const u16* pkh = pk + b * 131072 + h * 64;
  const u16* qph = qp + (long)z * 131072;
  __shared__ u16 pkL[128 * 64];
  __shared__ float zred[8][128];
  const int t = threadIdx.x, lane = t & 63, w = t >> 6;
  const int r15 = lane & 15, g = lane >> 4;
  #pragma unroll
  for (int i = 0; i < 2; ++i){
    int ch = i * 512 + t, row = ch >> 3, cc = ch & 7;
    int csrc = cc ^ (row & 7);
    gld16(pkh + (long)row * 1024 + csrc * 8, (char*)pkL + ch * 16);
  }
  __syncthreads();
  float zacc[8][4] = {};
  for (int c = 0; c < 8; ++c){
    const int n0 = w * 256 + c * 32;
    fx4 acc[8][2] = {};
    #pragma unroll
    for (int ks = 0; ks < 2; ++ks){
      bf16x8 bq[2];
      #pragma unroll
      for (int nf = 0; nf < 2; ++nf)
        bq[nf] = *(const bf16x8*)(qph + (long)(n0 + nf * 16 + r15) * 64 + ks * 32 + g * 8);
      #pragma unroll
      for (int mf = 0; mf < 8; ++mf){
        int row = mf * 16 + r15;
        int x = (ks * 4 + g) ^ (row & 7);
        bf16x8 a = *(const bf16x8*)((const char*)pkL + row * 128 + x * 16);
        #pragma unroll
        for (int nf = 0; nf < 2; ++nf)
          acc[mf][nf] = __builtin_amdgcn_mfma_f32_16x16x32_bf16(a, bq[nf], acc[mf][nf], 0, 0, 0);
      }
    }
    #pragma unroll
    for (int mf = 0; mf < 8; ++mf)
      #pragma unroll
      for (int nf = 0; nf < 2; ++nf)
        #pragma unroll
        for (int r = 0; r < 4; ++r)
          zacc[mf][r] += __expf(acc[mf][nf][r]);
  }
  #pragma unroll
  for (int mf = 0; mf < 8; ++mf)
    #pragma unroll
    for (int r = 0; r < 4; ++r){
      float v = zacc[mf][r];
      v += __shfl_xor(v, 1); v += __shfl_xor(v, 2);
      v += __shfl_xor(v, 4); v += __shfl_xor(v, 8);
      zacc[mf][r] = v;
    }
  if (r15 == 0){
    #pragma unroll
    for (int mf = 0; mf < 8; ++mf)
      #pragma unroll
      for (int r = 0; r < 4; ++r)
        zred[w][mf * 16 + g * 4 + r] = zacc[mf][r];
  }
  __syncthreads();
  if (t < 128){
    float s = 0.f;
    #pragma unroll
    for (int w2 = 0; w2 < 8; ++w2) s += zred[w2][t];
    invZ[(long)z * 128 + t] = 1.0f / s;
  }
}

// ---------------- fused attention, pass 2: out = attn^T @ pv ----------------
__global__ __launch_bounds__(256) void k_attn(const u16* __restrict__ pk,
                                              const u16* __restrict__ qp,
                                              const u16* __restrict__ pvT,
                                              const float* __restrict__ invZ,
                                              u16* __restrict__ outh){
  u32 bx, by, bz;
  xcd_remap(bx, by, bz);
  const int z = by, nb = bx;
  const int b = z >> 4, h = z & 15;
  const u16* pkh = pk  + b * 131072 + h * 64;
  const u16* qph = qp  + (long)z * 131072;
  const u16* pvh = pvT + b * 131072 + h * 8192;
  const float* zh = invZ + (long)z * 128;
  __shared__ u16 pkL[128 * 64];
  __shared__ u16 ptL[4][32 * 132];
  __shared__ float zL[128];
  const int t = threadIdx.x, lane = t & 63, w = t >> 6;
  const int r15 = lane & 15, g = lane >> 4;
  #pragma unroll
  for (int i = 0; i < 4; ++i){
    int ch = i * 256 + t, row = ch >> 3, cc = ch & 7;
    int csrc = cc ^ (row & 7);
    gld16(pkh + (long)row * 1024 + csrc * 8, (char*)pkL + ch * 16);
  }
  if (t < 128) zL[t] = zh[t];
  __syncthreads();
  const int n0 = nb * 128 + w * 32;
  fx4 acc[8][2] = {};
  #pragma unroll
  for (int ks = 0; ks < 2; ++ks){
    bf16x8 bq[2];
    #pragma unroll
    for (int nf = 0; nf < 2; ++nf)
      bq[nf] = *(const bf16x8*)(qph + (long)(n0 + nf * 16 + r15) * 64 + ks * 32 + g * 8);
    #pragma unroll
    for (int mf = 0; mf < 8; ++mf){
      int row = mf * 16 + r15;
      int x = (ks * 4 + g) ^ (row & 7);
      bf16x8 a = *(const bf16x8*)((const char*)pkL + row * 128 + x * 16);
      #pragma unroll
      for (int nf = 0; nf < 2; ++nf)
        acc[mf][nf] = __builtin_amdgcn_mfma_f32_16x16x32_bf16(a, bq[nf], acc[mf][nf], 0, 0, 0);
    }
  }
  u16* pt = ptL[w];
  #pragma unroll
  for (int mf = 0; mf < 8; ++mf){
    const int kb = mf * 16 + g * 4;
    const float z0 = zL[kb], z1 = zL[kb + 1], z2 = zL[kb + 2], z3 = zL[kb + 3];
    #pragma unroll
    for (int nf = 0; nf < 2; ++nf){
      const int nl = nf * 16 + r15;
      u32 lo = (u32)f2bf(__expf(acc[mf][nf][0]) * z0) |
               ((u32)f2bf(__expf(acc[mf][nf][1]) * z1) << 16);
      u32 hi = (u32)f2bf(__expf(acc[mf][nf][2]) * z2) |
               ((u32)f2bf(__expf(acc[mf][nf][3]) * z3) << 16);
      u32x2 pkd = { lo, hi };
      *(u32x2*)(pt + nl * 132 + kb) = pkd;
    }
  }
  fx4 o[2][4] = {};
  #pragma unroll
  for (int ks = 0; ks < 4; ++ks){
    bf16x8 bv[4];
    #pragma unroll
    for (int nf = 0; nf < 4; ++nf)
      bv[nf] = *(const bf16x8*)(pvh + (long)(nf * 16 + r15) * 128 + ks * 32 + g * 8);
    #pragma unroll
    for (int mf = 0; mf < 2; ++mf){
      bf16x8 pa = *(const bf16x8*)(pt + (mf * 16 + r15) * 132 + ks * 32 + g * 8);
      #pragma unroll
      for (int nf = 0; nf < 4; ++nf)
        o[mf][nf] = __builtin_amdgcn_mfma_f32_16x16x32_bf16(pa, bv[nf], o[mf][nf], 0, 0, 0);
    }
  }
  u16* og = outh + ((long)b * 2048 + n0) * 1024 + h * 64;
  #pragma unroll
  for (int mf = 0; mf < 2; ++mf)
    #pragma unroll
    for (int nf = 0; nf < 4; ++nf)
      #pragma unroll
      for (int r = 0; r < 4; ++r){
        int nl = mf * 16 + g * 4 + r;
        og[(long)nl * 1024 + nf * 16 + r15] = f2bf(o[mf][nf][r]);
      }
}

extern "C" void kernel_launch(void* const* d_in, const int* in_sizes, int n_in,
                              void* d_out, int out_size, void* d_ws, size_t ws_size,
                              hipStream_t stream)
{
  const float* q   = (const float*)d_in[0];
  const float* k   = (const float*)d_in[1];
  const float* v   = (const float*)d_in[2];
  const float* Wq  = (const float*)d_in[3];
  const float* bq  = (const float*)d_in[4];
  const float* Wk  = (const float*)d_in[5];
  const float* bk  = (const float*)d_in[6];
  const float* Wv  = (const float*)d_in[7];
  const float* bv  = (const float*)d_in[8];
  const float* pjk = (const float*)d_in[9];
  const float* pjv = (const float*)d_in[10];
  const float* Wo  = (const float*)d_in[11];
  const float* bo  = (const float*)d_in[12];

  if (ws_size < 152044544u) return;

  char* ws = (char*)d_ws;
  u16*  q_bf  = (u16*)(ws + 0);            // 32MB (reused by outh)
  u16*  kT    = (u16*)(ws + 33554432);     // 32MB (reused by invZ)
  u16*  vT    = (u16*)(ws + 67108864);     // 32MB
  u16*  W_bf  = (u16*)(ws + 100663296);    // 4 x 1Mi elems: Wq,Wk,Wv,Wo
  u16*  projT = (u16*)(ws + 109051904);    // projkT [128][2048], projvT after
  float* sk   = (float*)(ws + 110100480);
  float* sv   = (float*)(ws + 110100992);
  u16*  qp    = (u16*)(ws + 110101504);    // 32MB [16384,1024]
  u16*  ck    = (u16*)(ws + 143655936);    // [2][8][128][1024]
  u16*  pk    = (u16*)(ws + 147850240);    // [8][128][1024], pre-scaled 1/8
  u16*  pvT   = (u16*)(ws + 149947392);    // [8][16][64][128]
  float* invZ = (float*)(ws + 33554432);   // overlay kT (free after ck GEMM)
  u16*  outh  = (u16*)(ws + 0);            // overlay q_bf
  u16*  Wq_bf = W_bf, *Wk_bf = W_bf + 1048576, *Wv_bf = W_bf + 2097152, *Wo_bf = W_bf + 3145728;

  k_zero<<<1, 256, 0, stream>>>(sk, 256);

  k_f2bf<<<2048, 256, 0, stream>>>(q, q_bf, 2097152);
  k_f2bfW<<<dim3(128,4), 256, 0, stream>>>(Wq, Wk, Wv, Wo, W_bf);
  k_tconv<<<dim3(16,32,8), 256, 0, stream>>>(k, kT, 2048, 1024, 2097152, 2097152, nullptr);
  k_tconv<<<dim3(16,32,8), 256, 0, stream>>>(v, vT, 2048, 1024, 2097152, 2097152, nullptr);
  k_tconv<<<dim3(2,32,1),  256, 0, stream>>>(pjk, projT,          2048, 128, 0, 0, sk);
  k_tconv<<<dim3(2,32,1),  256, 0, stream>>>(pjv, projT + 262144, 2048, 128, 0, 0, sv);

  // qp = q @ Wq^T + bq   (256x256 4-phase kernel, grid 256 = 1 block/CU)
  k_gemm256b<1,u16><<<dim3(4,64), 512, 0, stream>>>(
      q_bf,1024, Wq_bf,1024, qp,1024, 1024, bq);
  // ck = projkT @ k^T ; cv = projvT @ v^T  (BN=64 -> 256 blocks)
  k_gemm<128,64,3,0,u16><<<dim3(16,1,16), 256, 0, stream>>>(
      projT,2048,0, kT,2048,0, ck,1024,0, 2048, nullptr, nullptr, 1.f);
  // pk = (ck @ Wk^T + sk (x) bk) / 8
  k_gemm<128,128,0,2,u16><<<dim3(8,1,8), 256, 0, stream>>>(
      ck,1024,131072, Wk_bf,1024,0, pk,1024,131072, 1024, bk, sk, 0.125f);
  // pvT = (cv @ Wv^T + sv (x) bv), transposed write
  k_gemm<128,128,0,3,u16><<<dim3(8,1,8), 256, 0, stream>>>(
      ck + 1048576,1024,131072, Wv_bf,1024,0, pvT,0,131072, 1024, bv, sv, 1.f);
  // fused attention
  k_stats<<<128, 512, 0, stream>>>(pk, qp, invZ);
  k_attn<<<dim3(16,128), 256, 0, stream>>>(pk, qp, pvT, invZ, outh);
  // final = outh @ Wo^T + bo -> fp32 d_out
  k_gemm256b<1,float><<<dim3(4,64), 512, 0, stream>>>(
      outh,1024, Wo_bf,1024, (float*)d_out,1024, 1024, bo);
}

// Round 6
// 267.720 us; speedup vs baseline: 1.4157x; 1.0617x over previous
//
#include <hip/hip_runtime.h>

typedef unsigned short u16;
typedef unsigned int   u32;
typedef __attribute__((ext_vector_type(4))) float fx4;
typedef __attribute__((ext_vector_type(8))) __bf16 bf16x8;
typedef __attribute__((ext_vector_type(8))) unsigned short us8;
typedef __attribute__((ext_vector_type(2))) unsigned int u32x2;

#define FENCE asm volatile("" ::: "memory")

__device__ __forceinline__ u16 f2bf(float x){
  u32 u = __builtin_bit_cast(u32, x);
  u += 0x7fffu + ((u >> 16) & 1u);
  return (u16)(u >> 16);
}
__device__ __forceinline__ float b2f(u16 h){
  u32 u = ((u32)h) << 16;
  return __builtin_bit_cast(float, u);
}
__device__ __forceinline__ void gld16(const void* g, void* l){
  __builtin_amdgcn_global_load_lds(
      (const __attribute__((address_space(1))) u32*)g,
      (__attribute__((address_space(3))) u32*)l, 16, 0, 0);
}
// XCD-chunked bijective swizzle (grid size must be %8==0).
__device__ __forceinline__ void xcd_remap(u32& bx, u32& by, u32& bz){
  u32 nx = gridDim.x, ny = gridDim.y, nz = gridDim.z;
  u32 nwg = nx * ny * nz;
  u32 orig = (blockIdx.z * ny + blockIdx.y) * nx + blockIdx.x;
  u32 lid = (orig & 7u) * (nwg >> 3) + (orig >> 3);
  bx = lid % nx;
  u32 rem = lid / nx;
  by = rem % ny;
  bz = rem / ny;
}

// ---------------- fp32 -> bf16 convert (vectorized, grid-stride) ----------------
__global__ __launch_bounds__(256) void k_f2bf(const float* __restrict__ in,
                                              u16* __restrict__ out, int n8){
  int i = blockIdx.x * 256 + threadIdx.x;
  const int stride = gridDim.x * 256;
  for (; i < n8; i += stride){
    const float4* p = (const float4*)in + (long)i * 2;
    float4 a = p[0], b = p[1];
    us8 o = { f2bf(a.x), f2bf(a.y), f2bf(a.z), f2bf(a.w),
              f2bf(b.x), f2bf(b.y), f2bf(b.z), f2bf(b.w) };
    *((us8*)out + i) = o;
  }
}

// four 1024x1024 weights in one launch; dst slabs contiguous (1Mi elems apart)
__global__ __launch_bounds__(256) void k_f2bfW(const float* __restrict__ w0,
                                               const float* __restrict__ w1,
                                               const float* __restrict__ w2,
                                               const float* __restrict__ w3,
                                               u16* __restrict__ out){
  const float* src = blockIdx.y == 0 ? w0 : blockIdx.y == 1 ? w1 :
                     blockIdx.y == 2 ? w2 : w3;
  u16* dst = out + (long)blockIdx.y * 1048576;
  int i = blockIdx.x * 256 + threadIdx.x;
  const int stride = gridDim.x * 256;
  for (; i < 131072; i += stride){
    const float4* p = (const float4*)src + (long)i * 2;
    float4 a = p[0], b = p[1];
    us8 o = { f2bf(a.x), f2bf(a.y), f2bf(a.z), f2bf(a.w),
              f2bf(b.x), f2bf(b.y), f2bf(b.z), f2bf(b.w) };
    *((us8*)dst + i) = o;
  }
}

__global__ void k_zero(float* p, int n){
  int i = blockIdx.x * 256 + threadIdx.x;
  if (i < n) p[i] = 0.f;
}

// ---------------- transpose + convert: in [R,C] f32 -> out [C,R] bf16 ----------------
__global__ __launch_bounds__(256) void k_tconv(const float* __restrict__ in,
                                               u16* __restrict__ out,
                                               int R, int C, long sIn, long sOut,
                                               float* __restrict__ colsum){
  in  += (long)blockIdx.z * sIn;
  out += (long)blockIdx.z * sOut;
  const int c0 = blockIdx.x * 64, r0 = blockIdx.y * 64;
  __shared__ u16 tile[64][66];
  __shared__ float red[256];
  const int t = threadIdx.x;
  const int cc = t & 63, wq = t >> 6;
  float part = 0.f;
  #pragma unroll
  for (int i = 0; i < 16; ++i){
    int rr = i * 4 + wq;
    float v = in[(long)(r0 + rr) * C + c0 + cc];
    tile[rr][cc] = f2bf(v);
    part += v;
  }
  if (colsum){
    red[t] = part;
    __syncthreads();
    if (t < 64){
      float s = red[t] + red[t + 64] + red[t + 128] + red[t + 192];
      atomicAdd(&colsum[c0 + t], s);
    }
  }
  __syncthreads();
  const int oc0 = t >> 5, jb = (t & 31) * 2;
  #pragma unroll
  for (int i = 0; i < 8; ++i){
    int oc = oc0 + i * 8;
    u32 pk2 = (u32)tile[jb][oc] | ((u32)tile[jb + 1][oc] << 16);
    *(u32*)(out + (long)(c0 + oc) * R + r0 + jb) = pk2;
  }
}

// ---------------- BT-layout MFMA GEMM (small/batched shapes) ----------------
template<int BM, int BN, int MODE, int EPI, typename OutT>
__global__ __launch_bounds__(256) void k_gemm(
    const u16* __restrict__ A, int lda, long sAz,
    const u16* __restrict__ B, int ldb, long sBz,
    OutT* __restrict__ C, int ldc, long sCz,
    int K, const float* __restrict__ bias, const float* __restrict__ srow, float scale)
{
  constexpr int BK = 64;
  constexpr int FM = BM / 32, FN = BN / 32;
  __shared__ u16 ldsA[BM * BK];
  __shared__ u16 ldsB[BN * BK];
  u32 bx, by, bz;
  xcd_remap(bx, by, bz);
  const long z = bz;
  if constexpr (MODE == 0){ A += z * sAz; B += z * sBz; C += z * sCz; }
  if constexpr (MODE == 3){ long p = z >> 3, bb = z & 7;
                            A += p * 262144; B += p * 16777216 + bb * 2097152;
                            C += p * 1048576 + bb * 131072; }
  const int t = threadIdx.x;
  const int lane = t & 63;
  const int w = t >> 6, wm = w >> 1, wn = w & 1;
  const int r15 = lane & 15, g = lane >> 4;
  const int m0 = by * BM, n0 = bx * BN;
  fx4 acc[FM][FN] = {};
  constexpr int CA = BM * BK / (8 * 256);
  constexpr int CB = BN * BK / (8 * 256);
  for (int kt = 0; kt < K; kt += BK){
    #pragma unroll
    for (int i = 0; i < CA; ++i){
      int ch = i * 256 + t, row = ch >> 3, cc = ch & 7;
      gld16(A + (long)(m0 + row) * lda + kt + cc * 8, (char*)ldsA + ch * 16);
    }
    #pragma unroll
    for (int i = 0; i < CB; ++i){
      int ch = i * 256 + t, row = ch >> 3, cc = ch & 7;
      gld16(B + (long)(n0 + row) * ldb + kt + cc * 8, (char*)ldsB + ch * 16);
    }
    __syncthreads();
    #pragma unroll
    for (int ks = 0; ks < 2; ++ks){
      bf16x8 af[FM], bfv[FN];
      #pragma unroll
      for (int mf = 0; mf < FM; ++mf)
        af[mf] = *(const bf16x8*)&ldsA[(wm * (BM/2) + mf * 16 + r15) * BK + ks * 32 + g * 8];
      #pragma unroll
      for (int nf = 0; nf < FN; ++nf)
        bfv[nf] = *(const bf16x8*)&ldsB[(wn * (BN/2) + nf * 16 + r15) * BK + ks * 32 + g * 8];
      #pragma unroll
      for (int mf = 0; mf < FM; ++mf)
        #pragma unroll
        for (int nf = 0; nf < FN; ++nf)
          acc[mf][nf] = __builtin_amdgcn_mfma_f32_16x16x32_bf16(af[mf], bfv[nf], acc[mf][nf], 0, 0, 0);
    }
    __syncthreads();
  }
  #pragma unroll
  for (int mf = 0; mf < FM; ++mf){
    #pragma unroll
    for (int nf = 0; nf < FN; ++nf){
      const int row0 = m0 + wm * (BM/2) + mf * 16 + g * 4;
      const int col  = n0 + wn * (BN/2) + nf * 16 + r15;
      float vv[4];
      #pragma unroll
      for (int r = 0; r < 4; ++r){
        float v = acc[mf][nf][r];
        if constexpr (EPI == 1) v += bias[col];
        if constexpr (EPI == 2) v = (v + srow[row0 + r] * bias[col]) * scale;
        if constexpr (EPI == 3) v = v + srow[row0 + r] * bias[col];
        vv[r] = v;
      }
      if constexpr (EPI == 3){
        u32 lo = (u32)f2bf(vv[0]) | ((u32)f2bf(vv[1]) << 16);
        u32 hi = (u32)f2bf(vv[2]) | ((u32)f2bf(vv[3]) << 16);
        u32x2 pk2 = { lo, hi };
        *(u32x2*)((u16*)C + (long)col * 128 + row0) = pk2;
      } else {
        #pragma unroll
        for (int r = 0; r < 4; ++r){
          if constexpr (sizeof(OutT) == 2) C[(long)(row0 + r) * ldc + col] = (OutT)f2bf(vv[r]);
          else                             C[(long)(row0 + r) * ldc + col] = (OutT)vv[r];
        }
      }
    }
  }
}

// ---------------- big GEMM: 256x256 tile, m201-style 8-phase schedule ----------------
// C[M,N]=A[M,K]*B[N,K]^T (+bias). 512 thr = 8 waves (2Mx4N), wave tile 128x64.
// 2 K-tiles/iter, 4 phases/K-tile, 2 barriers/phase:
//   {ds_read frags; stage; [lgkmcnt(8)]; BAR; lgkmcnt(0)+sched_barrier; 16 MFMA; BAR}
// Stage slots (slab-safe, derived): p1:Ahi(j1)->buf h^1; p3:Blo(j2)->buf h;
//   p4:Bhi(j2)+Alo(j2)->buf h.  vmcnt(6) only at p4 (after MFMA), once per K-tile.
// Invariant: enter each half with exactly 3 half-tiles (6 loads) in flight.
template<int EPI, typename OutT>
__global__ __launch_bounds__(512, 1) void k_gemm256b(
    const u16* __restrict__ A, int lda,
    const u16* __restrict__ B, int ldb,
    OutT* __restrict__ C, int ldc,
    int K, const float* __restrict__ bias)
{
  constexpr int BM = 256, BN = 256, BK = 64;
  __shared__ u16 ldsA[2][BM * BK];
  __shared__ u16 ldsB[2][BN * BK];
  u32 bx, by, bz;
  xcd_remap(bx, by, bz);
  const int m0 = by * BM, n0 = bx * BN;
  const int t = threadIdx.x, lane = t & 63, w = t >> 6;
  const int wm = w >> 2, wn = w & 3;
  const int r15 = lane & 15, g = lane >> 4;
  const int NT = K >> 6;

  auto stA = [&](int buf, int half, int kt){
    #pragma unroll
    for (int j = 0; j < 2; ++j){
      int ch = j * 512 + t, row = ch >> 3, cc = ch & 7;
      gld16(A + (long)(m0 + half * 128 + row) * lda + kt + ((cc ^ (row & 7)) * 8),
            (char*)ldsA[buf] + half * 16384 + ch * 16);
    }
  };
  auto stB = [&](int buf, int half, int kt){
    #pragma unroll
    for (int j = 0; j < 2; ++j){
      int ch = j * 512 + t, row = ch >> 3, cc = ch & 7;
      gld16(B + (long)(n0 + half * 128 + row) * ldb + kt + ((cc ^ (row & 7)) * 8),
            (char*)ldsB[buf] + half * 16384 + ch * 16);
    }
  };

  // prologue: T0 fully (8 loads), T1 Blo,Bhi,Alo (6 loads); T1.Ahi comes at p1.
  stB(0,0,0); stB(0,1,0); stA(0,0,0); stA(0,1,0);
  stB(1,0,BK); stB(1,1,BK); stA(1,0,BK);
  asm volatile("s_waitcnt vmcnt(6)" ::: "memory");
  FENCE; __builtin_amdgcn_s_barrier(); FENCE;

  fx4 acc[8][4] = {};
  const int NIT = NT >> 1;
  for (int i = 0; i < NIT; ++i){
    #pragma unroll
    for (int h = 0; h < 2; ++h){
      const char* bA = (const char*)ldsA[h];
      const char* bB = (const char*)ldsB[h];
      const int j1 = 2 * i + 1 + h, j2 = 2 * i + 2 + h;
      const bool p2f = (j2 < NT);
      bf16x8 a[2][4], b01[2][2], b23[2][2];
      // ---- p1: ds A(mf0-3)+B(nf0-1) [12]; stage Ahi(j1); MFMA Q(0-3,0-1)
      #pragma unroll
      for (int ks = 0; ks < 2; ++ks)
        #pragma unroll
        for (int mf = 0; mf < 4; ++mf)
          a[ks][mf] = *(const bf16x8*)(bA + (wm * 128 + mf * 16 + r15) * 128 +
                                       (((ks * 4 + g) ^ (r15 & 7)) * 16));
      #pragma unroll
      for (int ks = 0; ks < 2; ++ks)
        #pragma unroll
        for (int nf = 0; nf < 2; ++nf)
          b01[ks][nf] = *(const bf16x8*)(bB + (wn * 64 + nf * 16 + r15) * 128 +
                                         (((ks * 4 + g) ^ (r15 & 7)) * 16));
      if (j1 < NT) stA(h ^ 1, 1, j1 * BK);
      asm volatile("s_waitcnt lgkmcnt(8)" ::: "memory");
      FENCE; __builtin_amdgcn_s_barrier(); FENCE;
      asm volatile("s_waitcnt lgkmcnt(0)" ::: "memory");
      __builtin_amdgcn_sched_barrier(0);
      __builtin_amdgcn_s_setprio(1);
      #pragma unroll
      for (int ks = 0; ks < 2; ++ks)
        #pragma unroll
        for (int mf = 0; mf < 4; ++mf)
          #pragma unroll
          for (int nf = 0; nf < 2; ++nf)
            acc[mf][nf] = __builtin_amdgcn_mfma_f32_16x16x32_bf16(a[ks][mf], b01[ks][nf], acc[mf][nf], 0, 0, 0);
      __builtin_amdgcn_s_setprio(0);
      FENCE; __builtin_amdgcn_s_barrier(); FENCE;
      // ---- p2: ds B(nf2-3) [4]; MFMA Q(0-3,2-3)
      #pragma unroll
      for (int ks = 0; ks < 2; ++ks)
        #pragma unroll
        for (int nf = 0; nf < 2; ++nf)
          b23[ks][nf] = *(const bf16x8*)(bB + (wn * 64 + (nf + 2) * 16 + r15) * 128 +
                                         (((ks * 4 + g) ^ (r15 & 7)) * 16));
      FENCE; __builtin_amdgcn_s_barrier(); FENCE;
      asm volatile("s_waitcnt lgkmcnt(0)" ::: "memory");
      __builtin_amdgcn_sched_barrier(0);
      __builtin_amdgcn_s_setprio(1);
      #pragma unroll
      for (int ks = 0; ks < 2; ++ks)
        #pragma unroll
        for (int mf = 0; mf < 4; ++mf)
          #pragma unroll
          for (int nf = 0; nf < 2; ++nf)
            acc[mf][nf + 2] = __builtin_amdgcn_mfma_f32_16x16x32_bf16(a[ks][mf], b23[ks][nf], acc[mf][nf + 2], 0, 0, 0);
      __builtin_amdgcn_s_setprio(0);
      FENCE; __builtin_amdgcn_s_barrier(); FENCE;
      // ---- p3: ds A(mf4-7) [8]; stage Blo(j2); MFMA Q(4-7,2-3)
      #pragma unroll
      for (int ks = 0; ks < 2; ++ks)
        #pragma unroll
        for (int mf = 0; mf < 4; ++mf)
          a[ks][mf] = *(const bf16x8*)(bA + (wm * 128 + (mf + 4) * 16 + r15) * 128 +
                                       (((ks * 4 + g) ^ (r15 & 7)) * 16));
      if (p2f) stB(h, 0, j2 * BK);
      FENCE; __builtin_amdgcn_s_barrier(); FENCE;
      asm volatile("s_waitcnt lgkmcnt(0)" ::: "memory");
      __builtin_amdgcn_sched_barrier(0);
      __builtin_amdgcn_s_setprio(1);
      #pragma unroll
      for (int ks = 0; ks < 2; ++ks)
        #pragma unroll
        for (int mf = 0; mf < 4; ++mf)
          #pragma unroll
          for (int nf = 0; nf < 2; ++nf)
            acc[mf + 4][nf + 2] = __builtin_amdgcn_mfma_f32_16x16x32_bf16(a[ks][mf], b23[ks][nf], acc[mf + 4][nf + 2], 0, 0, 0);
      __builtin_amdgcn_s_setprio(0);
      FENCE; __builtin_amdgcn_s_barrier(); FENCE;
      // ---- p4: stage Bhi(j2)+Alo(j2); MFMA Q(4-7,0-1); counted vm-wait
      if (p2f){ stB(h, 1, j2 * BK); stA(h, 0, j2 * BK); }
      FENCE; __builtin_amdgcn_s_barrier(); FENCE;
      __builtin_amdgcn_s_setprio(1);
      #pragma unroll
      for (int ks = 0; ks < 2; ++ks)
        #pragma unroll
        for (int mf = 0; mf < 4; ++mf)
          #pragma unroll
          for (int nf = 0; nf < 2; ++nf)
            acc[mf + 4][nf] = __builtin_amdgcn_mfma_f32_16x16x32_bf16(a[ks][mf], b01[ks][nf], acc[mf + 4][nf], 0, 0, 0);
      __builtin_amdgcn_s_setprio(0);
      if (p2f) { asm volatile("s_waitcnt vmcnt(6)" ::: "memory"); }
      else     { asm volatile("s_waitcnt vmcnt(0)" ::: "memory"); }
      FENCE; __builtin_amdgcn_s_barrier(); FENCE;
    }
  }

  #pragma unroll
  for (int mf = 0; mf < 8; ++mf)
    #pragma unroll
    for (int nf = 0; nf < 4; ++nf){
      const int row0 = m0 + wm * 128 + mf * 16 + g * 4;
      const int col  = n0 + wn * 64 + nf * 16 + r15;
      float bcol = 0.f;
      if constexpr (EPI == 1) bcol = bias[col];
      #pragma unroll
      for (int r = 0; r < 4; ++r){
        float vv = acc[mf][nf][r] + bcol;
        if constexpr (sizeof(OutT) == 2) C[(long)(row0 + r) * ldc + col] = (OutT)f2bf(vv);
        else                             C[(long)(row0 + r) * ldc + col] = (OutT)vv;
      }
    }
}

// ---------------- fused attention, pass 1: Z[k] = sum_n exp(s[k,n]) ----------------
__global__ __launch_bounds__(512) void k_stats(const u16* __restrict__ pk,
                                               const u16* __restrict__ qp,
                                               float* __restrict__ invZ){
  const int z = blockIdx.x;
  const int b = z >> 4, h = z & 15;
  const u16* pkh = pk + b * 131072 + h * 64;
  const u16* qph = qp + (long)z * 131072;
  __shared__ u16 pkL[128 * 64];
  __shared__ float zred[8][128];
  const int t = threadIdx.x, lane = t & 63, w = t >> 6;
  const int r15 = lane & 15, g = lane >> 4;
  #pragma unroll
  for (int i = 0; i < 2; ++i){
    int ch = i * 512 + t, row = ch >> 3, cc = ch & 7;
    int csrc = cc ^ (row & 7);
    gld16(pkh + (long)row * 1024 + csrc * 8, (char*)pkL + ch * 16);
  }
  __syncthreads();
  float zacc[8][4] = {};
  for (int c = 0; c < 8; ++c){
    const int n0 = w * 256 + c * 32;
    fx4 acc[8][2] = {};
    #pragma unroll
    for (int ks = 0; ks < 2; ++ks){
      bf16x8 bq[2];
      #pragma unroll
      for (int nf = 0; nf < 2; ++nf)
        bq[nf] = *(const bf16x8*)(qph + (long)(n0 + nf * 16 + r15) * 64 + ks * 32 + g * 8);
      #pragma unroll
      for (int mf = 0; mf < 8; ++mf){
        int row = mf * 16 + r15;
        int x = (ks * 4 + g) ^ (row & 7);
        bf16x8 a = *(const bf16x8*)((const char*)pkL + row * 128 + x * 16);
        #pragma unroll
        for (int nf = 0; nf < 2; ++nf)
          acc[mf][nf] = __builtin_amdgcn_mfma_f32_16x16x32_bf16(a, bq[nf], acc[mf][nf], 0, 0, 0);
      }
    }
    #pragma unroll
    for (int mf = 0; mf < 8; ++mf)
      #pragma unroll
      for (int nf = 0; nf < 2; ++nf)
        #pragma unroll
        for (int r = 0; r < 4; ++r)
          zacc[mf][r] += __expf(acc[mf][nf][r]);
  }
  #pragma unroll
  for (int mf = 0; mf < 8; ++mf)
    #pragma unroll
    for (int r = 0; r < 4; ++r){
      float v = zacc[mf][r];
      v += __shfl_xor(v, 1); v += __shfl_xor(v, 2);
      v += __shfl_xor(v, 4); v += __shfl_xor(v, 8);
      zacc[mf][r] = v;
    }
  if (r15 == 0){
    #pragma unroll
    for (int mf = 0; mf < 8; ++mf)
      #pragma unroll
      for (int r = 0; r < 4; ++r)
        zred[w][mf * 16 + g * 4 + r] = zacc[mf][r];
  }
  __syncthreads();
  if (t < 128){
    float s = 0.f;
    #pragma unroll
    for (int w2 = 0; w2 < 8; ++w2) s += zred[w2][t];
    invZ[(long)z * 128 + t] = 1.0f / s;
  }
}

// ---------------- fused attention, pass 2: out = attn^T @ pv ----------------
__global__ __launch_bounds__(256) void k_attn(const u16* __restrict__ pk,
                                              const u16* __restrict__ qp,
                                              const u16* __restrict__ pvT,
                                              const float* __restrict__ invZ,
                                              u16* __restrict__ outh){
  u32 bx, by, bz;
  xcd_remap(bx, by, bz);
  const int z = by, nb = bx;
  const int b = z >> 4, h = z & 15;
  const u16* pkh = pk  + b * 131072 + h * 64;
  const u16* qph = qp  + (long)z * 131072;
  const u16* pvh = pvT + b * 131072 + h * 8192;
  const float* zh = invZ + (long)z * 128;
  __shared__ u16 pkL[128 * 64];
  __shared__ u16 ptL[4][32 * 132];
  __shared__ float zL[128];
  const int t = threadIdx.x, lane = t & 63, w = t >> 6;
  const int r15 = lane & 15, g = lane >> 4;
  #pragma unroll
  for (int i = 0; i < 4; ++i){
    int ch = i * 256 + t, row = ch >> 3, cc = ch & 7;
    int csrc = cc ^ (row & 7);
    gld16(pkh + (long)row * 1024 + csrc * 8, (char*)pkL + ch * 16);
  }
  if (t < 128) zL[t] = zh[t];
  __syncthreads();
  const int n0 = nb * 128 + w * 32;
  fx4 acc[8][2] = {};
  #pragma unroll
  for (int ks = 0; ks < 2; ++ks){
    bf16x8 bq[2];
    #pragma unroll
    for (int nf = 0; nf < 2; ++nf)
      bq[nf] = *(const bf16x8*)(qph + (long)(n0 + nf * 16 + r15) * 64 + ks * 32 + g * 8);
    #pragma unroll
    for (int mf = 0; mf < 8; ++mf){
      int row = mf * 16 + r15;
      int x = (ks * 4 + g) ^ (row & 7);
      bf16x8 a = *(const bf16x8*)((const char*)pkL + row * 128 + x * 16);
      #pragma unroll
      for (int nf = 0; nf < 2; ++nf)
        acc[mf][nf] = __builtin_amdgcn_mfma_f32_16x16x32_bf16(a, bq[nf], acc[mf][nf], 0, 0, 0);
    }
  }
  u16* pt = ptL[w];
  #pragma unroll
  for (int mf = 0; mf < 8; ++mf){
    const int kb = mf * 16 + g * 4;
    const float z0 = zL[kb], z1 = zL[kb + 1], z2 = zL[kb + 2], z3 = zL[kb + 3];
    #pragma unroll
    for (int nf = 0; nf < 2; ++nf){
      const int nl = nf * 16 + r15;
      u32 lo = (u32)f2bf(__expf(acc[mf][nf][0]) * z0) |
               ((u32)f2bf(__expf(acc[mf][nf][1]) * z1) << 16);
      u32 hi = (u32)f2bf(__expf(acc[mf][nf][2]) * z2) |
               ((u32)f2bf(__expf(acc[mf][nf][3]) * z3) << 16);
      u32x2 pkd = { lo, hi };
      *(u32x2*)(pt + nl * 132 + kb) = pkd;
    }
  }
  fx4 o[2][4] = {};
  #pragma unroll
  for (int ks = 0; ks < 4; ++ks){
    bf16x8 bv[4];
    #pragma unroll
    for (int nf = 0; nf < 4; ++nf)
      bv[nf] = *(const bf16x8*)(pvh + (long)(nf * 16 + r15) * 128 + ks * 32 + g * 8);
    #pragma unroll
    for (int mf = 0; mf < 2; ++mf){
      bf16x8 pa = *(const bf16x8*)(pt + (mf * 16 + r15) * 132 + ks * 32 + g * 8);
      #pragma unroll
      for (int nf = 0; nf < 4; ++nf)
        o[mf][nf] = __builtin_amdgcn_mfma_f32_16x16x32_bf16(pa, bv[nf], o[mf][nf], 0, 0, 0);
    }
  }
  u16* og = outh + ((long)b * 2048 + n0) * 1024 + h * 64;
  #pragma unroll
  for (int mf = 0; mf < 2; ++mf)
    #pragma unroll
    for (int nf = 0; nf < 4; ++nf)
      #pragma unroll
      for (int r = 0; r < 4; ++r){
        int nl = mf * 16 + g * 4 + r;
        og[(long)nl * 1024 + nf * 16 + r15] = f2bf(o[mf][nf][r]);
      }
}

extern "C" void kernel_launch(void* const* d_in, const int* in_sizes, int n_in,
                              void* d_out, int out_size, void* d_ws, size_t ws_size,
                              hipStream_t stream)
{
  const float* q   = (const float*)d_in[0];
  const float* k   = (const float*)d_in[1];
  const float* v   = (const float*)d_in[2];
  const float* Wq  = (const float*)d_in[3];
  const float* bq  = (const float*)d_in[4];
  const float* Wk  = (const float*)d_in[5];
  const float* bk  = (const float*)d_in[6];
  const float* Wv  = (const float*)d_in[7];
  const float* bv  = (const float*)d_in[8];
  const float* pjk = (const float*)d_in[9];
  const float* pjv = (const float*)d_in[10];
  const float* Wo  = (const float*)d_in[11];
  const float* bo  = (const float*)d_in[12];

  if (ws_size < 152044544u) return;

  char* ws = (char*)d_ws;
  u16*  q_bf  = (u16*)(ws + 0);            // 32MB (reused by outh)
  u16*  kT    = (u16*)(ws + 33554432);     // 32MB (reused by invZ)
  u16*  vT    = (u16*)(ws + 67108864);     // 32MB
  u16*  W_bf  = (u16*)(ws + 100663296);    // 4 x 1Mi elems: Wq,Wk,Wv,Wo
  u16*  projT = (u16*)(ws + 109051904);    // projkT [128][2048], projvT after
  float* sk   = (float*)(ws + 110100480);
  float* sv   = (float*)(ws + 110100992);
  u16*  qp    = (u16*)(ws + 110101504);    // 32MB [16384,1024]
  u16*  ck    = (u16*)(ws + 143655936);    // [2][8][128][1024]
  u16*  pk    = (u16*)(ws + 147850240);    // [8][128][1024], pre-scaled 1/8
  u16*  pvT   = (u16*)(ws + 149947392);    // [8][16][64][128]
  float* invZ = (float*)(ws + 33554432);   // overlay kT (free after ck GEMM)
  u16*  outh  = (u16*)(ws + 0);            // overlay q_bf
  u16*  Wq_bf = W_bf, *Wk_bf = W_bf + 1048576, *Wv_bf = W_bf + 2097152, *Wo_bf = W_bf + 3145728;

  k_zero<<<1, 256, 0, stream>>>(sk, 256);

  k_f2bf<<<2048, 256, 0, stream>>>(q, q_bf, 2097152);
  k_f2bfW<<<dim3(128,4), 256, 0, stream>>>(Wq, Wk, Wv, Wo, W_bf);
  k_tconv<<<dim3(16,32,8), 256, 0, stream>>>(k, kT, 2048, 1024, 2097152, 2097152, nullptr);
  k_tconv<<<dim3(16,32,8), 256, 0, stream>>>(v, vT, 2048, 1024, 2097152, 2097152, nullptr);
  k_tconv<<<dim3(2,32,1),  256, 0, stream>>>(pjk, projT,          2048, 128, 0, 0, sk);
  k_tconv<<<dim3(2,32,1),  256, 0, stream>>>(pjv, projT + 262144, 2048, 128, 0, 0, sv);

  // qp = q @ Wq^T + bq   (256x256 8-phase kernel, grid 256 = 1 block/CU)
  k_gemm256b<1,u16><<<dim3(4,64), 512, 0, stream>>>(
      q_bf,1024, Wq_bf,1024, qp,1024, 1024, bq);
  // ck = projkT @ k^T ; cv = projvT @ v^T  (BN=64 -> 256 blocks)
  k_gemm<128,64,3,0,u16><<<dim3(16,1,16), 256, 0, stream>>>(
      projT,2048,0, kT,2048,0, ck,1024,0, 2048, nullptr, nullptr, 1.f);
  // pk = (ck @ Wk^T + sk (x) bk) / 8   (64x64 tile -> 256 blocks)
  k_gemm<64,64,0,2,u16><<<dim3(16,2,8), 256, 0, stream>>>(
      ck,1024,131072, Wk_bf,1024,0, pk,1024,131072, 1024, bk, sk, 0.125f);
  // pvT = (cv @ Wv^T + sv (x) bv), transposed write (64x64 tile -> 256 blocks)
  k_gemm<64,64,0,3,u16><<<dim3(16,2,8), 256, 0, stream>>>(
      ck + 1048576,1024,131072, Wv_bf,1024,0, pvT,0,131072, 1024, bv, sv, 1.f);
  // fused attention
  k_stats<<<128, 512, 0, stream>>>(pk, qp, invZ);
  k_attn<<<dim3(16,128), 256, 0, stream>>>(pk, qp, pvT, invZ, outh);
  // final = outh @ Wo^T + bo -> fp32 d_out
  k_gemm256b<1,float><<<dim3(4,64), 512, 0, stream>>>(
      outh,1024, Wo_bf,1024, (float*)d_out,1024, 1024, bo);
}

// Round 7
// 250.367 us; speedup vs baseline: 1.5139x; 1.0693x over previous
//
#include <hip/hip_runtime.h>

typedef unsigned short u16;
typedef unsigned int   u32;
typedef __attribute__((ext_vector_type(4))) float fx4;
typedef __attribute__((ext_vector_type(8))) __bf16 bf16x8;
typedef __attribute__((ext_vector_type(8))) unsigned short us8;
typedef __attribute__((ext_vector_type(2))) unsigned int u32x2;

__device__ __forceinline__ u16 f2bf(float x){
  u32 u = __builtin_bit_cast(u32, x);
  u += 0x7fffu + ((u >> 16) & 1u);
  return (u16)(u >> 16);
}
__device__ __forceinline__ float b2f(u16 h){
  u32 u = ((u32)h) << 16;
  return __builtin_bit_cast(float, u);
}
__device__ __forceinline__ void gld16(const void* g, void* l){
  __builtin_amdgcn_global_load_lds(
      (const __attribute__((address_space(1))) u32*)g,
      (__attribute__((address_space(3))) u32*)l, 16, 0, 0);
}
// XCD-chunked bijective swizzle (grid size must be %8==0).
__device__ __forceinline__ void xcd_remap(u32& bx, u32& by, u32& bz){
  u32 nx = gridDim.x, ny = gridDim.y, nz = gridDim.z;
  u32 nwg = nx * ny * nz;
  u32 orig = (blockIdx.z * ny + blockIdx.y) * nx + blockIdx.x;
  u32 lid = (orig & 7u) * (nwg >> 3) + (orig >> 3);
  bx = lid % nx;
  u32 rem = lid / nx;
  by = rem % ny;
  bz = rem / ny;
}

// ---------------- fp32 -> bf16 convert (vectorized, grid-stride) ----------------
__global__ __launch_bounds__(256) void k_f2bf(const float* __restrict__ in,
                                              u16* __restrict__ out, int n8){
  int i = blockIdx.x * 256 + threadIdx.x;
  const int stride = gridDim.x * 256;
  for (; i < n8; i += stride){
    const float4* p = (const float4*)in + (long)i * 2;
    float4 a = p[0], b = p[1];
    us8 o = { f2bf(a.x), f2bf(a.y), f2bf(a.z), f2bf(a.w),
              f2bf(b.x), f2bf(b.y), f2bf(b.z), f2bf(b.w) };
    *((us8*)out + i) = o;
  }
}

// four 1024x1024 weights in one launch; dst slabs contiguous (1Mi elems apart)
__global__ __launch_bounds__(256) void k_f2bfW(const float* __restrict__ w0,
                                               const float* __restrict__ w1,
                                               const float* __restrict__ w2,
                                               const float* __restrict__ w3,
                                               u16* __restrict__ out){
  const float* src = blockIdx.y == 0 ? w0 : blockIdx.y == 1 ? w1 :
                     blockIdx.y == 2 ? w2 : w3;
  u16* dst = out + (long)blockIdx.y * 1048576;
  int i = blockIdx.x * 256 + threadIdx.x;
  const int stride = gridDim.x * 256;
  for (; i < 131072; i += stride){
    const float4* p = (const float4*)src + (long)i * 2;
    float4 a = p[0], b = p[1];
    us8 o = { f2bf(a.x), f2bf(a.y), f2bf(a.z), f2bf(a.w),
              f2bf(b.x), f2bf(b.y), f2bf(b.z), f2bf(b.w) };
    *((us8*)dst + i) = o;
  }
}

__global__ void k_zero(float* p, int n){
  int i = blockIdx.x * 256 + threadIdx.x;
  if (i < n) p[i] = 0.f;
}

// ---------------- transpose + convert (proj only): [R,C] f32 -> [C,R] bf16 -------
__global__ __launch_bounds__(256) void k_tconv(const float* __restrict__ in,
                                               u16* __restrict__ out,
                                               int R, int C, long sIn, long sOut,
                                               float* __restrict__ colsum){
  in  += (long)blockIdx.z * sIn;
  out += (long)blockIdx.z * sOut;
  const int c0 = blockIdx.x * 64, r0 = blockIdx.y * 64;
  __shared__ u16 tile[64][66];
  __shared__ float red[256];
  const int t = threadIdx.x;
  const int cc = t & 63, wq = t >> 6;
  float part = 0.f;
  #pragma unroll
  for (int i = 0; i < 16; ++i){
    int rr = i * 4 + wq;
    float v = in[(long)(r0 + rr) * C + c0 + cc];
    tile[rr][cc] = f2bf(v);
    part += v;
  }
  if (colsum){
    red[t] = part;
    __syncthreads();
    if (t < 64){
      float s = red[t] + red[t + 64] + red[t + 128] + red[t + 192];
      atomicAdd(&colsum[c0 + t], s);
    }
  }
  __syncthreads();
  const int oc0 = t >> 5, jb = (t & 31) * 2;
  #pragma unroll
  for (int i = 0; i < 8; ++i){
    int oc = oc0 + i * 8;
    u32 pk2 = (u32)tile[jb][oc] | ((u32)tile[jb + 1][oc] << 16);
    *(u32*)(out + (long)(c0 + oc) * R + r0 + jb) = pk2;
  }
}

// ---------------- BT-layout MFMA GEMM (small/batched shapes) ----------------
template<int BM, int BN, int MODE, int EPI, typename OutT>
__global__ __launch_bounds__(256) void k_gemm(
    const u16* __restrict__ A, int lda, long sAz,
    const u16* __restrict__ B, int ldb, long sBz,
    OutT* __restrict__ C, int ldc, long sCz,
    int K, const float* __restrict__ bias, const float* __restrict__ srow, float scale)
{
  constexpr int BK = 64;
  constexpr int FM = BM / 32, FN = BN / 32;
  __shared__ u16 ldsA[BM * BK];
  __shared__ u16 ldsB[BN * BK];
  u32 bx, by, bz;
  xcd_remap(bx, by, bz);
  const long z = bz;
  if constexpr (MODE == 0){ A += z * sAz; B += z * sBz; C += z * sCz; }
  const int t = threadIdx.x;
  const int lane = t & 63;
  const int w = t >> 6, wm = w >> 1, wn = w & 1;
  const int r15 = lane & 15, g = lane >> 4;
  const int m0 = by * BM, n0 = bx * BN;
  fx4 acc[FM][FN] = {};
  constexpr int CA = BM * BK / (8 * 256);
  constexpr int CB = BN * BK / (8 * 256);
  for (int kt = 0; kt < K; kt += BK){
    #pragma unroll
    for (int i = 0; i < CA; ++i){
      int ch = i * 256 + t, row = ch >> 3, cc = ch & 7;
      gld16(A + (long)(m0 + row) * lda + kt + cc * 8, (char*)ldsA + ch * 16);
    }
    #pragma unroll
    for (int i = 0; i < CB; ++i){
      int ch = i * 256 + t, row = ch >> 3, cc = ch & 7;
      gld16(B + (long)(n0 + row) * ldb + kt + cc * 8, (char*)ldsB + ch * 16);
    }
    __syncthreads();
    #pragma unroll
    for (int ks = 0; ks < 2; ++ks){
      bf16x8 af[FM], bfv[FN];
      #pragma unroll
      for (int mf = 0; mf < FM; ++mf)
        af[mf] = *(const bf16x8*)&ldsA[(wm * (BM/2) + mf * 16 + r15) * BK + ks * 32 + g * 8];
      #pragma unroll
      for (int nf = 0; nf < FN; ++nf)
        bfv[nf] = *(const bf16x8*)&ldsB[(wn * (BN/2) + nf * 16 + r15) * BK + ks * 32 + g * 8];
      #pragma unroll
      for (int mf = 0; mf < FM; ++mf)
        #pragma unroll
        for (int nf = 0; nf < FN; ++nf)
          acc[mf][nf] = __builtin_amdgcn_mfma_f32_16x16x32_bf16(af[mf], bfv[nf], acc[mf][nf], 0, 0, 0);
    }
    __syncthreads();
  }
  #pragma unroll
  for (int mf = 0; mf < FM; ++mf){
    #pragma unroll
    for (int nf = 0; nf < FN; ++nf){
      const int row0 = m0 + wm * (BM/2) + mf * 16 + g * 4;
      const int col  = n0 + wn * (BN/2) + nf * 16 + r15;
      float vv[4];
      #pragma unroll
      for (int r = 0; r < 4; ++r){
        float v = acc[mf][nf][r];
        if constexpr (EPI == 1) v += bias[col];
        if constexpr (EPI == 2) v = (v + srow[row0 + r] * bias[col]) * scale;
        if constexpr (EPI == 3) v = v + srow[row0 + r] * bias[col];
        vv[r] = v;
      }
      if constexpr (EPI == 3){
        u32 lo = (u32)f2bf(vv[0]) | ((u32)f2bf(vv[1]) << 16);
        u32 hi = (u32)f2bf(vv[2]) | ((u32)f2bf(vv[3]) << 16);
        u32x2 pk2 = { lo, hi };
        *(u32x2*)((u16*)C + (long)col * 128 + row0) = pk2;
      } else {
        #pragma unroll
        for (int r = 0; r < 4; ++r){
          if constexpr (sizeof(OutT) == 2) C[(long)(row0 + r) * ldc + col] = (OutT)f2bf(vv[r]);
          else                             C[(long)(row0 + r) * ldc + col] = (OutT)vv[r];
        }
      }
    }
  }
}

// ---------------- big-M GEMM: 256x128 tile, phased counted-vmcnt (R4, best) ------
template<int EPI, typename OutT>
__global__ __launch_bounds__(512, 1) void k_gemm256(
    const u16* __restrict__ A, int lda,
    const u16* __restrict__ B, int ldb,
    OutT* __restrict__ C, int ldc,
    int K, const float* __restrict__ bias)
{
  constexpr int BM = 256, BN = 128, BK = 64;
  __shared__ u16 ldsA[3][BM * BK];
  __shared__ u16 ldsB[3][BN * BK];
  u32 bx, by, bz;
  xcd_remap(bx, by, bz);
  const int m0 = by * BM, n0 = bx * BN;
  const int t = threadIdx.x;
  const int lane = t & 63, w = t >> 6;
  const int wm = w >> 1, wn = w & 1;
  const int r15 = lane & 15, g = lane >> 4;
  const int NT = K >> 6;

  auto stageA = [&](int kt, int buf){
    #pragma unroll
    for (int j = 0; j < 4; ++j){
      int ch = j * 512 + t, row = ch >> 3, cc = ch & 7;
      gld16(A + (long)(m0 + row) * lda + kt + ((cc ^ (row & 7)) * 8),
            (char*)ldsA[buf] + ch * 16);
    }
  };
  auto stageB = [&](int kt, int buf){
    #pragma unroll
    for (int j = 0; j < 2; ++j){
      int ch = j * 512 + t, row = ch >> 3, cc = ch & 7;
      gld16(B + (long)(n0 + row) * ldb + kt + ((cc ^ (row & 7)) * 8),
            (char*)ldsB[buf] + ch * 16);
    }
  };

  stageA(0, 0); stageB(0, 0);
  if (NT > 1){
    stageA(BK, 1); stageB(BK, 1);
    asm volatile("s_waitcnt vmcnt(6)" ::: "memory");
  } else {
    asm volatile("s_waitcnt vmcnt(0)" ::: "memory");
  }
  __builtin_amdgcn_s_barrier();
  asm volatile("" ::: "memory");

  fx4 acc[4][4] = {};
  for (int tt = 0; tt < NT; ++tt){
    const u16* bA = ldsA[tt % 3];
    const u16* bB = ldsB[tt % 3];
    const int sbuf = (tt + 2) % 3;
    const bool pf = (tt + 2 < NT);
    bf16x8 af[2][4], bf[2][2];
    #pragma unroll
    for (int ks = 0; ks < 2; ++ks)
      #pragma unroll
      for (int mf = 0; mf < 4; ++mf)
        af[ks][mf] = *(const bf16x8*)((const char*)bA +
            (wm * 64 + mf * 16 + r15) * 128 + (((ks * 4 + g) ^ (r15 & 7)) * 16));
    #pragma unroll
    for (int ks = 0; ks < 2; ++ks)
      #pragma unroll
      for (int nf = 0; nf < 2; ++nf)
        bf[ks][nf] = *(const bf16x8*)((const char*)bB +
            (wn * 64 + nf * 16 + r15) * 128 + (((ks * 4 + g) ^ (r15 & 7)) * 16));
    if (pf) stageA((tt + 2) * BK, sbuf);
    asm volatile("" ::: "memory");
    __builtin_amdgcn_s_barrier();
    asm volatile("" ::: "memory");
    __builtin_amdgcn_s_setprio(1);
    #pragma unroll
    for (int ks = 0; ks < 2; ++ks)
      #pragma unroll
      for (int mf = 0; mf < 4; ++mf)
        #pragma unroll
        for (int nf = 0; nf < 2; ++nf)
          acc[mf][nf] = __builtin_amdgcn_mfma_f32_16x16x32_bf16(af[ks][mf], bf[ks][nf], acc[mf][nf], 0, 0, 0);
    __builtin_amdgcn_s_setprio(0);
    asm volatile("" ::: "memory");
    __builtin_amdgcn_s_barrier();
    asm volatile("" ::: "memory");
    bf16x8 bf2[2][2];
    #pragma unroll
    for (int ks = 0; ks < 2; ++ks)
      #pragma unroll
      for (int nf = 0; nf < 2; ++nf)
        bf2[ks][nf] = *(const bf16x8*)((const char*)bB +
            (wn * 64 + (nf + 2) * 16 + r15) * 128 + (((ks * 4 + g) ^ (r15 & 7)) * 16));
    if (pf) stageB((tt + 2) * BK, sbuf);
    __builtin_amdgcn_s_setprio(1);
    #pragma unroll
    for (int ks = 0; ks < 2; ++ks)
      #pragma unroll
      for (int mf = 0; mf < 4; ++mf)
        #pragma unroll
        for (int nf = 0; nf < 2; ++nf)
          acc[mf][nf + 2] = __builtin_amdgcn_mfma_f32_16x16x32_bf16(af[ks][mf], bf2[ks][nf], acc[mf][nf + 2], 0, 0, 0);
    __builtin_amdgcn_s_setprio(0);
    if (pf)                { asm volatile("s_waitcnt vmcnt(6)" ::: "memory"); }
    else if (tt + 1 < NT)  { asm volatile("s_waitcnt vmcnt(0)" ::: "memory"); }
    asm volatile("" ::: "memory");
    __builtin_amdgcn_s_barrier();
    asm volatile("" ::: "memory");
  }

  #pragma unroll
  for (int mf = 0; mf < 4; ++mf)
    #pragma unroll
    for (int nf = 0; nf < 4; ++nf){
      const int row0 = m0 + wm * 64 + mf * 16 + g * 4;
      const int col  = n0 + wn * 64 + nf * 16 + r15;
      float bcol = 0.f;
      if constexpr (EPI == 1) bcol = bias[col];
      #pragma unroll
      for (int r = 0; r < 4; ++r){
        float vv = acc[mf][nf][r] + bcol;
        if constexpr (sizeof(OutT) == 2) C[(long)(row0 + r) * ldc + col] = (OutT)f2bf(vv);
        else                             C[(long)(row0 + r) * ldc + col] = (OutT)vv;
      }
    }
}

// ---------------- fused transpose ck GEMM ----------------
// ck[p][b][128 kr][1024 d] = projT[p] @ src[b]^T, src = k|v fp32 [2048 n][1024 d].
// B-tile (64d x 64n) transpose-converted during staging (fp32 coalesced reads,
// packed b64 LDS writes, stride 72 => aligned b128 frags, <=2-way read conflicts).
// BM=128 BN=64 BK=64, 256 thr, 25.6KB LDS -> ~6 blocks/CU (latency hiding via TLP).
__global__ __launch_bounds__(256) void k_gemmTN(
    const u16* __restrict__ projT, const float* __restrict__ ksrc,
    const float* __restrict__ vsrc, u16* __restrict__ ck)
{
  u32 bx, by, bz; xcd_remap(bx, by, bz);
  const int p = bz >> 3, b = bz & 7;
  const u16* A = projT + p * 262144;                       // [128][2048]
  const float* S = (p ? vsrc : ksrc) + (long)b * 2097152;  // [2048][1024]
  u16* C = ck + p * 1048576 + b * 131072;
  const int d0 = bx * 64;
  __shared__ u16 ldsA[128 * 64];
  __shared__ u16 ldsB[64 * 72];
  const int t = threadIdx.x, lane = t & 63, w = t >> 6;
  const int wm = w >> 1, wn = w & 1;
  const int r15 = lane & 15, g = lane >> 4;
  const int c4 = t & 15, r4 = t >> 4;
  fx4 acc[4][2] = {};
  for (int kt = 0; kt < 2048; kt += 64){
    #pragma unroll
    for (int i = 0; i < 4; ++i){
      int ch = i * 256 + t, row = ch >> 3, cc = ch & 7;
      gld16(A + (long)row * 2048 + kt + ((cc ^ (row & 7)) * 8), (char*)ldsA + ch * 16);
    }
    float4 f[4];
    #pragma unroll
    for (int i = 0; i < 4; ++i)
      f[i] = *(const float4*)(S + (long)(kt + r4 * 4 + i) * 1024 + d0 + c4 * 4);
    #pragma unroll
    for (int j = 0; j < 4; ++j){
      u32 lo = (u32)f2bf(((const float*)&f[0])[j]) | ((u32)f2bf(((const float*)&f[1])[j]) << 16);
      u32 hi = (u32)f2bf(((const float*)&f[2])[j]) | ((u32)f2bf(((const float*)&f[3])[j]) << 16);
      u32x2 pr = { lo, hi };
      *(u32x2*)&ldsB[(c4 * 4 + j) * 72 + r4 * 4] = pr;
    }
    __syncthreads();
    #pragma unroll
    for (int ks = 0; ks < 2; ++ks){
      bf16x8 af[4], bfv[2];
      #pragma unroll
      for (int mf = 0; mf < 4; ++mf){
        int row = wm * 64 + mf * 16 + r15;
        af[mf] = *(const bf16x8*)((const char*)ldsA + row * 128 + (((ks * 4 + g) ^ (row & 7)) * 16));
      }
      #pragma unroll
      for (int nf = 0; nf < 2; ++nf)
        bfv[nf] = *(const bf16x8*)&ldsB[(wn * 32 + nf * 16 + r15) * 72 + ks * 32 + g * 8];
      #pragma unroll
      for (int mf = 0; mf < 4; ++mf)
        #pragma unroll
        for (int nf = 0; nf < 2; ++nf)
          acc[mf][nf] = __builtin_amdgcn_mfma_f32_16x16x32_bf16(af[mf], bfv[nf], acc[mf][nf], 0, 0, 0);
    }
    __syncthreads();
  }
  #pragma unroll
  for (int mf = 0; mf < 4; ++mf)
    #pragma unroll
    for (int nf = 0; nf < 2; ++nf){
      const int row0 = wm * 64 + mf * 16 + g * 4;
      const int col  = d0 + wn * 32 + nf * 16 + r15;
      #pragma unroll
      for (int r = 0; r < 4; ++r)
        C[(long)(row0 + r) * 1024 + col] = f2bf(acc[mf][nf][r]);
    }
}

// ---------------- fused attention, pass 1: Z[k] = sum_n exp(s[k,n]) ----------------
__global__ __launch_bounds__(512) void k_stats(const u16* __restrict__ pk,
                                               const u16* __restrict__ qp,
                                               float* __restrict__ invZ){
  const int z = blockIdx.x;
  const int b = z >> 4, h = z & 15;
  const u16* pkh = pk + b * 131072 + h * 64;
  const u16* qph = qp + (long)z * 131072;
  __shared__ u16 pkL[128 * 64];
  __shared__ float zred[8][128];
  const int t = threadIdx.x, lane = t & 63, w = t >> 6;
  const int r15 = lane & 15, g = lane >> 4;
  #pragma unroll
  for (int i = 0; i < 2; ++i){
    int ch = i * 512 + t, row = ch >> 3, cc = ch & 7;
    int csrc = cc ^ (row & 7);
    gld16(pkh + (long)row * 1024 + csrc * 8, (char*)pkL + ch * 16);
  }
  __syncthreads();
  float zacc[8][4] = {};
  for (int c = 0; c < 8; ++c){
    const int n0 = w * 256 + c * 32;
    fx4 acc[8][2] = {};
    #pragma unroll
    for (int ks = 0; ks < 2; ++ks){
      bf16x8 bq[2];
      #pragma unroll
      for (int nf = 0; nf < 2; ++nf)
        bq[nf] = *(const bf16x8*)(qph + (long)(n0 + nf * 16 + r15) * 64 + ks * 32 + g * 8);
      #pragma unroll
      for (int mf = 0; mf < 8; ++mf){
        int row = mf * 16 + r15;
        int x = (ks * 4 + g) ^ (row & 7);
        bf16x8 a = *(const bf16x8*)((const char*)pkL + row * 128 + x * 16);
        #pragma unroll
        for (int nf = 0; nf < 2; ++nf)
          acc[mf][nf] = __builtin_amdgcn_mfma_f32_16x16x32_bf16(a, bq[nf], acc[mf][nf], 0, 0, 0);
      }
    }
    #pragma unroll
    for (int mf = 0; mf < 8; ++mf)
      #pragma unroll
      for (int nf = 0; nf < 2; ++nf)
        #pragma unroll
        for (int r = 0; r < 4; ++r)
          zacc[mf][r] += __expf(acc[mf][nf][r]);
  }
  #pragma unroll
  for (int mf = 0; mf < 8; ++mf)
    #pragma unroll
    for (int r = 0; r < 4; ++r){
      float v = zacc[mf][r];
      v += __shfl_xor(v, 1); v += __shfl_xor(v, 2);
      v += __shfl_xor(v, 4); v += __shfl_xor(v, 8);
      zacc[mf][r] = v;
    }
  if (r15 == 0){
    #pragma unroll
    for (int mf = 0; mf < 8; ++mf)
      #pragma unroll
      for (int r = 0; r < 4; ++r)
        zred[w][mf * 16 + g * 4 + r] = zacc[mf][r];
  }
  __syncthreads();
  if (t < 128){
    float s = 0.f;
    #pragma unroll
    for (int w2 = 0; w2 < 8; ++w2) s += zred[w2][t];
    invZ[(long)z * 128 + t] = 1.0f / s;
  }
}

// ---------------- fused attention, pass 2: out = attn^T @ pv ----------------
__global__ __launch_bounds__(256) void k_attn(const u16* __restrict__ pk,
                                              const u16* __restrict__ qp,
                                              const u16* __restrict__ pvT,
                                              const float* __restrict__ invZ,
                                              u16* __restrict__ outh){
  u32 bx, by, bz;
  xcd_remap(bx, by, bz);
  const int z = by, nb = bx;
  const int b = z >> 4, h = z & 15;
  const u16* pkh = pk  + b * 131072 + h * 64;
  const u16* qph = qp  + (long)z * 131072;
  const u16* pvh = pvT + b * 131072 + h * 8192;
  const float* zh = invZ + (long)z * 128;
  __shared__ u16 pkL[128 * 64];
  __shared__ u16 ptL[4][32 * 132];
  __shared__ float zL[128];
  const int t = threadIdx.x, lane = t & 63, w = t >> 6;
  const int r15 = lane & 15, g = lane >> 4;
  #pragma unroll
  for (int i = 0; i < 4; ++i){
    int ch = i * 256 + t, row = ch >> 3, cc = ch & 7;
    int csrc = cc ^ (row & 7);
    gld16(pkh + (long)row * 1024 + csrc * 8, (char*)pkL + ch * 16);
  }
  if (t < 128) zL[t] = zh[t];
  __syncthreads();
  const int n0 = nb * 128 + w * 32;
  fx4 acc[8][2] = {};
  #pragma unroll
  for (int ks = 0; ks < 2; ++ks){
    bf16x8 bq[2];
    #pragma unroll
    for (int nf = 0; nf < 2; ++nf)
      bq[nf] = *(const bf16x8*)(qph + (long)(n0 + nf * 16 + r15) * 64 + ks * 32 + g * 8);
    #pragma unroll
    for (int mf = 0; mf < 8; ++mf){
      int row = mf * 16 + r15;
      int x = (ks * 4 + g) ^ (row & 7);
      bf16x8 a = *(const bf16x8*)((const char*)pkL + row * 128 + x * 16);
      #pragma unroll
      for (int nf = 0; nf < 2; ++nf)
        acc[mf][nf] = __builtin_amdgcn_mfma_f32_16x16x32_bf16(a, bq[nf], acc[mf][nf], 0, 0, 0);
    }
  }
  u16* pt = ptL[w];
  #pragma unroll
  for (int mf = 0; mf < 8; ++mf){
    const int kb = mf * 16 + g * 4;
    const float z0 = zL[kb], z1 = zL[kb + 1], z2 = zL[kb + 2], z3 = zL[kb + 3];
    #pragma unroll
    for (int nf = 0; nf < 2; ++nf){
      const int nl = nf * 16 + r15;
      u32 lo = (u32)f2bf(__expf(acc[mf][nf][0]) * z0) |
               ((u32)f2bf(__expf(acc[mf][nf][1]) * z1) << 16);
      u32 hi = (u32)f2bf(__expf(acc[mf][nf][2]) * z2) |
               ((u32)f2bf(__expf(acc[mf][nf][3]) * z3) << 16);
      u32x2 pkd = { lo, hi };
      *(u32x2*)(pt + nl * 132 + kb) = pkd;
    }
  }
  fx4 o[2][4] = {};
  #pragma unroll
  for (int ks = 0; ks < 4; ++ks){
    bf16x8 bv[4];
    #pragma unroll
    for (int nf = 0; nf < 4; ++nf)
      bv[nf] = *(const bf16x8*)(pvh + (long)(nf * 16 + r15) * 128 + ks * 32 + g * 8);
    #pragma unroll
    for (int mf = 0; mf < 2; ++mf){
      bf16x8 pa = *(const bf16x8*)(pt + (mf * 16 + r15) * 132 + ks * 32 + g * 8);
      #pragma unroll
      for (int nf = 0; nf < 4; ++nf)
        o[mf][nf] = __builtin_amdgcn_mfma_f32_16x16x32_bf16(pa, bv[nf], o[mf][nf], 0, 0, 0);
    }
  }
  u16* og = outh + ((long)b * 2048 + n0) * 1024 + h * 64;
  #pragma unroll
  for (int mf = 0; mf < 2; ++mf)
    #pragma unroll
    for (int nf = 0; nf < 4; ++nf)
      #pragma unroll
      for (int r = 0; r < 4; ++r){
        int nl = mf * 16 + g * 4 + r;
        og[(long)nl * 1024 + nf * 16 + r15] = f2bf(o[mf][nf][r]);
      }
}

extern "C" void kernel_launch(void* const* d_in, const int* in_sizes, int n_in,
                              void* d_out, int out_size, void* d_ws, size_t ws_size,
                              hipStream_t stream)
{
  const float* q   = (const float*)d_in[0];
  const float* k   = (const float*)d_in[1];
  const float* v   = (const float*)d_in[2];
  const float* Wq  = (const float*)d_in[3];
  const float* bq  = (const float*)d_in[4];
  const float* Wk  = (const float*)d_in[5];
  const float* bk  = (const float*)d_in[6];
  const float* Wv  = (const float*)d_in[7];
  const float* bv  = (const float*)d_in[8];
  const float* pjk = (const float*)d_in[9];
  const float* pjv = (const float*)d_in[10];
  const float* Wo  = (const float*)d_in[11];
  const float* bo  = (const float*)d_in[12];

  if (ws_size < 152044544u) return;

  char* ws = (char*)d_ws;
  u16*  q_bf  = (u16*)(ws + 0);            // 32MB (reused by outh)
  float* invZ = (float*)(ws + 33554432);   // [128][128]
  u16*  W_bf  = (u16*)(ws + 100663296);    // 4 x 1Mi elems: Wq,Wk,Wv,Wo
  u16*  projT = (u16*)(ws + 109051904);    // projkT [128][2048], projvT after
  float* sk   = (float*)(ws + 110100480);
  float* sv   = (float*)(ws + 110100992);
  u16*  qp    = (u16*)(ws + 110101504);    // 32MB [16384,1024]
  u16*  ck    = (u16*)(ws + 143655936);    // [2][8][128][1024]
  u16*  pk    = (u16*)(ws + 147850240);    // [8][128][1024], pre-scaled 1/8
  u16*  pvT   = (u16*)(ws + 149947392);    // [8][16][64][128]
  u16*  outh  = (u16*)(ws + 0);            // overlay q_bf
  u16*  Wq_bf = W_bf, *Wk_bf = W_bf + 1048576, *Wv_bf = W_bf + 2097152, *Wo_bf = W_bf + 3145728;

  k_zero<<<1, 256, 0, stream>>>(sk, 256);

  k_f2bf<<<2048, 256, 0, stream>>>(q, q_bf, 2097152);
  k_f2bfW<<<dim3(128,4), 256, 0, stream>>>(Wq, Wk, Wv, Wo, W_bf);
  k_tconv<<<dim3(2,32,1),  256, 0, stream>>>(pjk, projT,          2048, 128, 0, 0, sk);
  k_tconv<<<dim3(2,32,1),  256, 0, stream>>>(pjv, projT + 262144, 2048, 128, 0, 0, sv);

  // qp = q @ Wq^T + bq   (256x128 phased kernel)
  k_gemm256<1,u16><<<dim3(8,64), 512, 0, stream>>>(
      q_bf,1024, Wq_bf,1024, qp,1024, 1024, bq);
  // ck = projkT @ k^T ; cv = projvT @ v^T  (fused transpose, reads fp32 k/v)
  k_gemmTN<<<dim3(16,1,16), 256, 0, stream>>>(projT, k, v, ck);
  // pk = (ck @ Wk^T + sk (x) bk) / 8   (64x64 tile -> 256 blocks)
  k_gemm<64,64,0,2,u16><<<dim3(16,2,8), 256, 0, stream>>>(
      ck,1024,131072, Wk_bf,1024,0, pk,1024,131072, 1024, bk, sk, 0.125f);
  // pvT = (cv @ Wv^T + sv (x) bv), transposed write (64x64 tile -> 256 blocks)
  k_gemm<64,64,0,3,u16><<<dim3(16,2,8), 256, 0, stream>>>(
      ck + 1048576,1024,131072, Wv_bf,1024,0, pvT,0,131072, 1024, bv, sv, 1.f);
  // fused attention
  k_stats<<<128, 512, 0, stream>>>(pk, qp, invZ);
  k_attn<<<dim3(16,128), 256, 0, stream>>>(pk, qp, pvT, invZ, outh);
  // final = outh @ Wo^T + bo -> fp32 d_out
  k_gemm256<1,float><<<dim3(8,64), 512, 0, stream>>>(
      outh,1024, Wo_bf,1024, (float*)d_out,1024, 1024, bo);
}

// Round 8
// 240.321 us; speedup vs baseline: 1.5771x; 1.0418x over previous
//
#include <hip/hip_runtime.h>

typedef unsigned short u16;
typedef unsigned int   u32;
typedef __attribute__((ext_vector_type(4))) float fx4;
typedef __attribute__((ext_vector_type(8))) __bf16 bf16x8;
typedef __attribute__((ext_vector_type(8))) unsigned short us8;
typedef __attribute__((ext_vector_type(2))) unsigned int u32x2;

__device__ __forceinline__ u16 f2bf(float x){
  u32 u = __builtin_bit_cast(u32, x);
  u += 0x7fffu + ((u >> 16) & 1u);
  return (u16)(u >> 16);
}
__device__ __forceinline__ float b2f(u16 h){
  u32 u = ((u32)h) << 16;
  return __builtin_bit_cast(float, u);
}
__device__ __forceinline__ void gld16(const void* g, void* l){
  __builtin_amdgcn_global_load_lds(
      (const __attribute__((address_space(1))) u32*)g,
      (__attribute__((address_space(3))) u32*)l, 16, 0, 0);
}
// XCD-chunked bijective swizzle (grid size must be %8==0).
__device__ __forceinline__ void xcd_remap(u32& bx, u32& by, u32& bz){
  u32 nx = gridDim.x, ny = gridDim.y, nz = gridDim.z;
  u32 nwg = nx * ny * nz;
  u32 orig = (blockIdx.z * ny + blockIdx.y) * nx + blockIdx.x;
  u32 lid = (orig & 7u) * (nwg >> 3) + (orig >> 3);
  bx = lid % nx;
  u32 rem = lid / nx;
  by = rem % ny;
  bz = rem / ny;
}

// ---------------- fp32 -> bf16 convert (vectorized, grid-stride) ----------------
__global__ __launch_bounds__(256) void k_f2bf(const float* __restrict__ in,
                                              u16* __restrict__ out, int n8){
  int i = blockIdx.x * 256 + threadIdx.x;
  const int stride = gridDim.x * 256;
  for (; i < n8; i += stride){
    const float4* p = (const float4*)in + (long)i * 2;
    float4 a = p[0], b = p[1];
    us8 o = { f2bf(a.x), f2bf(a.y), f2bf(a.z), f2bf(a.w),
              f2bf(b.x), f2bf(b.y), f2bf(b.z), f2bf(b.w) };
    *((us8*)out + i) = o;
  }
}

// four 1024x1024 weights in one launch; also zeroes the 256-float colsum buffer
__global__ __launch_bounds__(256) void k_f2bfW(const float* __restrict__ w0,
                                               const float* __restrict__ w1,
                                               const float* __restrict__ w2,
                                               const float* __restrict__ w3,
                                               u16* __restrict__ out,
                                               float* __restrict__ zbuf){
  if (blockIdx.x == 0 && blockIdx.y == 0) zbuf[threadIdx.x] = 0.f;
  const float* src = blockIdx.y == 0 ? w0 : blockIdx.y == 1 ? w1 :
                     blockIdx.y == 2 ? w2 : w3;
  u16* dst = out + (long)blockIdx.y * 1048576;
  int i = blockIdx.x * 256 + threadIdx.x;
  const int stride = gridDim.x * 256;
  for (; i < 131072; i += stride){
    const float4* p = (const float4*)src + (long)i * 2;
    float4 a = p[0], b = p[1];
    us8 o = { f2bf(a.x), f2bf(a.y), f2bf(a.z), f2bf(a.w),
              f2bf(b.x), f2bf(b.y), f2bf(b.z), f2bf(b.w) };
    *((us8*)dst + i) = o;
  }
}

// ---------------- transpose + convert (proj only): [R,C] f32 -> [C,R] bf16 -------
__global__ __launch_bounds__(256) void k_tconv(const float* __restrict__ in,
                                               u16* __restrict__ out,
                                               int R, int C, long sIn, long sOut,
                                               float* __restrict__ colsum){
  in  += (long)blockIdx.z * sIn;
  out += (long)blockIdx.z * sOut;
  const int c0 = blockIdx.x * 64, r0 = blockIdx.y * 64;
  __shared__ u16 tile[64][66];
  __shared__ float red[256];
  const int t = threadIdx.x;
  const int cc = t & 63, wq = t >> 6;
  float part = 0.f;
  #pragma unroll
  for (int i = 0; i < 16; ++i){
    int rr = i * 4 + wq;
    float v = in[(long)(r0 + rr) * C + c0 + cc];
    tile[rr][cc] = f2bf(v);
    part += v;
  }
  if (colsum){
    red[t] = part;
    __syncthreads();
    if (t < 64){
      float s = red[t] + red[t + 64] + red[t + 128] + red[t + 192];
      atomicAdd(&colsum[c0 + t], s);
    }
  }
  __syncthreads();
  const int oc0 = t >> 5, jb = (t & 31) * 2;
  #pragma unroll
  for (int i = 0; i < 8; ++i){
    int oc = oc0 + i * 8;
    u32 pk2 = (u32)tile[jb][oc] | ((u32)tile[jb + 1][oc] << 16);
    *(u32*)(out + (long)(c0 + oc) * R + r0 + jb) = pk2;
  }
}

// ---------------- BT-layout MFMA GEMM (small/batched shapes) ----------------
template<int BM, int BN, int MODE, int EPI, typename OutT>
__global__ __launch_bounds__(256) void k_gemm(
    const u16* __restrict__ A, int lda, long sAz,
    const u16* __restrict__ B, int ldb, long sBz,
    OutT* __restrict__ C, int ldc, long sCz,
    int K, const float* __restrict__ bias, const float* __restrict__ srow, float scale)
{
  constexpr int BK = 64;
  constexpr int FM = BM / 32, FN = BN / 32;
  __shared__ u16 ldsA[BM * BK];
  __shared__ u16 ldsB[BN * BK];
  u32 bx, by, bz;
  xcd_remap(bx, by, bz);
  const long z = bz;
  if constexpr (MODE == 0){ A += z * sAz; B += z * sBz; C += z * sCz; }
  const int t = threadIdx.x;
  const int lane = t & 63;
  const int w = t >> 6, wm = w >> 1, wn = w & 1;
  const int r15 = lane & 15, g = lane >> 4;
  const int m0 = by * BM, n0 = bx * BN;
  fx4 acc[FM][FN] = {};
  constexpr int CA = BM * BK / (8 * 256);
  constexpr int CB = BN * BK / (8 * 256);
  for (int kt = 0; kt < K; kt += BK){
    #pragma unroll
    for (int i = 0; i < CA; ++i){
      int ch = i * 256 + t, row = ch >> 3, cc = ch & 7;
      gld16(A + (long)(m0 + row) * lda + kt + cc * 8, (char*)ldsA + ch * 16);
    }
    #pragma unroll
    for (int i = 0; i < CB; ++i){
      int ch = i * 256 + t, row = ch >> 3, cc = ch & 7;
      gld16(B + (long)(n0 + row) * ldb + kt + cc * 8, (char*)ldsB + ch * 16);
    }
    __syncthreads();
    #pragma unroll
    for (int ks = 0; ks < 2; ++ks){
      bf16x8 af[FM], bfv[FN];
      #pragma unroll
      for (int mf = 0; mf < FM; ++mf)
        af[mf] = *(const bf16x8*)&ldsA[(wm * (BM/2) + mf * 16 + r15) * BK + ks * 32 + g * 8];
      #pragma unroll
      for (int nf = 0; nf < FN; ++nf)
        bfv[nf] = *(const bf16x8*)&ldsB[(wn * (BN/2) + nf * 16 + r15) * BK + ks * 32 + g * 8];
      #pragma unroll
      for (int mf = 0; mf < FM; ++mf)
        #pragma unroll
        for (int nf = 0; nf < FN; ++nf)
          acc[mf][nf] = __builtin_amdgcn_mfma_f32_16x16x32_bf16(af[mf], bfv[nf], acc[mf][nf], 0, 0, 0);
    }
    __syncthreads();
  }
  #pragma unroll
  for (int mf = 0; mf < FM; ++mf){
    #pragma unroll
    for (int nf = 0; nf < FN; ++nf){
      const int row0 = m0 + wm * (BM/2) + mf * 16 + g * 4;
      const int col  = n0 + wn * (BN/2) + nf * 16 + r15;
      float vv[4];
      #pragma unroll
      for (int r = 0; r < 4; ++r){
        float v = acc[mf][nf][r];
        if constexpr (EPI == 1) v += bias[col];
        if constexpr (EPI == 2) v = (v + srow[row0 + r] * bias[col]) * scale;
        if constexpr (EPI == 3) v = v + srow[row0 + r] * bias[col];
        vv[r] = v;
      }
      if constexpr (EPI == 3){
        u32 lo = (u32)f2bf(vv[0]) | ((u32)f2bf(vv[1]) << 16);
        u32 hi = (u32)f2bf(vv[2]) | ((u32)f2bf(vv[3]) << 16);
        u32x2 pk2 = { lo, hi };
        *(u32x2*)((u16*)C + (long)col * 128 + row0) = pk2;
      } else {
        #pragma unroll
        for (int r = 0; r < 4; ++r){
          if constexpr (sizeof(OutT) == 2) C[(long)(row0 + r) * ldc + col] = (OutT)f2bf(vv[r]);
          else                             C[(long)(row0 + r) * ldc + col] = (OutT)vv[r];
        }
      }
    }
  }
}

// ---------------- big-M GEMM: 256x128 tile, phased counted-vmcnt (R4, best) ------
template<int EPI, typename OutT>
__global__ __launch_bounds__(512, 1) void k_gemm256(
    const u16* __restrict__ A, int lda,
    const u16* __restrict__ B, int ldb,
    OutT* __restrict__ C, int ldc,
    int K, const float* __restrict__ bias)
{
  constexpr int BM = 256, BN = 128, BK = 64;
  __shared__ u16 ldsA[3][BM * BK];
  __shared__ u16 ldsB[3][BN * BK];
  u32 bx, by, bz;
  xcd_remap(bx, by, bz);
  const int m0 = by * BM, n0 = bx * BN;
  const int t = threadIdx.x;
  const int lane = t & 63, w = t >> 6;
  const int wm = w >> 1, wn = w & 1;
  const int r15 = lane & 15, g = lane >> 4;
  const int NT = K >> 6;

  auto stageA = [&](int kt, int buf){
    #pragma unroll
    for (int j = 0; j < 4; ++j){
      int ch = j * 512 + t, row = ch >> 3, cc = ch & 7;
      gld16(A + (long)(m0 + row) * lda + kt + ((cc ^ (row & 7)) * 8),
            (char*)ldsA[buf] + ch * 16);
    }
  };
  auto stageB = [&](int kt, int buf){
    #pragma unroll
    for (int j = 0; j < 2; ++j){
      int ch = j * 512 + t, row = ch >> 3, cc = ch & 7;
      gld16(B + (long)(n0 + row) * ldb + kt + ((cc ^ (row & 7)) * 8),
            (char*)ldsB[buf] + ch * 16);
    }
  };

  stageA(0, 0); stageB(0, 0);
  if (NT > 1){
    stageA(BK, 1); stageB(BK, 1);
    asm volatile("s_waitcnt vmcnt(6)" ::: "memory");
  } else {
    asm volatile("s_waitcnt vmcnt(0)" ::: "memory");
  }
  __builtin_amdgcn_s_barrier();
  asm volatile("" ::: "memory");

  fx4 acc[4][4] = {};
  for (int tt = 0; tt < NT; ++tt){
    const u16* bA = ldsA[tt % 3];
    const u16* bB = ldsB[tt % 3];
    const int sbuf = (tt + 2) % 3;
    const bool pf = (tt + 2 < NT);
    bf16x8 af[2][4], bf[2][2];
    #pragma unroll
    for (int ks = 0; ks < 2; ++ks)
      #pragma unroll
      for (int mf = 0; mf < 4; ++mf)
        af[ks][mf] = *(const bf16x8*)((const char*)bA +
            (wm * 64 + mf * 16 + r15) * 128 + (((ks * 4 + g) ^ (r15 & 7)) * 16));
    #pragma unroll
    for (int ks = 0; ks < 2; ++ks)
      #pragma unroll
      for (int nf = 0; nf < 2; ++nf)
        bf[ks][nf] = *(const bf16x8*)((const char*)bB +
            (wn * 64 + nf * 16 + r15) * 128 + (((ks * 4 + g) ^ (r15 & 7)) * 16));
    if (pf) stageA((tt + 2) * BK, sbuf);
    asm volatile("" ::: "memory");
    __builtin_amdgcn_s_barrier();
    asm volatile("" ::: "memory");
    __builtin_amdgcn_s_setprio(1);
    #pragma unroll
    for (int ks = 0; ks < 2; ++ks)
      #pragma unroll
      for (int mf = 0; mf < 4; ++mf)
        #pragma unroll
        for (int nf = 0; nf < 2; ++nf)
          acc[mf][nf] = __builtin_amdgcn_mfma_f32_16x16x32_bf16(af[ks][mf], bf[ks][nf], acc[mf][nf], 0, 0, 0);
    __builtin_amdgcn_s_setprio(0);
    asm volatile("" ::: "memory");
    __builtin_amdgcn_s_barrier();
    asm volatile("" ::: "memory");
    bf16x8 bf2[2][2];
    #pragma unroll
    for (int ks = 0; ks < 2; ++ks)
      #pragma unroll
      for (int nf = 0; nf < 2; ++nf)
        bf2[ks][nf] = *(const bf16x8*)((const char*)bB +
            (wn * 64 + (nf + 2) * 16 + r15) * 128 + (((ks * 4 + g) ^ (r15 & 7)) * 16));
    if (pf) stageB((tt + 2) * BK, sbuf);
    __builtin_amdgcn_s_setprio(1);
    #pragma unroll
    for (int ks = 0; ks < 2; ++ks)
      #pragma unroll
      for (int mf = 0; mf < 4; ++mf)
        #pragma unroll
        for (int nf = 0; nf < 2; ++nf)
          acc[mf][nf + 2] = __builtin_amdgcn_mfma_f32_16x16x32_bf16(af[ks][mf], bf2[ks][nf], acc[mf][nf + 2], 0, 0, 0);
    __builtin_amdgcn_s_setprio(0);
    if (pf)                { asm volatile("s_waitcnt vmcnt(6)" ::: "memory"); }
    else if (tt + 1 < NT)  { asm volatile("s_waitcnt vmcnt(0)" ::: "memory"); }
    asm volatile("" ::: "memory");
    __builtin_amdgcn_s_barrier();
    asm volatile("" ::: "memory");
  }

  #pragma unroll
  for (int mf = 0; mf < 4; ++mf)
    #pragma unroll
    for (int nf = 0; nf < 4; ++nf){
      const int row0 = m0 + wm * 64 + mf * 16 + g * 4;
      const int col  = n0 + wn * 64 + nf * 16 + r15;
      float bcol = 0.f;
      if constexpr (EPI == 1) bcol = bias[col];
      #pragma unroll
      for (int r = 0; r < 4; ++r){
        float vv = acc[mf][nf][r] + bcol;
        if constexpr (sizeof(OutT) == 2) C[(long)(row0 + r) * ldc + col] = (OutT)f2bf(vv);
        else                             C[(long)(row0 + r) * ldc + col] = (OutT)vv;
      }
    }
}

// ---------------- fused transpose ck GEMM v2 (pipelined, 2 blocks/CU) ----------------
// ck[p][b][kr][d] = projT[p] @ src[b]^T, src = k|v fp32 [2048 n][1024 d].
// BM=64(kr) BN=64(d) BK=64(n); grid (16 d, 2 kr, 16 pb) = 512 blocks = 2/CU.
// Double-buffered LDS; per tile: issue S-float4 + A-gld16 for t+1, compute t,
// vmcnt(0), transpose-write S(t+1) to LDS, one barrier. (T14 issue-early/write-late)
__global__ __launch_bounds__(256) void k_gemmTN(
    const u16* __restrict__ projT, const float* __restrict__ ksrc,
    const float* __restrict__ vsrc, u16* __restrict__ ck)
{
  u32 bx, by, bz; xcd_remap(bx, by, bz);
  const int p = bz >> 3, b = bz & 7;
  const u16* A = projT + p * 262144 + by * 64 * 2048;      // [64 kr][2048 n]
  const float* S = (p ? vsrc : ksrc) + (long)b * 2097152;  // [2048 n][1024 d]
  u16* C = ck + p * 1048576 + b * 131072 + by * 64 * 1024;
  const int d0 = bx * 64;
  __shared__ u16 ldsA[2][64 * 64];
  __shared__ u16 ldsB[2][64 * 72];
  const int t = threadIdx.x, lane = t & 63, w = t >> 6;
  const int wm = w >> 1, wn = w & 1;
  const int r15 = lane & 15, g = lane >> 4;
  const int c4 = t & 15, r4 = t >> 4;

  auto ldA = [&](int kt, int buf){
    #pragma unroll
    for (int i = 0; i < 2; ++i){
      int ch = i * 256 + t, row = ch >> 3, cc = ch & 7;
      gld16(A + (long)row * 2048 + kt + ((cc ^ (row & 7)) * 8),
            (char*)ldsA[buf] + ch * 16);
    }
  };
  auto ldS = [&](int kt, float4* f){
    #pragma unroll
    for (int i = 0; i < 4; ++i)
      f[i] = *(const float4*)(S + (long)(kt + r4 * 4 + i) * 1024 + d0 + c4 * 4);
  };
  auto wrB = [&](const float4* f, int buf){
    #pragma unroll
    for (int j = 0; j < 4; ++j){
      u32 lo = (u32)f2bf(((const float*)&f[0])[j]) | ((u32)f2bf(((const float*)&f[1])[j]) << 16);
      u32 hi = (u32)f2bf(((const float*)&f[2])[j]) | ((u32)f2bf(((const float*)&f[3])[j]) << 16);
      u32x2 pr = { lo, hi };
      *(u32x2*)&ldsB[buf][(c4 * 4 + j) * 72 + r4 * 4] = pr;
    }
  };

  { float4 f0[4];
    ldS(0, f0); ldA(0, 0);
    asm volatile("s_waitcnt vmcnt(0)" ::: "memory");
    wrB(f0, 0); }
  __syncthreads();

  fx4 acc[2][2] = {};
  for (int tt = 0; tt < 32; ++tt){
    const int buf = tt & 1;
    const bool pf = (tt + 1 < 32);
    float4 fn[4];
    if (pf){ ldS((tt + 1) * 64, fn); ldA((tt + 1) * 64, buf ^ 1); }
    asm volatile("" ::: "memory");
    #pragma unroll
    for (int ks = 0; ks < 2; ++ks){
      bf16x8 af[2], bfv[2];
      #pragma unroll
      for (int mf = 0; mf < 2; ++mf){
        int row = wm * 32 + mf * 16 + r15;
        af[mf] = *(const bf16x8*)((const char*)ldsA[buf] + row * 128 +
                                  (((ks * 4 + g) ^ (row & 7)) * 16));
      }
      #pragma unroll
      for (int nf = 0; nf < 2; ++nf)
        bfv[nf] = *(const bf16x8*)&ldsB[buf][(wn * 32 + nf * 16 + r15) * 72 + ks * 32 + g * 8];
      #pragma unroll
      for (int mf = 0; mf < 2; ++mf)
        #pragma unroll
        for (int nf = 0; nf < 2; ++nf)
          acc[mf][nf] = __builtin_amdgcn_mfma_f32_16x16x32_bf16(af[mf], bfv[nf], acc[mf][nf], 0, 0, 0);
    }
    if (pf){
      asm volatile("s_waitcnt vmcnt(0)" ::: "memory");
      wrB(fn, buf ^ 1);
    }
    __syncthreads();
  }
  #pragma unroll
  for (int mf = 0; mf < 2; ++mf)
    #pragma unroll
    for (int nf = 0; nf < 2; ++nf){
      const int row0 = wm * 32 + mf * 16 + g * 4;
      const int col  = d0 + wn * 32 + nf * 16 + r15;
      #pragma unroll
      for (int r = 0; r < 4; ++r)
        C[(long)(row0 + r) * 1024 + col] = f2bf(acc[mf][nf][r]);
    }
}

// ---------------- fused attention, pass 1: Z[k] = sum_n exp(s[k,n]) ----------------
__global__ __launch_bounds__(512) void k_stats(const u16* __restrict__ pk,
                                               const u16* __restrict__ qp,
                                               float* __restrict__ invZ){
  const int z = blockIdx.x;
  const int b = z >> 4, h = z & 15;
  const u16* pkh = pk + b * 131072 + h * 64;
  const u16* qph = qp + (long)z * 131072;
  __shared__ u16 pkL[128 * 64];
  __shared__ float zred[8][128];
  const int t = threadIdx.x, lane = t & 63, w = t >> 6;
  const int r15 = lane & 15, g = lane >> 4;
  #pragma unroll
  for (int i = 0; i < 2; ++i){
    int ch = i * 512 + t, row = ch >> 3, cc = ch & 7;
    int csrc = cc ^ (row & 7);
    gld16(pkh + (long)row * 1024 + csrc * 8, (char*)pkL + ch * 16);
  }
  __syncthreads();
  float zacc[8][4] = {};
  for (int c = 0; c < 8; ++c){
    const int n0 = w * 256 + c * 32;
    fx4 acc[8][2] = {};
    #pragma unroll
    for (int ks = 0; ks < 2; ++ks){
      bf16x8 bq[2];
      #pragma unroll
      for (int nf = 0; nf < 2; ++nf)
        bq[nf] = *(const bf16x8*)(qph + (long)(n0 + nf * 16 + r15) * 64 + ks * 32 + g * 8);
      #pragma unroll
      for (int mf = 0; mf < 8; ++mf){
        int row = mf * 16 + r15;
        int x = (ks * 4 + g) ^ (row & 7);
        bf16x8 a = *(const bf16x8*)((const char*)pkL + row * 128 + x * 16);
        #pragma unroll
        for (int nf = 0; nf < 2; ++nf)
          acc[mf][nf] = __builtin_amdgcn_mfma_f32_16x16x32_bf16(a, bq[nf], acc[mf][nf], 0, 0, 0);
      }
    }
    #pragma unroll
    for (int mf = 0; mf < 8; ++mf)
      #pragma unroll
      for (int nf = 0; nf < 2; ++nf)
        #pragma unroll
        for (int r = 0; r < 4; ++r)
          zacc[mf][r] += __expf(acc[mf][nf][r]);
  }
  #pragma unroll
  for (int mf = 0; mf < 8; ++mf)
    #pragma unroll
    for (int r = 0; r < 4; ++r){
      float v = zacc[mf][r];
      v += __shfl_xor(v, 1); v += __shfl_xor(v, 2);
      v += __shfl_xor(v, 4); v += __shfl_xor(v, 8);
      zacc[mf][r] = v;
    }
  if (r15 == 0){
    #pragma unroll
    for (int mf = 0; mf < 8; ++mf)
      #pragma unroll
      for (int r = 0; r < 4; ++r)
        zred[w][mf * 16 + g * 4 + r] = zacc[mf][r];
  }
  __syncthreads();
  if (t < 128){
    float s = 0.f;
    #pragma unroll
    for (int w2 = 0; w2 < 8; ++w2) s += zred[w2][t];
    invZ[(long)z * 128 + t] = 1.0f / s;
  }
}

// ---------------- fused attention, pass 2: out = attn^T @ pv ----------------
__global__ __launch_bounds__(256) void k_attn(const u16* __restrict__ pk,
                                              const u16* __restrict__ qp,
                                              const u16* __restrict__ pvT,
                                              const float* __restrict__ invZ,
                                              u16* __restrict__ outh){
  u32 bx, by, bz;
  xcd_remap(bx, by, bz);
  const int z = by, nb = bx;
  const int b = z >> 4, h = z & 15;
  const u16* pkh = pk  + b * 131072 + h * 64;
  const u16* qph = qp  + (long)z * 131072;
  const u16* pvh = pvT + b * 131072 + h * 8192;
  const float* zh = invZ + (long)z * 128;
  __shared__ u16 pkL[128 * 64];
  __shared__ u16 ptL[4][32 * 132];
  __shared__ float zL[128];
  const int t = threadIdx.x, lane = t & 63, w = t >> 6;
  const int r15 = lane & 15, g = lane >> 4;
  #pragma unroll
  for (int i = 0; i < 4; ++i){
    int ch = i * 256 + t, row = ch >> 3, cc = ch & 7;
    int csrc = cc ^ (row & 7);
    gld16(pkh + (long)row * 1024 + csrc * 8, (char*)pkL + ch * 16);
  }
  if (t < 128) zL[t] = zh[t];
  __syncthreads();
  const int n0 = nb * 128 + w * 32;
  fx4 acc[8][2] = {};
  #pragma unroll
  for (int ks = 0; ks < 2; ++ks){
    bf16x8 bq[2];
    #pragma unroll
    for (int nf = 0; nf < 2; ++nf)
      bq[nf] = *(const bf16x8*)(qph + (long)(n0 + nf * 16 + r15) * 64 + ks * 32 + g * 8);
    #pragma unroll
    for (int mf = 0; mf < 8; ++mf){
      int row = mf * 16 + r15;
      int x = (ks * 4 + g) ^ (row & 7);
      bf16x8 a = *(const bf16x8*)((const char*)pkL + row * 128 + x * 16);
      #pragma unroll
      for (int nf = 0; nf < 2; ++nf)
        acc[mf][nf] = __builtin_amdgcn_mfma_f32_16x16x32_bf16(a, bq[nf], acc[mf][nf], 0, 0, 0);
    }
  }
  u16* pt = ptL[w];
  #pragma unroll
  for (int mf = 0; mf < 8; ++mf){
    const int kb = mf * 16 + g * 4;
    const float z0 = zL[kb], z1 = zL[kb + 1], z2 = zL[kb + 2], z3 = zL[kb + 3];
    #pragma unroll
    for (int nf = 0; nf < 2; ++nf){
      const int nl = nf * 16 + r15;
      u32 lo = (u32)f2bf(__expf(acc[mf][nf][0]) * z0) |
               ((u32)f2bf(__expf(acc[mf][nf][1]) * z1) << 16);
      u32 hi = (u32)f2bf(__expf(acc[mf][nf][2]) * z2) |
               ((u32)f2bf(__expf(acc[mf][nf][3]) * z3) << 16);
      u32x2 pkd = { lo, hi };
      *(u32x2*)(pt + nl * 132 + kb) = pkd;
    }
  }
  fx4 o[2][4] = {};
  #pragma unroll
  for (int ks = 0; ks < 4; ++ks){
    bf16x8 bv[4];
    #pragma unroll
    for (int nf = 0; nf < 4; ++nf)
      bv[nf] = *(const bf16x8*)(pvh + (long)(nf * 16 + r15) * 128 + ks * 32 + g * 8);
    #pragma unroll
    for (int mf = 0; mf < 2; ++mf){
      bf16x8 pa = *(const bf16x8*)(pt + (mf * 16 + r15) * 132 + ks * 32 + g * 8);
      #pragma unroll
      for (int nf = 0; nf < 4; ++nf)
        o[mf][nf] = __builtin_amdgcn_mfma_f32_16x16x32_bf16(pa, bv[nf], o[mf][nf], 0, 0, 0);
    }
  }
  u16* og = outh + ((long)b * 2048 + n0) * 1024 + h * 64;
  #pragma unroll
  for (int mf = 0; mf < 2; ++mf)
    #pragma unroll
    for (int nf = 0; nf < 4; ++nf)
      #pragma unroll
      for (int r = 0; r < 4; ++r){
        int nl = mf * 16 + g * 4 + r;
        og[(long)nl * 1024 + nf * 16 + r15] = f2bf(o[mf][nf][r]);
      }
}

extern "C" void kernel_launch(void* const* d_in, const int* in_sizes, int n_in,
                              void* d_out, int out_size, void* d_ws, size_t ws_size,
                              hipStream_t stream)
{
  const float* q   = (const float*)d_in[0];
  const float* k   = (const float*)d_in[1];
  const float* v   = (const float*)d_in[2];
  const float* Wq  = (const float*)d_in[3];
  const float* bq  = (const float*)d_in[4];
  const float* Wk  = (const float*)d_in[5];
  const float* bk  = (const float*)d_in[6];
  const float* Wv  = (const float*)d_in[7];
  const float* bv  = (const float*)d_in[8];
  const float* pjk = (const float*)d_in[9];
  const float* pjv = (const float*)d_in[10];
  const float* Wo  = (const float*)d_in[11];
  const float* bo  = (const float*)d_in[12];

  if (ws_size < 152044544u) return;

  char* ws = (char*)d_ws;
  u16*  q_bf  = (u16*)(ws + 0);            // 32MB (reused by outh)
  float* invZ = (float*)(ws + 33554432);   // [128][128]
  u16*  W_bf  = (u16*)(ws + 100663296);    // 4 x 1Mi elems: Wq,Wk,Wv,Wo
  u16*  projT = (u16*)(ws + 109051904);    // projkT [128][2048], projvT after
  float* sk   = (float*)(ws + 110100480);
  float* sv   = (float*)(ws + 110100992);
  u16*  qp    = (u16*)(ws + 110101504);    // 32MB [16384,1024]
  u16*  ck    = (u16*)(ws + 143655936);    // [2][8][128][1024]
  u16*  pk    = (u16*)(ws + 147850240);    // [8][128][1024], pre-scaled 1/8
  u16*  pvT   = (u16*)(ws + 149947392);    // [8][16][64][128]
  u16*  outh  = (u16*)(ws + 0);            // overlay q_bf
  u16*  Wq_bf = W_bf, *Wk_bf = W_bf + 1048576, *Wv_bf = W_bf + 2097152, *Wo_bf = W_bf + 3145728;

  k_f2bf<<<2048, 256, 0, stream>>>(q, q_bf, 2097152);
  k_f2bfW<<<dim3(128,4), 256, 0, stream>>>(Wq, Wk, Wv, Wo, W_bf, sk);
  k_tconv<<<dim3(2,32,1),  256, 0, stream>>>(pjk, projT,          2048, 128, 0, 0, sk);
  k_tconv<<<dim3(2,32,1),  256, 0, stream>>>(pjv, projT + 262144, 2048, 128, 0, 0, sv);

  // qp = q @ Wq^T + bq   (256x128 phased kernel)
  k_gemm256<1,u16><<<dim3(8,64), 512, 0, stream>>>(
      q_bf,1024, Wq_bf,1024, qp,1024, 1024, bq);
  // ck = projkT @ k^T ; cv = projvT @ v^T  (fused transpose, reads fp32 k/v)
  k_gemmTN<<<dim3(16,2,16), 256, 0, stream>>>(projT, k, v, ck);
  // pk = (ck @ Wk^T + sk (x) bk) / 8   (64x64 tile -> 256 blocks)
  k_gemm<64,64,0,2,u16><<<dim3(16,2,8), 256, 0, stream>>>(
      ck,1024,131072, Wk_bf,1024,0, pk,1024,131072, 1024, bk, sk, 0.125f);
  // pvT = (cv @ Wv^T + sv (x) bv), transposed write (64x64 tile -> 256 blocks)
  k_gemm<64,64,0,3,u16><<<dim3(16,2,8), 256, 0, stream>>>(
      ck + 1048576,1024,131072, Wv_bf,1024,0, pvT,0,131072, 1024, bv, sv, 1.f);
  // fused attention
  k_stats<<<128, 512, 0, stream>>>(pk, qp, invZ);
  k_attn<<<dim3(16,128), 256, 0, stream>>>(pk, qp, pvT, invZ, outh);
  // final = outh @ Wo^T + bo -> fp32 d_out
  k_gemm256<1,float><<<dim3(8,64), 512, 0, stream>>>(
      outh,1024, Wo_bf,1024, (float*)d_out,1024, 1024, bo);
}

// Round 9
// 239.029 us; speedup vs baseline: 1.5857x; 1.0054x over previous
//
#include <hip/hip_runtime.h>

typedef unsigned short u16;
typedef unsigned int   u32;
typedef __attribute__((ext_vector_type(4))) float fx4;
typedef __attribute__((ext_vector_type(8))) __bf16 bf16x8;
typedef __attribute__((ext_vector_type(4))) __bf16 bf16x4;
typedef __attribute__((ext_vector_type(8))) unsigned short us8;
typedef __attribute__((ext_vector_type(2))) unsigned int u32x2;

__device__ __forceinline__ u16 f2bf(float x){
  u32 u = __builtin_bit_cast(u32, x);
  u += 0x7fffu + ((u >> 16) & 1u);
  return (u16)(u >> 16);
}
__device__ __forceinline__ float b2f(u16 h){
  u32 u = ((u32)h) << 16;
  return __builtin_bit_cast(float, u);
}
__device__ __forceinline__ void gld16(const void* g, void* l){
  __builtin_amdgcn_global_load_lds(
      (const __attribute__((address_space(1))) u32*)g,
      (__attribute__((address_space(3))) u32*)l, 16, 0, 0);
}
// XCD-chunked bijective swizzle (grid size must be %8==0).
__device__ __forceinline__ void xcd_remap(u32& bx, u32& by, u32& bz){
  u32 nx = gridDim.x, ny = gridDim.y, nz = gridDim.z;
  u32 nwg = nx * ny * nz;
  u32 orig = (blockIdx.z * ny + blockIdx.y) * nx + blockIdx.x;
  u32 lid = (orig & 7u) * (nwg >> 3) + (orig >> 3);
  bx = lid % nx;
  u32 rem = lid / nx;
  by = rem % ny;
  bz = rem / ny;
}

// ---------------- fp32 -> bf16 convert (vectorized, grid-stride) ----------------
__global__ __launch_bounds__(256) void k_f2bf(const float* __restrict__ in,
                                              u16* __restrict__ out, int n8){
  int i = blockIdx.x * 256 + threadIdx.x;
  const int stride = gridDim.x * 256;
  for (; i < n8; i += stride){
    const float4* p = (const float4*)in + (long)i * 2;
    float4 a = p[0], b = p[1];
    us8 o = { f2bf(a.x), f2bf(a.y), f2bf(a.z), f2bf(a.w),
              f2bf(b.x), f2bf(b.y), f2bf(b.z), f2bf(b.w) };
    *((us8*)out + i) = o;
  }
}

// four 1024x1024 weights in one launch; also zeroes the 256-float colsum buffer
__global__ __launch_bounds__(256) void k_f2bfW(const float* __restrict__ w0,
                                               const float* __restrict__ w1,
                                               const float* __restrict__ w2,
                                               const float* __restrict__ w3,
                                               u16* __restrict__ out,
                                               float* __restrict__ zbuf){
  if (blockIdx.x == 0 && blockIdx.y == 0) zbuf[threadIdx.x] = 0.f;
  const float* src = blockIdx.y == 0 ? w0 : blockIdx.y == 1 ? w1 :
                     blockIdx.y == 2 ? w2 : w3;
  u16* dst = out + (long)blockIdx.y * 1048576;
  int i = blockIdx.x * 256 + threadIdx.x;
  const int stride = gridDim.x * 256;
  for (; i < 131072; i += stride){
    const float4* p = (const float4*)src + (long)i * 2;
    float4 a = p[0], b = p[1];
    us8 o = { f2bf(a.x), f2bf(a.y), f2bf(a.z), f2bf(a.w),
              f2bf(b.x), f2bf(b.y), f2bf(b.z), f2bf(b.w) };
    *((us8*)dst + i) = o;
  }
}

// ---------------- transpose + convert (proj only): [R,C] f32 -> [C,R] bf16 -------
__global__ __launch_bounds__(256) void k_tconv(const float* __restrict__ in,
                                               u16* __restrict__ out,
                                               int R, int C, long sIn, long sOut,
                                               float* __restrict__ colsum){
  in  += (long)blockIdx.z * sIn;
  out += (long)blockIdx.z * sOut;
  const int c0 = blockIdx.x * 64, r0 = blockIdx.y * 64;
  __shared__ u16 tile[64][66];
  __shared__ float red[256];
  const int t = threadIdx.x;
  const int cc = t & 63, wq = t >> 6;
  float part = 0.f;
  #pragma unroll
  for (int i = 0; i < 16; ++i){
    int rr = i * 4 + wq;
    float v = in[(long)(r0 + rr) * C + c0 + cc];
    tile[rr][cc] = f2bf(v);
    part += v;
  }
  if (colsum){
    red[t] = part;
    __syncthreads();
    if (t < 64){
      float s = red[t] + red[t + 64] + red[t + 128] + red[t + 192];
      atomicAdd(&colsum[c0 + t], s);
    }
  }
  __syncthreads();
  const int oc0 = t >> 5, jb = (t & 31) * 2;
  #pragma unroll
  for (int i = 0; i < 8; ++i){
    int oc = oc0 + i * 8;
    u32 pk2 = (u32)tile[jb][oc] | ((u32)tile[jb + 1][oc] << 16);
    *(u32*)(out + (long)(c0 + oc) * R + r0 + jb) = pk2;
  }
}

// ---------------- BT-layout MFMA GEMM (small/batched shapes) ----------------
template<int BM, int BN, int MODE, int EPI, typename OutT>
__global__ __launch_bounds__(256) void k_gemm(
    const u16* __restrict__ A, int lda, long sAz,
    const u16* __restrict__ B, int ldb, long sBz,
    OutT* __restrict__ C, int ldc, long sCz,
    int K, const float* __restrict__ bias, const float* __restrict__ srow, float scale)
{
  constexpr int BK = 64;
  constexpr int FM = BM / 32, FN = BN / 32;
  __shared__ u16 ldsA[BM * BK];
  __shared__ u16 ldsB[BN * BK];
  u32 bx, by, bz;
  xcd_remap(bx, by, bz);
  const long z = bz;
  if constexpr (MODE == 0){ A += z * sAz; B += z * sBz; C += z * sCz; }
  const int t = threadIdx.x;
  const int lane = t & 63;
  const int w = t >> 6, wm = w >> 1, wn = w & 1;
  const int r15 = lane & 15, g = lane >> 4;
  const int m0 = by * BM, n0 = bx * BN;
  fx4 acc[FM][FN] = {};
  constexpr int CA = BM * BK / (8 * 256);
  constexpr int CB = BN * BK / (8 * 256);
  for (int kt = 0; kt < K; kt += BK){
    #pragma unroll
    for (int i = 0; i < CA; ++i){
      int ch = i * 256 + t, row = ch >> 3, cc = ch & 7;
      gld16(A + (long)(m0 + row) * lda + kt + cc * 8, (char*)ldsA + ch * 16);
    }
    #pragma unroll
    for (int i = 0; i < CB; ++i){
      int ch = i * 256 + t, row = ch >> 3, cc = ch & 7;
      gld16(B + (long)(n0 + row) * ldb + kt + cc * 8, (char*)ldsB + ch * 16);
    }
    __syncthreads();
    #pragma unroll
    for (int ks = 0; ks < 2; ++ks){
      bf16x8 af[FM], bfv[FN];
      #pragma unroll
      for (int mf = 0; mf < FM; ++mf)
        af[mf] = *(const bf16x8*)&ldsA[(wm * (BM/2) + mf * 16 + r15) * BK + ks * 32 + g * 8];
      #pragma unroll
      for (int nf = 0; nf < FN; ++nf)
        bfv[nf] = *(const bf16x8*)&ldsB[(wn * (BN/2) + nf * 16 + r15) * BK + ks * 32 + g * 8];
      #pragma unroll
      for (int mf = 0; mf < FM; ++mf)
        #pragma unroll
        for (int nf = 0; nf < FN; ++nf)
          acc[mf][nf] = __builtin_amdgcn_mfma_f32_16x16x32_bf16(af[mf], bfv[nf], acc[mf][nf], 0, 0, 0);
    }
    __syncthreads();
  }
  #pragma unroll
  for (int mf = 0; mf < FM; ++mf){
    #pragma unroll
    for (int nf = 0; nf < FN; ++nf){
      const int row0 = m0 + wm * (BM/2) + mf * 16 + g * 4;
      const int col  = n0 + wn * (BN/2) + nf * 16 + r15;
      float vv[4];
      #pragma unroll
      for (int r = 0; r < 4; ++r){
        float v = acc[mf][nf][r];
        if constexpr (EPI == 1) v += bias[col];
        if constexpr (EPI == 2) v = (v + srow[row0 + r] * bias[col]) * scale;
        if constexpr (EPI == 3) v = v + srow[row0 + r] * bias[col];
        vv[r] = v;
      }
      if constexpr (EPI == 3){
        u32 lo = (u32)f2bf(vv[0]) | ((u32)f2bf(vv[1]) << 16);
        u32 hi = (u32)f2bf(vv[2]) | ((u32)f2bf(vv[3]) << 16);
        u32x2 pk2 = { lo, hi };
        *(u32x2*)((u16*)C + (long)col * 128 + row0) = pk2;
      } else {
        #pragma unroll
        for (int r = 0; r < 4; ++r){
          if constexpr (sizeof(OutT) == 2) C[(long)(row0 + r) * ldc + col] = (OutT)f2bf(vv[r]);
          else                             C[(long)(row0 + r) * ldc + col] = (OutT)vv[r];
        }
      }
    }
  }
}

// ---------------- big-M GEMM: 256x128 tile, phased counted-vmcnt (R4, best) ------
template<int EPI, typename OutT>
__global__ __launch_bounds__(512, 1) void k_gemm256(
    const u16* __restrict__ A, int lda,
    const u16* __restrict__ B, int ldb,
    OutT* __restrict__ C, int ldc,
    int K, const float* __restrict__ bias)
{
  constexpr int BM = 256, BN = 128, BK = 64;
  __shared__ u16 ldsA[3][BM * BK];
  __shared__ u16 ldsB[3][BN * BK];
  u32 bx, by, bz;
  xcd_remap(bx, by, bz);
  const int m0 = by * BM, n0 = bx * BN;
  const int t = threadIdx.x;
  const int lane = t & 63, w = t >> 6;
  const int wm = w >> 1, wn = w & 1;
  const int r15 = lane & 15, g = lane >> 4;
  const int NT = K >> 6;

  auto stageA = [&](int kt, int buf){
    #pragma unroll
    for (int j = 0; j < 4; ++j){
      int ch = j * 512 + t, row = ch >> 3, cc = ch & 7;
      gld16(A + (long)(m0 + row) * lda + kt + ((cc ^ (row & 7)) * 8),
            (char*)ldsA[buf] + ch * 16);
    }
  };
  auto stageB = [&](int kt, int buf){
    #pragma unroll
    for (int j = 0; j < 2; ++j){
      int ch = j * 512 + t, row = ch >> 3, cc = ch & 7;
      gld16(B + (long)(n0 + row) * ldb + kt + ((cc ^ (row & 7)) * 8),
            (char*)ldsB[buf] + ch * 16);
    }
  };

  stageA(0, 0); stageB(0, 0);
  if (NT > 1){
    stageA(BK, 1); stageB(BK, 1);
    asm volatile("s_waitcnt vmcnt(6)" ::: "memory");
  } else {
    asm volatile("s_waitcnt vmcnt(0)" ::: "memory");
  }
  __builtin_amdgcn_s_barrier();
  asm volatile("" ::: "memory");

  fx4 acc[4][4] = {};
  for (int tt = 0; tt < NT; ++tt){
    const u16* bA = ldsA[tt % 3];
    const u16* bB = ldsB[tt % 3];
    const int sbuf = (tt + 2) % 3;
    const bool pf = (tt + 2 < NT);
    bf16x8 af[2][4], bf[2][2];
    #pragma unroll
    for (int ks = 0; ks < 2; ++ks)
      #pragma unroll
      for (int mf = 0; mf < 4; ++mf)
        af[ks][mf] = *(const bf16x8*)((const char*)bA +
            (wm * 64 + mf * 16 + r15) * 128 + (((ks * 4 + g) ^ (r15 & 7)) * 16));
    #pragma unroll
    for (int ks = 0; ks < 2; ++ks)
      #pragma unroll
      for (int nf = 0; nf < 2; ++nf)
        bf[ks][nf] = *(const bf16x8*)((const char*)bB +
            (wn * 64 + nf * 16 + r15) * 128 + (((ks * 4 + g) ^ (r15 & 7)) * 16));
    if (pf) stageA((tt + 2) * BK, sbuf);
    asm volatile("" ::: "memory");
    __builtin_amdgcn_s_barrier();
    asm volatile("" ::: "memory");
    __builtin_amdgcn_s_setprio(1);
    #pragma unroll
    for (int ks = 0; ks < 2; ++ks)
      #pragma unroll
      for (int mf = 0; mf < 4; ++mf)
        #pragma unroll
        for (int nf = 0; nf < 2; ++nf)
          acc[mf][nf] = __builtin_amdgcn_mfma_f32_16x16x32_bf16(af[ks][mf], bf[ks][nf], acc[mf][nf], 0, 0, 0);
    __builtin_amdgcn_s_setprio(0);
    asm volatile("" ::: "memory");
    __builtin_amdgcn_s_barrier();
    asm volatile("" ::: "memory");
    bf16x8 bf2[2][2];
    #pragma unroll
    for (int ks = 0; ks < 2; ++ks)
      #pragma unroll
      for (int nf = 0; nf < 2; ++nf)
        bf2[ks][nf] = *(const bf16x8*)((const char*)bB +
            (wn * 64 + (nf + 2) * 16 + r15) * 128 + (((ks * 4 + g) ^ (r15 & 7)) * 16));
    if (pf) stageB((tt + 2) * BK, sbuf);
    __builtin_amdgcn_s_setprio(1);
    #pragma unroll
    for (int ks = 0; ks < 2; ++ks)
      #pragma unroll
      for (int mf = 0; mf < 4; ++mf)
        #pragma unroll
        for (int nf = 0; nf < 2; ++nf)
          acc[mf][nf + 2] = __builtin_amdgcn_mfma_f32_16x16x32_bf16(af[ks][mf], bf2[ks][nf], acc[mf][nf + 2], 0, 0, 0);
    __builtin_amdgcn_s_setprio(0);
    if (pf)                { asm volatile("s_waitcnt vmcnt(6)" ::: "memory"); }
    else if (tt + 1 < NT)  { asm volatile("s_waitcnt vmcnt(0)" ::: "memory"); }
    asm volatile("" ::: "memory");
    __builtin_amdgcn_s_barrier();
    asm volatile("" ::: "memory");
  }

  #pragma unroll
  for (int mf = 0; mf < 4; ++mf)
    #pragma unroll
    for (int nf = 0; nf < 4; ++nf){
      const int row0 = m0 + wm * 64 + mf * 16 + g * 4;
      const int col  = n0 + wn * 64 + nf * 16 + r15;
      float bcol = 0.f;
      if constexpr (EPI == 1) bcol = bias[col];
      #pragma unroll
      for (int r = 0; r < 4; ++r){
        float vv = acc[mf][nf][r] + bcol;
        if constexpr (sizeof(OutT) == 2) C[(long)(row0 + r) * ldc + col] = (OutT)f2bf(vv);
        else                             C[(long)(row0 + r) * ldc + col] = (OutT)vv;
      }
    }
}

// ---------------- fused transpose ck GEMM v3 ----------------
// ck[p][b][kr][d] = projT[p] @ src[b]^T, src = k|v fp32 [2048 n][1024 d].
// BM=64(kr) BN=64(d) BK=64(n); grid (16,2,16)=512 blocks; LDS 51KB -> 3 blocks/CU
// (all 512 co-resident). Depth-2 pipeline, 3 LDS buffers, counted vmcnt(6),
// raw s_barrier (no vmcnt(0) drain in loop). B transpose-write piece-XOR swizzled:
// 8B piece r4 of row d stored at piece r4^(d&15); read as 2x ds_read_b64 mirrored.
__global__ __launch_bounds__(256) void k_gemmTN(
    const u16* __restrict__ projT, const float* __restrict__ ksrc,
    const float* __restrict__ vsrc, u16* __restrict__ ck)
{
  u32 bx, by, bz; xcd_remap(bx, by, bz);
  const int p = bz >> 3, b = bz & 7;
  const u16* A = projT + p * 262144 + by * 64 * 2048;      // [64 kr][2048 n]
  const float* S = (p ? vsrc : ksrc) + (long)b * 2097152;  // [2048 n][1024 d]
  u16* C = ck + p * 1048576 + b * 131072 + by * 65536;
  const int d0 = bx * 64;
  __shared__ u16 ldsA[3][64 * 64];
  __shared__ u16 ldsB[3][64 * 72];
  const int t = threadIdx.x, lane = t & 63, w = t >> 6;
  const int wm = w >> 1, wn = w & 1;
  const int r15 = lane & 15, g = lane >> 4;
  const int c4 = t & 15, r4 = t >> 4;

  auto ldA = [&](int kt, int buf){
    #pragma unroll
    for (int i = 0; i < 2; ++i){
      int ch = i * 256 + t, row = ch >> 3, cc = ch & 7;
      gld16(A + (long)row * 2048 + kt + ((cc ^ (row & 7)) * 8),
            (char*)ldsA[buf] + ch * 16);
    }
  };
  auto ldS = [&](int kt, float4* f){
    #pragma unroll
    for (int i = 0; i < 4; ++i)
      f[i] = *(const float4*)(S + (long)(kt + r4 * 4 + i) * 1024 + d0 + c4 * 4);
  };
  auto wrB = [&](const float4* f, int buf){
    #pragma unroll
    for (int j = 0; j < 4; ++j){
      const int d = c4 * 4 + j;
      u32 lo = (u32)f2bf(((const float*)&f[0])[j]) | ((u32)f2bf(((const float*)&f[1])[j]) << 16);
      u32 hi = (u32)f2bf(((const float*)&f[2])[j]) | ((u32)f2bf(((const float*)&f[3])[j]) << 16);
      u32x2 pr = { lo, hi };
      *(u32x2*)&ldsB[buf][d * 72 + ((r4 ^ (d & 15)) * 4)] = pr;
    }
  };

  fx4 acc[2][2] = {};
  auto compute = [&](int buf){
    #pragma unroll
    for (int ks = 0; ks < 2; ++ks){
      bf16x8 af[2], bfv[2];
      #pragma unroll
      for (int mf = 0; mf < 2; ++mf){
        int row = wm * 32 + mf * 16 + r15;
        af[mf] = *(const bf16x8*)((const char*)ldsA[buf] + row * 128 +
                                  (((ks * 4 + g) ^ (row & 7)) * 16));
      }
      #pragma unroll
      for (int nf = 0; nf < 2; ++nf){
        const int d = wn * 32 + nf * 16 + r15, x = d & 15;
        const int q0 = ks * 8 + g * 2;
        bf16x4 lo = *(const bf16x4*)&ldsB[buf][d * 72 + ((q0 ^ x) * 4)];
        bf16x4 hi = *(const bf16x4*)&ldsB[buf][d * 72 + (((q0 + 1) ^ x) * 4)];
        bfv[nf] = __builtin_shufflevector(lo, hi, 0, 1, 2, 3, 4, 5, 6, 7);
      }
      #pragma unroll
      for (int mf = 0; mf < 2; ++mf)
        #pragma unroll
        for (int nf = 0; nf < 2; ++nf)
          acc[mf][nf] = __builtin_amdgcn_mfma_f32_16x16x32_bf16(af[mf], bfv[nf], acc[mf][nf], 0, 0, 0);
    }
  };

  float4 fa[4], fb[4];
  ldS(0, fa); ldA(0, 0);
  ldS(64, fb); ldA(64, 1);
  asm volatile("s_waitcnt vmcnt(6)" ::: "memory");  // fa's 4 + A0's 2 landed
  wrB(fa, 0);
  asm volatile("s_waitcnt lgkmcnt(0)" ::: "memory");
  __builtin_amdgcn_s_barrier();
  asm volatile("" ::: "memory");

  for (int tt = 0; tt < 32; tt += 2){
    { // phase E: compute tile tt; prefetch tt+2 into fa; publish tt+1 (fb)
      const bool pf = (tt + 2 < 32);
      if (pf){ ldS((tt + 2) * 64, fa); ldA((tt + 2) * 64, (tt + 2) % 3); }
      asm volatile("" ::: "memory");
      compute(tt % 3);
      if (pf) { asm volatile("s_waitcnt vmcnt(6)" ::: "memory"); }
      else    { asm volatile("s_waitcnt vmcnt(0)" ::: "memory"); }
      wrB(fb, (tt + 1) % 3);
      asm volatile("s_waitcnt lgkmcnt(0)" ::: "memory");
      __builtin_amdgcn_s_barrier();
      asm volatile("" ::: "memory");
    }
    { // phase O: compute tile tt+1; prefetch tt+3 into fb; publish tt+2 (fa)
      const bool pf = (tt + 3 < 32);
      const bool hv = (tt + 2 < 32);
      if (pf){ ldS((tt + 3) * 64, fb); ldA((tt + 3) * 64, (tt + 3) % 3); }
      asm volatile("" ::: "memory");
      compute((tt + 1) % 3);
      if (hv){
        if (pf) { asm volatile("s_waitcnt vmcnt(6)" ::: "memory"); }
        else    { asm volatile("s_waitcnt vmcnt(0)" ::: "memory"); }
        wrB(fa, (tt + 2) % 3);
      }
      asm volatile("s_waitcnt lgkmcnt(0)" ::: "memory");
      __builtin_amdgcn_s_barrier();
      asm volatile("" ::: "memory");
    }
  }

  #pragma unroll
  for (int mf = 0; mf < 2; ++mf)
    #pragma unroll
    for (int nf = 0; nf < 2; ++nf){
      const int row0 = wm * 32 + mf * 16 + g * 4;
      const int col  = d0 + wn * 32 + nf * 16 + r15;
      #pragma unroll
      for (int r = 0; r < 4; ++r)
        C[(long)(row0 + r) * 1024 + col] = f2bf(acc[mf][nf][r]);
    }
}

// ---------------- fused attention, pass 1: Z[k] = sum_n exp(s[k,n]) ----------------
__global__ __launch_bounds__(512) void k_stats(const u16* __restrict__ pk,
                                               const u16* __restrict__ qp,
                                               float* __restrict__ invZ){
  const int z = blockIdx.x;
  const int b = z >> 4, h = z & 15;
  const u16* pkh = pk + b * 131072 + h * 64;
  const u16* qph = qp + (long)z * 131072;
  __shared__ u16 pkL[128 * 64];
  __shared__ float zred[8][128];
  const int t = threadIdx.x, lane = t & 63, w = t >> 6;
  const int r15 = lane & 15, g = lane >> 4;
  #pragma unroll
  for (int i = 0; i < 2; ++i){
    int ch = i * 512 + t, row = ch >> 3, cc = ch & 7;
    int csrc = cc ^ (row & 7);
    gld16(pkh + (long)row * 1024 + csrc * 8, (char*)pkL + ch * 16);
  }
  __syncthreads();
  float zacc[8][4] = {};
  for (int c = 0; c < 8; ++c){
    const int n0 = w * 256 + c * 32;
    fx4 acc[8][2] = {};
    #pragma unroll
    for (int ks = 0; ks < 2; ++ks){
      bf16x8 bq[2];
      #pragma unroll
      for (int nf = 0; nf < 2; ++nf)
        bq[nf] = *(const bf16x8*)(qph + (long)(n0 + nf * 16 + r15) * 64 + ks * 32 + g * 8);
      #pragma unroll
      for (int mf = 0; mf < 8; ++mf){
        int row = mf * 16 + r15;
        int x = (ks * 4 + g) ^ (row & 7);
        bf16x8 a = *(const bf16x8*)((const char*)pkL + row * 128 + x * 16);
        #pragma unroll
        for (int nf = 0; nf < 2; ++nf)
          acc[mf][nf] = __builtin_amdgcn_mfma_f32_16x16x32_bf16(a, bq[nf], acc[mf][nf], 0, 0, 0);
      }
    }
    #pragma unroll
    for (int mf = 0; mf < 8; ++mf)
      #pragma unroll
      for (int nf = 0; nf < 2; ++nf)
        #pragma unroll
        for (int r = 0; r < 4; ++r)
          zacc[mf][r] += __expf(acc[mf][nf][r]);
  }
  #pragma unroll
  for (int mf = 0; mf < 8; ++mf)
    #pragma unroll
    for (int r = 0; r < 4; ++r){
      float v = zacc[mf][r];
      v += __shfl_xor(v, 1); v += __shfl_xor(v, 2);
      v += __shfl_xor(v, 4); v += __shfl_xor(v, 8);
      zacc[mf][r] = v;
    }
  if (r15 == 0){
    #pragma unroll
    for (int mf = 0; mf < 8; ++mf)
      #pragma unroll
      for (int r = 0; r < 4; ++r)
        zred[w][mf * 16 + g * 4 + r] = zacc[mf][r];
  }
  __syncthreads();
  if (t < 128){
    float s = 0.f;
    #pragma unroll
    for (int w2 = 0; w2 < 8; ++w2) s += zred[w2][t];
    invZ[(long)z * 128 + t] = 1.0f / s;
  }
}

// ---------------- fused attention, pass 2: out = attn^T @ pv ----------------
__global__ __launch_bounds__(256) void k_attn(const u16* __restrict__ pk,
                                              const u16* __restrict__ qp,
                                              const u16* __restrict__ pvT,
                                              const float* __restrict__ invZ,
                                              u16* __restrict__ outh){
  u32 bx, by, bz;
  xcd_remap(bx, by, bz);
  const int z = by, nb = bx;
  const int b = z >> 4, h = z & 15;
  const u16* pkh = pk  + b * 131072 + h * 64;
  const u16* qph = qp  + (long)z * 131072;
  const u16* pvh = pvT + b * 131072 + h * 8192;
  const float* zh = invZ + (long)z * 128;
  __shared__ u16 pkL[128 * 64];
  __shared__ u16 ptL[4][32 * 132];
  __shared__ float zL[128];
  const int t = threadIdx.x, lane = t & 63, w = t >> 6;
  const int r15 = lane & 15, g = lane >> 4;
  #pragma unroll
  for (int i = 0; i < 4; ++i){
    int ch = i * 256 + t, row = ch >> 3, cc = ch & 7;
    int csrc = cc ^ (row & 7);
    gld16(pkh + (long)row * 1024 + csrc * 8, (char*)pkL + ch * 16);
  }
  if (t < 128) zL[t] = zh[t];
  __syncthreads();
  const int n0 = nb * 128 + w * 32;
  fx4 acc[8][2] = {};
  #pragma unroll
  for (int ks = 0; ks < 2; ++ks){
    bf16x8 bq[2];
    #pragma unroll
    for (int nf = 0; nf < 2; ++nf)
      bq[nf] = *(const bf16x8*)(qph + (long)(n0 + nf * 16 + r15) * 64 + ks * 32 + g * 8);
    #pragma unroll
    for (int mf = 0; mf < 8; ++mf){
      int row = mf * 16 + r15;
      int x = (ks * 4 + g) ^ (row & 7);
      bf16x8 a = *(const bf16x8*)((const char*)pkL + row * 128 + x * 16);
      #pragma unroll
      for (int nf = 0; nf < 2; ++nf)
        acc[mf][nf] = __builtin_amdgcn_mfma_f32_16x16x32_bf16(a, bq[nf], acc[mf][nf], 0, 0, 0);
    }
  }
  u16* pt = ptL[w];
  #pragma unroll
  for (int mf = 0; mf < 8; ++mf){
    const int kb = mf * 16 + g * 4;
    const float z0 = zL[kb], z1 = zL[kb + 1], z2 = zL[kb + 2], z3 = zL[kb + 3];
    #pragma unroll
    for (int nf = 0; nf < 2; ++nf){
      const int nl = nf * 16 + r15;
      u32 lo = (u32)f2bf(__expf(acc[mf][nf][0]) * z0) |
               ((u32)f2bf(__expf(acc[mf][nf][1]) * z1) << 16);
      u32 hi = (u32)f2bf(__expf(acc[mf][nf][2]) * z2) |
               ((u32)f2bf(__expf(acc[mf][nf][3]) * z3) << 16);
      u32x2 pkd = { lo, hi };
      *(u32x2*)(pt + nl * 132 + kb) = pkd;
    }
  }
  fx4 o[2][4] = {};
  #pragma unroll
  for (int ks = 0; ks < 4; ++ks){
    bf16x8 bv[4];
    #pragma unroll
    for (int nf = 0; nf < 4; ++nf)
      bv[nf] = *(const bf16x8*)(pvh + (long)(nf * 16 + r15) * 128 + ks * 32 + g * 8);
    #pragma unroll
    for (int mf = 0; mf < 2; ++mf){
      bf16x8 pa = *(const bf16x8*)(pt + (mf * 16 + r15) * 132 + ks * 32 + g * 8);
      #pragma unroll
      for (int nf = 0; nf < 4; ++nf)
        o[mf][nf] = __builtin_amdgcn_mfma_f32_16x16x32_bf16(pa, bv[nf], o[mf][nf], 0, 0, 0);
    }
  }
  u16* og = outh + ((long)b * 2048 + n0) * 1024 + h * 64;
  #pragma unroll
  for (int mf = 0; mf < 2; ++mf)
    #pragma unroll
    for (int nf = 0; nf < 4; ++nf)
      #pragma unroll
      for (int r = 0; r < 4; ++r){
        int nl = mf * 16 + g * 4 + r;
        og[(long)nl * 1024 + nf * 16 + r15] = f2bf(o[mf][nf][r]);
      }
}

extern "C" void kernel_launch(void* const* d_in, const int* in_sizes, int n_in,
                              void* d_out, int out_size, void* d_ws, size_t ws_size,
                              hipStream_t stream)
{
  const float* q   = (const float*)d_in[0];
  const float* k   = (const float*)d_in[1];
  const float* v   = (const float*)d_in[2];
  const float* Wq  = (const float*)d_in[3];
  const float* bq  = (const float*)d_in[4];
  const float* Wk  = (const float*)d_in[5];
  const float* bk  = (const float*)d_in[6];
  const float* Wv  = (const float*)d_in[7];
  const float* bv  = (const float*)d_in[8];
  const float* pjk = (const float*)d_in[9];
  const float* pjv = (const float*)d_in[10];
  const float* Wo  = (const float*)d_in[11];
  const float* bo  = (const float*)d_in[12];

  if (ws_size < 152044544u) return;

  char* ws = (char*)d_ws;
  u16*  q_bf  = (u16*)(ws + 0);            // 32MB (reused by outh)
  float* invZ = (float*)(ws + 33554432);   // [128][128]
  u16*  W_bf  = (u16*)(ws + 100663296);    // 4 x 1Mi elems: Wq,Wk,Wv,Wo
  u16*  projT = (u16*)(ws + 109051904);    // projkT [128][2048], projvT after
  float* sk   = (float*)(ws + 110100480);
  float* sv   = (float*)(ws + 110100992);
  u16*  qp    = (u16*)(ws + 110101504);    // 32MB [16384,1024]
  u16*  ck    = (u16*)(ws + 143655936);    // [2][8][128][1024]
  u16*  pk    = (u16*)(ws + 147850240);    // [8][128][1024], pre-scaled 1/8
  u16*  pvT   = (u16*)(ws + 149947392);    // [8][16][64][128]
  u16*  outh  = (u16*)(ws + 0);            // overlay q_bf
  u16*  Wq_bf = W_bf, *Wk_bf = W_bf + 1048576, *Wv_bf = W_bf + 2097152, *Wo_bf = W_bf + 3145728;

  k_f2bf<<<2048, 256, 0, stream>>>(q, q_bf, 2097152);
  k_f2bfW<<<dim3(128,4), 256, 0, stream>>>(Wq, Wk, Wv, Wo, W_bf, sk);
  k_tconv<<<dim3(2,32,1),  256, 0, stream>>>(pjk, projT,          2048, 128, 0, 0, sk);
  k_tconv<<<dim3(2,32,1),  256, 0, stream>>>(pjv, projT + 262144, 2048, 128, 0, 0, sv);

  // qp = q @ Wq^T + bq   (256x128 phased kernel)
  k_gemm256<1,u16><<<dim3(8,64), 512, 0, stream>>>(
      q_bf,1024, Wq_bf,1024, qp,1024, 1024, bq);
  // ck = projkT @ k^T ; cv = projvT @ v^T  (fused transpose, reads fp32 k/v)
  k_gemmTN<<<dim3(16,2,16), 256, 0, stream>>>(projT, k, v, ck);
  // pk = (ck @ Wk^T + sk (x) bk) / 8   (64x64 tile -> 256 blocks)
  k_gemm<64,64,0,2,u16><<<dim3(16,2,8), 256, 0, stream>>>(
      ck,1024,131072, Wk_bf,1024,0, pk,1024,131072, 1024, bk, sk, 0.125f);
  // pvT = (cv @ Wv^T + sv (x) bv), transposed write (64x64 tile -> 256 blocks)
  k_gemm<64,64,0,3,u16><<<dim3(16,2,8), 256, 0, stream>>>(
      ck + 1048576,1024,131072, Wv_bf,1024,0, pvT,0,131072, 1024, bv, sv, 1.f);
  // fused attention
  k_stats<<<128, 512, 0, stream>>>(pk, qp, invZ);
  k_attn<<<dim3(16,128), 256, 0, stream>>>(pk, qp, pvT, invZ, outh);
  // final = outh @ Wo^T + bo -> fp32 d_out
  k_gemm256<1,float><<<dim3(8,64), 512, 0, stream>>>(
      outh,1024, Wo_bf,1024, (float*)d_out,1024, 1024, bo);
}